// Round 1
// baseline (427.916 us; speedup 1.0000x reference)
//
#include <hip/hip_runtime.h>
#include <hip/hip_bf16.h>

// ---------------- problem constants ----------------
#define B_N 2
#define L_N 8192
#define DM_N 256
#define NH_N 4
#define HP_N 64
#define NS_N 8
#define ROWS (B_N * L_N)          // 16384
#define DPROJ_N 532
#define ZXLD 1088                 // padded row stride of zx (1064 -> 1088, mult of 64)
#define SLICE_B 532
#define CHUNK 256
#define NCHUNK (L_N / CHUNK)      // 32

typedef __bf16 bf16x8 __attribute__((ext_vector_type(8)));
typedef float f32x4 __attribute__((ext_vector_type(4)));

__device__ __forceinline__ float siluf(float v) { return v / (1.f + __expf(-v)); }
__device__ __forceinline__ float softplusf_(float v) {
  return fmaxf(v, 0.f) + log1pf(__expf(-fabsf(v)));
}
__device__ __forceinline__ unsigned short f2bf(float v) {
  union { float f; unsigned u; } x; x.f = v;
  unsigned r = x.u + 0x7fffu + ((x.u >> 16) & 1u);
  return (unsigned short)(r >> 16);
}

// ---------------- conversion kernels ----------------
__global__ void k_cvt(const float* __restrict__ src, unsigned short* __restrict__ dst, int n) {
  int i = blockIdx.x * blockDim.x + threadIdx.x;
  int stride = gridDim.x * blockDim.x;
  for (; i < n; i += stride) dst[i] = f2bf(src[i]);
}

// dst[n*K + k] = bf16(src[k*N + n]); rows n in [N, Npad) zero-padded
__global__ void k_cvtT(const float* __restrict__ src, unsigned short* __restrict__ dst,
                       int K, int N, int Npad) {
  int i = blockIdx.x * blockDim.x + threadIdx.x;
  int total = K * Npad;
  int stride = gridDim.x * blockDim.x;
  for (; i < total; i += stride) {
    int k = i / Npad, n = i - k * Npad;
    float v = (n < N) ? src[(long)k * N + n] : 0.f;
    dst[(long)n * K + k] = f2bf(v);
  }
}

__global__ void k_rowmap(const int* __restrict__ v2h, int* __restrict__ rowmap) {
  int m = blockIdx.x * blockDim.x + threadIdx.x;
  if (m < ROWS) {
    int b = m >> 13;
    rowmap[m] = b * L_N + v2h[m];
  }
}

// exact fp32 recompute of the 4 dt columns of each 532-slice (both mats, both slices)
__global__ void k_dtfix(const float* __restrict__ xH, const float* __restrict__ xV,
                        const float* __restrict__ WH, const float* __restrict__ WV,
                        float* __restrict__ zxH, float* __restrict__ zxV) {
  int idx = blockIdx.x * blockDim.x + threadIdx.x;   // ROWS*16
  int row = idx >> 4;
  int c = idx & 15;
  int mat = c >> 3, sl = (c >> 2) & 1, hc = c & 3;
  const float* x = (mat ? xV : xH) + (long)row * DM_N;
  const float* W = (mat ? WV : WH);
  int wcol = sl * 532 + 528 + hc;
  float s = 0.f;
  #pragma unroll 8
  for (int k = 0; k < DM_N; ++k) s = fmaf(x[k], W[(long)k * 1064 + wcol], s);
  float* zx = (mat ? zxV : zxH);
  zx[(long)row * ZXLD + sl * 532 + 528 + hc] = s;
}

// ---------------- bf16 MFMA GEMM ----------------
// C(MxN) = A(MxK) * B(KxN), A row-major bf16 (lda), B supplied TRANSPOSED: Bt[n][k] (ldb)
// MODE 0: C float, plain store. MODE 1: C bf16, silu applied.
// rowmap: optional row scatter. col_off added to column index.
template <int MODE>
__global__ __launch_bounds__(256) void k_gemm(
    const unsigned short* __restrict__ A, const unsigned short* __restrict__ Bt,
    void* __restrict__ Cv, int M, int N, int K, int lda, int ldb, int ldc,
    const int* __restrict__ rowmap, int col_off) {
  __shared__ unsigned short As[128][56];   // 128 x 32 K-tile, padded to 56 (16B-aligned rows, 2-way banks)
  __shared__ unsigned short Bs[64][56];    // 64 n-rows x 32 k
  const int tid = threadIdx.x;
  const int lane = tid & 63;
  const int wid = tid >> 6;
  const int wm = wid & 1, wn = wid >> 1;
  const int q = lane >> 4, r = lane & 15;
  const int m0 = blockIdx.y * 128;
  const int n0 = blockIdx.x * 64;

  f32x4 acc[4][2] = {};

  for (int kt = 0; kt < K; kt += 32) {
    #pragma unroll
    for (int i = 0; i < 2; ++i) {
      int chunk = tid + i * 256;
      int row = chunk >> 2, c = (chunk & 3) * 8;
      uint4 v = *(const uint4*)(A + (long)(m0 + row) * lda + kt + c);
      *(uint4*)&As[row][c] = v;
    }
    {
      int row = tid >> 2, c = (tid & 3) * 8;
      uint4 v = *(const uint4*)(Bt + (long)(n0 + row) * ldb + kt + c);
      *(uint4*)&Bs[row][c] = v;
    }
    __syncthreads();
    bf16x8 af[4], bfr[2];
    #pragma unroll
    for (int mi = 0; mi < 4; ++mi)
      af[mi] = *(const bf16x8*)&As[wm * 64 + mi * 16 + r][q * 8];
    #pragma unroll
    for (int ni = 0; ni < 2; ++ni)
      bfr[ni] = *(const bf16x8*)&Bs[wn * 32 + ni * 16 + r][q * 8];
    #pragma unroll
    for (int mi = 0; mi < 4; ++mi)
      #pragma unroll
      for (int ni = 0; ni < 2; ++ni)
        acc[mi][ni] = __builtin_amdgcn_mfma_f32_16x16x32_bf16(af[mi], bfr[ni], acc[mi][ni], 0, 0, 0);
    __syncthreads();
  }

  #pragma unroll
  for (int mi = 0; mi < 4; ++mi) {
    #pragma unroll
    for (int ni = 0; ni < 2; ++ni) {
      #pragma unroll
      for (int j = 0; j < 4; ++j) {
        int row = m0 + wm * 64 + mi * 16 + q * 4 + j;
        int col = n0 + wn * 32 + ni * 16 + r;
        int orow = rowmap ? rowmap[row] : row;
        float v = acc[mi][ni][j];
        if (MODE == 0) {
          ((float*)Cv)[(long)orow * ldc + col + col_off] = v;
        } else {
          ((unsigned short*)Cv)[(long)orow * ldc + col + col_off] = f2bf(siluf(v));
        }
      }
    }
  }
}

// ---------------- scan kernels ----------------
struct ScanParams {
  const float* zx[4];
  const float* dt_bias[4];
  const float* A_log[4];
  const float* D[4];
  int slice[4];
  int rev[4];
};

// phase 1: per-chunk local scan from zero; write end-state S and cum-dA P
__global__ __launch_bounds__(64) void k_scan1(ScanParams sp, float* __restrict__ S,
                                              float* __restrict__ P) {
  __shared__ float xs[64][64];
  __shared__ float Bst[64][8];
  __shared__ float dAs[64];
  const int p = threadIdx.x;
  const int c = blockIdx.x;
  const int bh = blockIdx.y;
  const int d = blockIdx.z;
  const int b = bh >> 2, h = bh & 3;
  const float* zx = sp.zx[d];
  const int slice = sp.slice[d];
  const int rev = sp.rev[d];
  const float A_h = -__expf(sp.A_log[d][h]);
  const float dtb = sp.dt_bias[d][h];

  float st[8] = {0, 0, 0, 0, 0, 0, 0, 0};
  float cumdA = 1.f;

  for (int sub = 0; sub < CHUNK / 64; ++sub) {
    const int t0 = c * CHUNK + sub * 64;
    {
      const int t = t0 + p;
      const int l = rev ? (L_N - 1 - t) : t;
      const float* rp = zx + (long)((b << 13) + l) * ZXLD + slice;
      float4 b0 = *(const float4*)(rp + 512);
      float4 b1 = *(const float4*)(rp + 516);
      float dtv = softplusf_(rp[528 + h] + dtb);
      dAs[p] = __expf(dtv * A_h);
      Bst[p][0] = siluf(b0.x) * dtv;
      Bst[p][1] = siluf(b0.y) * dtv;
      Bst[p][2] = siluf(b0.z) * dtv;
      Bst[p][3] = siluf(b0.w) * dtv;
      Bst[p][4] = siluf(b1.x) * dtv;
      Bst[p][5] = siluf(b1.y) * dtv;
      Bst[p][6] = siluf(b1.z) * dtv;
      Bst[p][7] = siluf(b1.w) * dtv;
    }
    {
      const int l0 = rev ? (L_N - 1 - t0) : t0;
      const float* xp = zx + (long)((b << 13) + l0) * ZXLD + slice + 256 + h * 64 + p;
      const long stp = rev ? -(long)ZXLD : (long)ZXLD;
      #pragma unroll 8
      for (int s = 0; s < 64; ++s) {
        xs[s][p] = siluf(*xp);
        xp += stp;
      }
    }
    __syncthreads();
    #pragma unroll 8
    for (int s = 0; s < 64; ++s) {
      float x = xs[s][p];
      float dA = dAs[s];
      float4 B0 = *(const float4*)&Bst[s][0];
      float4 B1 = *(const float4*)&Bst[s][4];
      cumdA *= dA;
      st[0] = fmaf(dA, st[0], x * B0.x);
      st[1] = fmaf(dA, st[1], x * B0.y);
      st[2] = fmaf(dA, st[2], x * B0.z);
      st[3] = fmaf(dA, st[3], x * B0.w);
      st[4] = fmaf(dA, st[4], x * B1.x);
      st[5] = fmaf(dA, st[5], x * B1.y);
      st[6] = fmaf(dA, st[6], x * B1.z);
      st[7] = fmaf(dA, st[7], x * B1.w);
    }
    __syncthreads();
  }
  float* Sp = S + ((((long)d * NCHUNK + c) * 8 + bh) * 64 + p) * 8;
  #pragma unroll
  for (int n = 0; n < 8; ++n) Sp[n] = st[n];
  if (p == 0) P[((long)d * NCHUNK + c) * 8 + bh] = cumdA;
}

// phase 2: sequential chunk-level combine -> carry-in per chunk
__global__ __launch_bounds__(64) void k_scan2(const float* __restrict__ S,
                                              const float* __restrict__ P,
                                              float* __restrict__ carry) {
  const int p = threadIdx.x;
  const int dbh = blockIdx.x;
  const int d = dbh >> 3, bh = dbh & 7;
  float cy[8] = {0, 0, 0, 0, 0, 0, 0, 0};
  {
    float* cp = carry + (((long)d * NCHUNK * 8 + bh) * 64 + p) * 8;
    #pragma unroll
    for (int n = 0; n < 8; ++n) cp[n] = 0.f;
  }
  for (int c = 1; c < NCHUNK; ++c) {
    const float Pv = P[((long)d * NCHUNK + (c - 1)) * 8 + bh];
    const float* Sp = S + ((((long)d * NCHUNK + (c - 1)) * 8 + bh) * 64 + p) * 8;
    float* cp = carry + ((((long)d * NCHUNK + c) * 8 + bh) * 64 + p) * 8;
    #pragma unroll
    for (int n = 0; n < 8; ++n) {
      cy[n] = fmaf(Pv, cy[n], Sp[n]);
      cp[n] = cy[n];
    }
  }
}

// phase 3: re-scan with carry-in, produce gated y in bf16
__global__ __launch_bounds__(64) void k_scan3(ScanParams sp, const float* __restrict__ carry,
                                              unsigned short* __restrict__ ybf) {
  __shared__ float xs[64][64];
  __shared__ float zs[64][64];
  __shared__ float Bst[64][8];
  __shared__ float Cst[64][8];
  __shared__ float dAs[64];
  const int p = threadIdx.x;
  const int c = blockIdx.x;
  const int bh = blockIdx.y;
  const int d = blockIdx.z;
  const int b = bh >> 2, h = bh & 3;
  const float* zx = sp.zx[d];
  const int slice = sp.slice[d];
  const int rev = sp.rev[d];
  const float A_h = -__expf(sp.A_log[d][h]);
  const float dtb = sp.dt_bias[d][h];
  const float Dv = sp.D[d][h];

  float st[8];
  {
    const float* cp = carry + ((((long)d * NCHUNK + c) * 8 + bh) * 64 + p) * 8;
    #pragma unroll
    for (int n = 0; n < 8; ++n) st[n] = cp[n];
  }

  for (int sub = 0; sub < CHUNK / 64; ++sub) {
    const int t0 = c * CHUNK + sub * 64;
    {
      const int t = t0 + p;
      const int l = rev ? (L_N - 1 - t) : t;
      const float* rp = zx + (long)((b << 13) + l) * ZXLD + slice;
      float4 b0 = *(const float4*)(rp + 512);
      float4 b1 = *(const float4*)(rp + 516);
      float4 c0 = *(const float4*)(rp + 520);
      float4 c1 = *(const float4*)(rp + 524);
      float dtv = softplusf_(rp[528 + h] + dtb);
      dAs[p] = __expf(dtv * A_h);
      Bst[p][0] = siluf(b0.x) * dtv;
      Bst[p][1] = siluf(b0.y) * dtv;
      Bst[p][2] = siluf(b0.z) * dtv;
      Bst[p][3] = siluf(b0.w) * dtv;
      Bst[p][4] = siluf(b1.x) * dtv;
      Bst[p][5] = siluf(b1.y) * dtv;
      Bst[p][6] = siluf(b1.z) * dtv;
      Bst[p][7] = siluf(b1.w) * dtv;
      Cst[p][0] = siluf(c0.x);
      Cst[p][1] = siluf(c0.y);
      Cst[p][2] = siluf(c0.z);
      Cst[p][3] = siluf(c0.w);
      Cst[p][4] = siluf(c1.x);
      Cst[p][5] = siluf(c1.y);
      Cst[p][6] = siluf(c1.z);
      Cst[p][7] = siluf(c1.w);
    }
    {
      const int l0 = rev ? (L_N - 1 - t0) : t0;
      const float* xp = zx + (long)((b << 13) + l0) * ZXLD + slice + 256 + h * 64 + p;
      const float* zp = zx + (long)((b << 13) + l0) * ZXLD + slice + h * 64 + p;
      const long stp = rev ? -(long)ZXLD : (long)ZXLD;
      #pragma unroll 4
      for (int s = 0; s < 64; ++s) {
        xs[s][p] = siluf(*xp);
        zs[s][p] = siluf(*zp);
        xp += stp;
        zp += stp;
      }
    }
    __syncthreads();
    const int l0 = rev ? (L_N - 1 - t0) : t0;
    unsigned short* yp = ybf + ((long)d * ROWS + (b << 13) + l0) * 256 + h * 64 + p;
    const long ystp = rev ? -256L : 256L;
    #pragma unroll 4
    for (int s = 0; s < 64; ++s) {
      float x = xs[s][p];
      float dA = dAs[s];
      float4 B0 = *(const float4*)&Bst[s][0];
      float4 B1 = *(const float4*)&Bst[s][4];
      float4 C0 = *(const float4*)&Cst[s][0];
      float4 C1 = *(const float4*)&Cst[s][4];
      st[0] = fmaf(dA, st[0], x * B0.x);
      st[1] = fmaf(dA, st[1], x * B0.y);
      st[2] = fmaf(dA, st[2], x * B0.z);
      st[3] = fmaf(dA, st[3], x * B0.w);
      st[4] = fmaf(dA, st[4], x * B1.x);
      st[5] = fmaf(dA, st[5], x * B1.y);
      st[6] = fmaf(dA, st[6], x * B1.z);
      st[7] = fmaf(dA, st[7], x * B1.w);
      float y = st[0] * C0.x;
      y = fmaf(st[1], C0.y, y);
      y = fmaf(st[2], C0.z, y);
      y = fmaf(st[3], C0.w, y);
      y = fmaf(st[4], C1.x, y);
      y = fmaf(st[5], C1.y, y);
      y = fmaf(st[6], C1.z, y);
      y = fmaf(st[7], C1.w, y);
      y = (y + Dv * x) * zs[s][p];
      *yp = f2bf(y);
      yp += ystp;
    }
    __syncthreads();
  }
}

// ---------------- launch ----------------
extern "C" void kernel_launch(void* const* d_in, const int* in_sizes, int n_in,
                              void* d_out, int out_size, void* d_ws, size_t ws_size,
                              hipStream_t stream) {
  const float* x_H = (const float*)d_in[0];
  const float* x_V = (const float*)d_in[1];
  const float* W_in_H = (const float*)d_in[2];
  const float* W_in_V = (const float*)d_in[3];
  const float* W_out_HF = (const float*)d_in[4];
  const float* W_out_HB = (const float*)d_in[5];
  const float* W_out_VF = (const float*)d_in[6];
  const float* W_out_VB = (const float*)d_in[7];
  const float* W_out = (const float*)d_in[8];
  const float* dt_bias_HF = (const float*)d_in[9];
  const float* A_log_HF = (const float*)d_in[10];
  const float* D_HF = (const float*)d_in[11];
  const float* dt_bias_HB = (const float*)d_in[12];
  const float* A_log_HB = (const float*)d_in[13];
  const float* D_HB = (const float*)d_in[14];
  const float* dt_bias_VF = (const float*)d_in[15];
  const float* A_log_VF = (const float*)d_in[16];
  const float* D_VF = (const float*)d_in[17];
  const float* dt_bias_VB = (const float*)d_in[18];
  const float* A_log_VB = (const float*)d_in[19];
  const float* D_VB = (const float*)d_in[20];
  const int* v2h = (const int*)d_in[21];

  char* ws = (char*)d_ws;
  size_t off = 0;
  auto alloc = [&](size_t bytes) {
    void* pp = ws + off;
    off = (off + bytes + 255) & ~(size_t)255;
    return pp;
  };
  float* zx_H = (float*)alloc((size_t)ROWS * ZXLD * 4);
  float* zx_V = (float*)alloc((size_t)ROWS * ZXLD * 4);
  unsigned short* xbf_H = (unsigned short*)alloc((size_t)ROWS * 256 * 2);
  unsigned short* xbf_V = (unsigned short*)alloc((size_t)ROWS * 256 * 2);
  unsigned short* Wt_inH = (unsigned short*)alloc((size_t)ZXLD * 256 * 2);
  unsigned short* Wt_inV = (unsigned short*)alloc((size_t)ZXLD * 256 * 2);
  unsigned short* Wt_dirs = (unsigned short*)alloc((size_t)4 * 256 * 256 * 2);
  unsigned short* Wt_fin = (unsigned short*)alloc((size_t)256 * 1024 * 2);
  unsigned short* ybf = (unsigned short*)alloc((size_t)4 * ROWS * 256 * 2);
  unsigned short* ycatbf = (unsigned short*)alloc((size_t)ROWS * 1024 * 2);
  float* S = (float*)alloc((size_t)4 * NCHUNK * 8 * 64 * 8 * 4);
  float* P = (float*)alloc((size_t)4 * NCHUNK * 8 * 4);
  float* carry = (float*)alloc((size_t)4 * NCHUNK * 8 * 64 * 8 * 4);
  int* rowmap = (int*)alloc((size_t)ROWS * 4);

  // conversions
  k_cvt<<<2048, 256, 0, stream>>>(x_H, xbf_H, ROWS * 256);
  k_cvt<<<2048, 256, 0, stream>>>(x_V, xbf_V, ROWS * 256);
  k_cvtT<<<1088, 256, 0, stream>>>(W_in_H, Wt_inH, 256, 1064, ZXLD);
  k_cvtT<<<1088, 256, 0, stream>>>(W_in_V, Wt_inV, 256, 1064, ZXLD);
  // per-dir out weights in cat order: dir0 HF uses W_out_HB, dir1 HB uses W_out_HF,
  // dir2 VF uses W_out_VB, dir3 VB uses W_out_VF
  k_cvtT<<<256, 256, 0, stream>>>(W_out_HB, Wt_dirs + 0 * 65536, 256, 256, 256);
  k_cvtT<<<256, 256, 0, stream>>>(W_out_HF, Wt_dirs + 1 * 65536, 256, 256, 256);
  k_cvtT<<<256, 256, 0, stream>>>(W_out_VB, Wt_dirs + 2 * 65536, 256, 256, 256);
  k_cvtT<<<256, 256, 0, stream>>>(W_out_VF, Wt_dirs + 3 * 65536, 256, 256, 256);
  k_cvtT<<<1024, 256, 0, stream>>>(W_out, Wt_fin, 1024, 256, 256);
  k_rowmap<<<ROWS / 256, 256, 0, stream>>>(v2h, rowmap);

  // input GEMMs: zx = x @ W_in  (bf16 MFMA, fp32 out)
  k_gemm<0><<<dim3(ZXLD / 64, ROWS / 128), 256, 0, stream>>>(
      xbf_H, Wt_inH, zx_H, ROWS, ZXLD, 256, 256, 256, ZXLD, nullptr, 0);
  k_gemm<0><<<dim3(ZXLD / 64, ROWS / 128), 256, 0, stream>>>(
      xbf_V, Wt_inV, zx_V, ROWS, ZXLD, 256, 256, 256, ZXLD, nullptr, 0);
  // exact fp32 dt columns
  k_dtfix<<<(ROWS * 16) / 256, 256, 0, stream>>>(x_H, x_V, W_in_H, W_in_V, zx_H, zx_V);

  ScanParams sp;
  sp.zx[0] = zx_H; sp.zx[1] = zx_H; sp.zx[2] = zx_V; sp.zx[3] = zx_V;
  sp.slice[0] = 0; sp.slice[1] = SLICE_B; sp.slice[2] = 0; sp.slice[3] = SLICE_B;
  sp.rev[0] = 0; sp.rev[1] = 1; sp.rev[2] = 0; sp.rev[3] = 1;
  sp.dt_bias[0] = dt_bias_HF; sp.dt_bias[1] = dt_bias_HB;
  sp.dt_bias[2] = dt_bias_VF; sp.dt_bias[3] = dt_bias_VB;
  sp.A_log[0] = A_log_HF; sp.A_log[1] = A_log_HB;
  sp.A_log[2] = A_log_VF; sp.A_log[3] = A_log_VB;
  sp.D[0] = D_HF; sp.D[1] = D_HB; sp.D[2] = D_VF; sp.D[3] = D_VB;

  k_scan1<<<dim3(NCHUNK, 8, 4), 64, 0, stream>>>(sp, S, P);
  k_scan2<<<32, 64, 0, stream>>>(S, P, carry);
  k_scan3<<<dim3(NCHUNK, 8, 4), 64, 0, stream>>>(sp, carry, ybf);

  // out projections -> silu(bf16) into cat buffer (V dirs row-scattered via v2h)
  for (int d = 0; d < 4; ++d) {
    k_gemm<1><<<dim3(4, ROWS / 128), 256, 0, stream>>>(
        ybf + (size_t)d * ROWS * 256, Wt_dirs + (size_t)d * 65536, ycatbf,
        ROWS, 256, 256, 256, 256, 1024, (d >= 2) ? rowmap : nullptr, d * 256);
  }

  // final GEMM: out = silu(cat) @ W_out
  k_gemm<0><<<dim3(4, ROWS / 128), 256, 0, stream>>>(
      ycatbf, Wt_fin, d_out, ROWS, 256, 1024, 1024, 1024, 256, nullptr, 0);

  (void)in_sizes; (void)n_in; (void)out_size; (void)ws_size;
}

// Round 2
// 422.908 us; speedup vs baseline: 1.0118x; 1.0118x over previous
//
#include <hip/hip_runtime.h>
#include <hip/hip_bf16.h>

// ---------------- problem constants ----------------
#define B_N 2
#define L_N 8192
#define DM_N 256
#define NH_N 4
#define HP_N 64
#define NS_N 8
#define ROWS (B_N * L_N)          // 16384
#define DPROJ_N 532
#define ZXLD 1088                 // padded row stride of zx (1064 -> 1088, mult of 64)
#define SLICE_B 532
#define CHUNK 64
#define NCHUNK (L_N / CHUNK)      // 128

typedef __bf16 bf16x8 __attribute__((ext_vector_type(8)));
typedef float f32x4 __attribute__((ext_vector_type(4)));

__device__ __forceinline__ float siluf(float v) { return v / (1.f + __expf(-v)); }
__device__ __forceinline__ float softplusf_(float v) {
  return fmaxf(v, 0.f) + log1pf(__expf(-fabsf(v)));
}
__device__ __forceinline__ unsigned short f2bf(float v) {
  union { float f; unsigned u; } x; x.f = v;
  unsigned r = x.u + 0x7fffu + ((x.u >> 16) & 1u);
  return (unsigned short)(r >> 16);
}

// ---------------- conversion kernels ----------------
__global__ void k_cvt(const float* __restrict__ src, unsigned short* __restrict__ dst, int n) {
  int i = blockIdx.x * blockDim.x + threadIdx.x;
  int stride = gridDim.x * blockDim.x;
  for (; i < n; i += stride) dst[i] = f2bf(src[i]);
}

// dst[n*K + k] = bf16(src[k*N + n]); rows n in [N, Npad) zero-padded
__global__ void k_cvtT(const float* __restrict__ src, unsigned short* __restrict__ dst,
                       int K, int N, int Npad) {
  int i = blockIdx.x * blockDim.x + threadIdx.x;
  int total = K * Npad;
  int stride = gridDim.x * blockDim.x;
  for (; i < total; i += stride) {
    int k = i / Npad, n = i - k * Npad;
    float v = (n < N) ? src[(long)k * N + n] : 0.f;
    dst[(long)n * K + k] = f2bf(v);
  }
}

__global__ void k_rowmap(const int* __restrict__ v2h, int* __restrict__ rowmap) {
  int m = blockIdx.x * blockDim.x + threadIdx.x;
  if (m < ROWS) {
    int b = m >> 13;
    rowmap[m] = b * L_N + v2h[m];
  }
}

// exact fp32 recompute of the 4 dt columns of each 532-slice (both mats, both slices)
__global__ void k_dtfix(const float* __restrict__ xH, const float* __restrict__ xV,
                        const float* __restrict__ WH, const float* __restrict__ WV,
                        float* __restrict__ zxH, float* __restrict__ zxV) {
  int idx = blockIdx.x * blockDim.x + threadIdx.x;   // ROWS*16
  int row = idx >> 4;
  int c = idx & 15;
  int mat = c >> 3, sl = (c >> 2) & 1, hc = c & 3;
  const float* x = (mat ? xV : xH) + (long)row * DM_N;
  const float* W = (mat ? WV : WH);
  int wcol = sl * 532 + 528 + hc;
  float s = 0.f;
  #pragma unroll 8
  for (int k = 0; k < DM_N; ++k) s = fmaf(x[k], W[(long)k * 1064 + wcol], s);
  float* zx = (mat ? zxV : zxH);
  zx[(long)row * ZXLD + sl * 532 + 528 + hc] = s;
}

// ---------------- bf16 MFMA GEMM ----------------
// C(MxN) = A(MxK) * B(KxN), A row-major bf16 (lda), B supplied TRANSPOSED: Bt[n][k] (ldb)
// MODE 0: C float, plain store. MODE 1: C bf16, silu applied.
template <int MODE>
__global__ __launch_bounds__(256) void k_gemm(
    const unsigned short* __restrict__ A, const unsigned short* __restrict__ Bt,
    void* __restrict__ Cv, int M, int N, int K, int lda, int ldb, int ldc,
    const int* __restrict__ rowmap, int col_off) {
  __shared__ unsigned short As[128][56];
  __shared__ unsigned short Bs[64][56];
  const int tid = threadIdx.x;
  const int lane = tid & 63;
  const int wid = tid >> 6;
  const int wm = wid & 1, wn = wid >> 1;
  const int q = lane >> 4, r = lane & 15;
  const int m0 = blockIdx.y * 128;
  const int n0 = blockIdx.x * 64;

  f32x4 acc[4][2] = {};

  for (int kt = 0; kt < K; kt += 32) {
    #pragma unroll
    for (int i = 0; i < 2; ++i) {
      int chunk = tid + i * 256;
      int row = chunk >> 2, c = (chunk & 3) * 8;
      uint4 v = *(const uint4*)(A + (long)(m0 + row) * lda + kt + c);
      *(uint4*)&As[row][c] = v;
    }
    {
      int row = tid >> 2, c = (tid & 3) * 8;
      uint4 v = *(const uint4*)(Bt + (long)(n0 + row) * ldb + kt + c);
      *(uint4*)&Bs[row][c] = v;
    }
    __syncthreads();
    bf16x8 af[4], bfr[2];
    #pragma unroll
    for (int mi = 0; mi < 4; ++mi)
      af[mi] = *(const bf16x8*)&As[wm * 64 + mi * 16 + r][q * 8];
    #pragma unroll
    for (int ni = 0; ni < 2; ++ni)
      bfr[ni] = *(const bf16x8*)&Bs[wn * 32 + ni * 16 + r][q * 8];
    #pragma unroll
    for (int mi = 0; mi < 4; ++mi)
      #pragma unroll
      for (int ni = 0; ni < 2; ++ni)
        acc[mi][ni] = __builtin_amdgcn_mfma_f32_16x16x32_bf16(af[mi], bfr[ni], acc[mi][ni], 0, 0, 0);
    __syncthreads();
  }

  #pragma unroll
  for (int mi = 0; mi < 4; ++mi) {
    #pragma unroll
    for (int ni = 0; ni < 2; ++ni) {
      #pragma unroll
      for (int j = 0; j < 4; ++j) {
        int row = m0 + wm * 64 + mi * 16 + q * 4 + j;
        int col = n0 + wn * 32 + ni * 16 + r;
        int orow = rowmap ? rowmap[row] : row;
        float v = acc[mi][ni][j];
        if (MODE == 0) {
          ((float*)Cv)[(long)orow * ldc + col + col_off] = v;
        } else {
          ((unsigned short*)Cv)[(long)orow * ldc + col + col_off] = f2bf(siluf(v));
        }
      }
    }
  }
}

// ---------------- scan kernels ----------------
struct ScanParams {
  const float* zx[4];
  const float* dt_bias[4];
  const float* A_log[4];
  const float* D[4];
  int slice[4];
  int rev[4];
};

// phase 1: per-chunk (64 steps) local scan from zero; write end-state S and cum-dA P
__global__ __launch_bounds__(64) void k_scan1(ScanParams sp, float* __restrict__ S,
                                              float* __restrict__ P) {
  __shared__ float Bst[64][8];
  __shared__ float dAs[64];
  const int p = threadIdx.x;
  const int c = blockIdx.x;
  const int bh = blockIdx.y;
  const int d = blockIdx.z;
  const int b = bh >> 2, h = bh & 3;
  const float* zx = sp.zx[d];
  const int slice = sp.slice[d];
  const int rev = sp.rev[d];
  const float A_h = -__expf(sp.A_log[d][h]);
  const float dtb = sp.dt_bias[d][h];

  const int t0 = c * CHUNK;
  {
    const int t = t0 + p;
    const int l = rev ? (L_N - 1 - t) : t;
    const float* rp = zx + (long)((b << 13) + l) * ZXLD + slice;
    float4 b0 = *(const float4*)(rp + 512);
    float4 b1 = *(const float4*)(rp + 516);
    float dtv = softplusf_(rp[528 + h] + dtb);
    dAs[p] = __expf(dtv * A_h);
    Bst[p][0] = siluf(b0.x) * dtv;
    Bst[p][1] = siluf(b0.y) * dtv;
    Bst[p][2] = siluf(b0.z) * dtv;
    Bst[p][3] = siluf(b0.w) * dtv;
    Bst[p][4] = siluf(b1.x) * dtv;
    Bst[p][5] = siluf(b1.y) * dtv;
    Bst[p][6] = siluf(b1.z) * dtv;
    Bst[p][7] = siluf(b1.w) * dtv;
  }
  __syncthreads();

  float st[8] = {0, 0, 0, 0, 0, 0, 0, 0};
  float cumdA = 1.f;
  const int l0 = rev ? (L_N - 1 - t0) : t0;
  const float* xp = zx + (long)((b << 13) + l0) * ZXLD + slice + 256 + h * 64 + p;
  const long stp = rev ? -(long)ZXLD : (long)ZXLD;

  #pragma unroll 8
  for (int s = 0; s < 64; ++s) {
    float x = siluf(xp[(long)s * stp]);
    float dA = dAs[s];
    float4 B0 = *(const float4*)&Bst[s][0];
    float4 B1 = *(const float4*)&Bst[s][4];
    cumdA *= dA;
    st[0] = fmaf(dA, st[0], x * B0.x);
    st[1] = fmaf(dA, st[1], x * B0.y);
    st[2] = fmaf(dA, st[2], x * B0.z);
    st[3] = fmaf(dA, st[3], x * B0.w);
    st[4] = fmaf(dA, st[4], x * B1.x);
    st[5] = fmaf(dA, st[5], x * B1.y);
    st[6] = fmaf(dA, st[6], x * B1.z);
    st[7] = fmaf(dA, st[7], x * B1.w);
  }
  float* Sp = S + ((((long)d * NCHUNK + c) * 8 + bh) * 64 + p) * 8;
  #pragma unroll
  for (int n = 0; n < 8; ++n) Sp[n] = st[n];
  if (p == 0) P[((long)d * NCHUNK + c) * 8 + bh] = cumdA;
}

// phase 2: sequential chunk-level combine -> carry-in per chunk.
// 512 threads: one per (p,n) state element; 1 fma per chunk step.
__global__ __launch_bounds__(512) void k_scan2(const float* __restrict__ S,
                                               const float* __restrict__ P,
                                               float* __restrict__ carry) {
  const int tid = threadIdx.x;          // 512 = 64p x 8n
  const int dbh = blockIdx.x;
  const int d = dbh >> 3, bh = dbh & 7;
  float cy = 0.f;
  carry[(((long)d * NCHUNK + 0) * 8 + bh) * 512 + tid] = 0.f;
  #pragma unroll 4
  for (int c = 1; c < NCHUNK; ++c) {
    const float Pv = P[((long)d * NCHUNK + (c - 1)) * 8 + bh];
    const float Sv = S[(((long)d * NCHUNK + (c - 1)) * 8 + bh) * 512 + tid];
    cy = fmaf(Pv, cy, Sv);
    carry[(((long)d * NCHUNK + c) * 8 + bh) * 512 + tid] = cy;
  }
}

// phase 3: re-scan with carry-in, produce gated y in bf16
__global__ __launch_bounds__(64) void k_scan3(ScanParams sp, const float* __restrict__ carry,
                                              unsigned short* __restrict__ ybf) {
  __shared__ float Bst[64][8];
  __shared__ float Cst[64][8];
  __shared__ float dAs[64];
  const int p = threadIdx.x;
  const int c = blockIdx.x;
  const int bh = blockIdx.y;
  const int d = blockIdx.z;
  const int b = bh >> 2, h = bh & 3;
  const float* zx = sp.zx[d];
  const int slice = sp.slice[d];
  const int rev = sp.rev[d];
  const float A_h = -__expf(sp.A_log[d][h]);
  const float dtb = sp.dt_bias[d][h];
  const float Dv = sp.D[d][h];

  const int t0 = c * CHUNK;
  {
    const int t = t0 + p;
    const int l = rev ? (L_N - 1 - t) : t;
    const float* rp = zx + (long)((b << 13) + l) * ZXLD + slice;
    float4 b0 = *(const float4*)(rp + 512);
    float4 b1 = *(const float4*)(rp + 516);
    float4 c0 = *(const float4*)(rp + 520);
    float4 c1 = *(const float4*)(rp + 524);
    float dtv = softplusf_(rp[528 + h] + dtb);
    dAs[p] = __expf(dtv * A_h);
    Bst[p][0] = siluf(b0.x) * dtv;
    Bst[p][1] = siluf(b0.y) * dtv;
    Bst[p][2] = siluf(b0.z) * dtv;
    Bst[p][3] = siluf(b0.w) * dtv;
    Bst[p][4] = siluf(b1.x) * dtv;
    Bst[p][5] = siluf(b1.y) * dtv;
    Bst[p][6] = siluf(b1.z) * dtv;
    Bst[p][7] = siluf(b1.w) * dtv;
    Cst[p][0] = siluf(c0.x);
    Cst[p][1] = siluf(c0.y);
    Cst[p][2] = siluf(c0.z);
    Cst[p][3] = siluf(c0.w);
    Cst[p][4] = siluf(c1.x);
    Cst[p][5] = siluf(c1.y);
    Cst[p][6] = siluf(c1.z);
    Cst[p][7] = siluf(c1.w);
  }
  __syncthreads();

  float st[8];
  {
    const float* cp = carry + ((((long)d * NCHUNK + c) * 8 + bh) * 64 + p) * 8;
    #pragma unroll
    for (int n = 0; n < 8; ++n) st[n] = cp[n];
  }

  const int l0 = rev ? (L_N - 1 - t0) : t0;
  const float* xp = zx + (long)((b << 13) + l0) * ZXLD + slice + 256 + h * 64 + p;
  const float* zp = zx + (long)((b << 13) + l0) * ZXLD + slice + h * 64 + p;
  unsigned short* yp = ybf + ((long)d * ROWS + (b << 13) + l0) * 256 + h * 64 + p;
  const long stp = rev ? -(long)ZXLD : (long)ZXLD;
  const long ystp = rev ? -256L : 256L;

  #pragma unroll 8
  for (int s = 0; s < 64; ++s) {
    float x = siluf(xp[(long)s * stp]);
    float z = siluf(zp[(long)s * stp]);
    float dA = dAs[s];
    float4 B0 = *(const float4*)&Bst[s][0];
    float4 B1 = *(const float4*)&Bst[s][4];
    float4 C0 = *(const float4*)&Cst[s][0];
    float4 C1 = *(const float4*)&Cst[s][4];
    st[0] = fmaf(dA, st[0], x * B0.x);
    st[1] = fmaf(dA, st[1], x * B0.y);
    st[2] = fmaf(dA, st[2], x * B0.z);
    st[3] = fmaf(dA, st[3], x * B0.w);
    st[4] = fmaf(dA, st[4], x * B1.x);
    st[5] = fmaf(dA, st[5], x * B1.y);
    st[6] = fmaf(dA, st[6], x * B1.z);
    st[7] = fmaf(dA, st[7], x * B1.w);
    float y01 = fmaf(st[1], C0.y, st[0] * C0.x);
    float y23 = fmaf(st[3], C0.w, st[2] * C0.z);
    float y45 = fmaf(st[5], C1.y, st[4] * C1.x);
    float y67 = fmaf(st[7], C1.w, st[6] * C1.z);
    float y = (y01 + y23) + (y45 + y67);
    y = (fmaf(Dv, x, y)) * z;
    yp[(long)s * ystp] = f2bf(y);
  }
}

// ---------------- launch ----------------
extern "C" void kernel_launch(void* const* d_in, const int* in_sizes, int n_in,
                              void* d_out, int out_size, void* d_ws, size_t ws_size,
                              hipStream_t stream) {
  const float* x_H = (const float*)d_in[0];
  const float* x_V = (const float*)d_in[1];
  const float* W_in_H = (const float*)d_in[2];
  const float* W_in_V = (const float*)d_in[3];
  const float* W_out_HF = (const float*)d_in[4];
  const float* W_out_HB = (const float*)d_in[5];
  const float* W_out_VF = (const float*)d_in[6];
  const float* W_out_VB = (const float*)d_in[7];
  const float* W_out = (const float*)d_in[8];
  const float* dt_bias_HF = (const float*)d_in[9];
  const float* A_log_HF = (const float*)d_in[10];
  const float* D_HF = (const float*)d_in[11];
  const float* dt_bias_HB = (const float*)d_in[12];
  const float* A_log_HB = (const float*)d_in[13];
  const float* D_HB = (const float*)d_in[14];
  const float* dt_bias_VF = (const float*)d_in[15];
  const float* A_log_VF = (const float*)d_in[16];
  const float* D_VF = (const float*)d_in[17];
  const float* dt_bias_VB = (const float*)d_in[18];
  const float* A_log_VB = (const float*)d_in[19];
  const float* D_VB = (const float*)d_in[20];
  const int* v2h = (const int*)d_in[21];

  char* ws = (char*)d_ws;
  size_t off = 0;
  auto alloc = [&](size_t bytes) {
    void* pp = ws + off;
    off = (off + bytes + 255) & ~(size_t)255;
    return pp;
  };
  float* zx_H = (float*)alloc((size_t)ROWS * ZXLD * 4);
  float* zx_V = (float*)alloc((size_t)ROWS * ZXLD * 4);
  unsigned short* xbf_H = (unsigned short*)alloc((size_t)ROWS * 256 * 2);
  unsigned short* xbf_V = (unsigned short*)alloc((size_t)ROWS * 256 * 2);
  unsigned short* Wt_inH = (unsigned short*)alloc((size_t)ZXLD * 256 * 2);
  unsigned short* Wt_inV = (unsigned short*)alloc((size_t)ZXLD * 256 * 2);
  unsigned short* Wt_dirs = (unsigned short*)alloc((size_t)4 * 256 * 256 * 2);
  unsigned short* Wt_fin = (unsigned short*)alloc((size_t)256 * 1024 * 2);
  unsigned short* ybf = (unsigned short*)alloc((size_t)4 * ROWS * 256 * 2);
  unsigned short* ycatbf = (unsigned short*)alloc((size_t)ROWS * 1024 * 2);
  float* S = (float*)alloc((size_t)4 * NCHUNK * 8 * 64 * 8 * 4);
  float* P = (float*)alloc((size_t)4 * NCHUNK * 8 * 4);
  float* carry = (float*)alloc((size_t)4 * NCHUNK * 8 * 64 * 8 * 4);
  int* rowmap = (int*)alloc((size_t)ROWS * 4);

  // conversions
  k_cvt<<<2048, 256, 0, stream>>>(x_H, xbf_H, ROWS * 256);
  k_cvt<<<2048, 256, 0, stream>>>(x_V, xbf_V, ROWS * 256);
  k_cvtT<<<1088, 256, 0, stream>>>(W_in_H, Wt_inH, 256, 1064, ZXLD);
  k_cvtT<<<1088, 256, 0, stream>>>(W_in_V, Wt_inV, 256, 1064, ZXLD);
  // per-dir out weights in cat order: dir0 HF uses W_out_HB, dir1 HB uses W_out_HF,
  // dir2 VF uses W_out_VB, dir3 VB uses W_out_VF
  k_cvtT<<<256, 256, 0, stream>>>(W_out_HB, Wt_dirs + 0 * 65536, 256, 256, 256);
  k_cvtT<<<256, 256, 0, stream>>>(W_out_HF, Wt_dirs + 1 * 65536, 256, 256, 256);
  k_cvtT<<<256, 256, 0, stream>>>(W_out_VB, Wt_dirs + 2 * 65536, 256, 256, 256);
  k_cvtT<<<256, 256, 0, stream>>>(W_out_VF, Wt_dirs + 3 * 65536, 256, 256, 256);
  k_cvtT<<<1024, 256, 0, stream>>>(W_out, Wt_fin, 1024, 256, 256);
  k_rowmap<<<ROWS / 256, 256, 0, stream>>>(v2h, rowmap);

  // input GEMMs: zx = x @ W_in  (bf16 MFMA, fp32 out)
  k_gemm<0><<<dim3(ZXLD / 64, ROWS / 128), 256, 0, stream>>>(
      xbf_H, Wt_inH, zx_H, ROWS, ZXLD, 256, 256, 256, ZXLD, nullptr, 0);
  k_gemm<0><<<dim3(ZXLD / 64, ROWS / 128), 256, 0, stream>>>(
      xbf_V, Wt_inV, zx_V, ROWS, ZXLD, 256, 256, 256, ZXLD, nullptr, 0);
  // exact fp32 dt columns
  k_dtfix<<<(ROWS * 16) / 256, 256, 0, stream>>>(x_H, x_V, W_in_H, W_in_V, zx_H, zx_V);

  ScanParams sp;
  sp.zx[0] = zx_H; sp.zx[1] = zx_H; sp.zx[2] = zx_V; sp.zx[3] = zx_V;
  sp.slice[0] = 0; sp.slice[1] = SLICE_B; sp.slice[2] = 0; sp.slice[3] = SLICE_B;
  sp.rev[0] = 0; sp.rev[1] = 1; sp.rev[2] = 0; sp.rev[3] = 1;
  sp.dt_bias[0] = dt_bias_HF; sp.dt_bias[1] = dt_bias_HB;
  sp.dt_bias[2] = dt_bias_VF; sp.dt_bias[3] = dt_bias_VB;
  sp.A_log[0] = A_log_HF; sp.A_log[1] = A_log_HB;
  sp.A_log[2] = A_log_VF; sp.A_log[3] = A_log_VB;
  sp.D[0] = D_HF; sp.D[1] = D_HB; sp.D[2] = D_VF; sp.D[3] = D_VB;

  k_scan1<<<dim3(NCHUNK, 8, 4), 64, 0, stream>>>(sp, S, P);
  k_scan2<<<32, 512, 0, stream>>>(S, P, carry);
  k_scan3<<<dim3(NCHUNK, 8, 4), 64, 0, stream>>>(sp, carry, ybf);

  // out projections -> silu(bf16) into cat buffer (V dirs row-scattered via v2h)
  for (int d = 0; d < 4; ++d) {
    k_gemm<1><<<dim3(4, ROWS / 128), 256, 0, stream>>>(
        ybf + (size_t)d * ROWS * 256, Wt_dirs + (size_t)d * 65536, ycatbf,
        ROWS, 256, 256, 256, 256, 1024, (d >= 2) ? rowmap : nullptr, d * 256);
  }

  // final GEMM: out = silu(cat) @ W_out
  k_gemm<0><<<dim3(4, ROWS / 128), 256, 0, stream>>>(
      ycatbf, Wt_fin, d_out, ROWS, 256, 1024, 1024, 1024, 256, nullptr, 0);

  (void)in_sizes; (void)n_in; (void)out_size; (void)ws_size;
}

// Round 3
// 380.919 us; speedup vs baseline: 1.1234x; 1.1102x over previous
//
#include <hip/hip_runtime.h>
#include <hip/hip_bf16.h>

// ---------------- problem constants ----------------
#define B_N 2
#define L_N 8192
#define ROWS 16384                // B_N * L_N
#define CHUNK 64
#define NCHUNK 128                // L_N / CHUNK
#define NPAD 1152                 // input-proj N padded: 2 x 544 + pad to 9*128

typedef __bf16 bf16x8 __attribute__((ext_vector_type(8)));
typedef float f32x4 __attribute__((ext_vector_type(4)));

__device__ __forceinline__ float siluf(float v) { return v / (1.f + __expf(-v)); }
__device__ __forceinline__ float softplusf_(float v) {
  return fmaxf(v, 0.f) + log1pf(__expf(-fabsf(v)));
}
__device__ __forceinline__ unsigned short f2bf(float v) {
  union { float f; unsigned u; } x; x.f = v;
  unsigned r = x.u + 0x7fffu + ((x.u >> 16) & 1u);
  return (unsigned short)(r >> 16);
}
__device__ __forceinline__ float bf2f(unsigned short u) {
  union { unsigned u; float f; } x; x.u = ((unsigned)u) << 16;
  return x.f;
}

// async global->LDS, 16B per lane, LDS dest = wave-uniform base + lane*16
__device__ __forceinline__ void gload_lds16(const unsigned short* g, unsigned short* l) {
  __builtin_amdgcn_global_load_lds(
      (const __attribute__((address_space(1))) unsigned int*)g,
      (__attribute__((address_space(3))) unsigned int*)l, 16, 0, 0);
}

// ---------------- conversion kernels ----------------
// x (fp32) -> bf16, vectorized
__global__ void k_cvt2(const float* __restrict__ xH, const float* __restrict__ xV,
                       unsigned short* __restrict__ dst /* [2][ROWS*256] */) {
  int i = blockIdx.x * 256 + threadIdx.x;     // per float4
  const float* s = blockIdx.y ? xV : xH;
  unsigned short* d = dst + (size_t)blockIdx.y * ROWS * 256;
  float4 v = ((const float4*)s)[i];
  ushort4 o;
  o.x = f2bf(v.x); o.y = f2bf(v.y); o.z = f2bf(v.z); o.w = f2bf(v.w);
  ((ushort4*)d)[i] = o;
}

// W_in (256 x 1064) -> Wt[z][n][k], n in [0,1152): slice0 at [0,532), slice1 at [544,1076), pads zero
__global__ void k_cvtT_in(const float* __restrict__ WH, const float* __restrict__ WV,
                          unsigned short* __restrict__ dst) {
  int i = blockIdx.x * 256 + threadIdx.x;     // 2*1152*256
  int z = i / (NPAD * 256);
  int rem = i - z * (NPAD * 256);
  int n = rem >> 8, k = rem & 255;
  const float* W = z ? WV : WH;
  int sl = n >= 544;
  int cc = n - (sl ? 544 : 0);
  float v = (cc < 532) ? W[(long)k * 1064 + sl * 532 + cc] : 0.f;
  dst[i] = f2bf(v);
}

struct P4 { const float* p[4]; };
// 4 dir out-weights (256x256) -> Wt[d][n][k]
__global__ void k_cvtT_dirs(P4 ws, unsigned short* __restrict__ dst) {
  int i = blockIdx.x * 256 + threadIdx.x;     // 4*65536
  int d = i >> 16;
  int rem = i & 65535;
  int n = rem >> 8, k = rem & 255;
  dst[i] = f2bf(ws.p[d][(long)k * 256 + n]);
}

// W_out (1024x256) -> Wt[n][k] n<256,k<1024
__global__ void k_cvtT_fin(const float* __restrict__ W, unsigned short* __restrict__ dst) {
  int i = blockIdx.x * 256 + threadIdx.x;     // 256*1024, i = n*1024+k
  int n = i >> 10, k = i & 1023;
  dst[i] = f2bf(W[(long)k * 256 + n]);
}

__global__ void k_rowmap(const int* __restrict__ v2h, int* __restrict__ rowmap) {
  int m = blockIdx.x * blockDim.x + threadIdx.x;
  if (m < ROWS) {
    int b = m >> 13;
    rowmap[m] = b * L_N + v2h[m];
  }
}

struct ScanConsts {
  const float* dt_bias[4];
  const float* A_log[4];
  const float* D[4];
};

// exact fp32 dt dot; precompute dtv (softplus) and dA (exp(dt*A)) per (dir,h,row)
__global__ void k_dtfix(const float* __restrict__ xH, const float* __restrict__ xV,
                        const float* __restrict__ WH, const float* __restrict__ WV,
                        ScanConsts sc, float* __restrict__ dtv_arr, float* __restrict__ dA_arr) {
  int idx = blockIdx.x * 256 + threadIdx.x;   // ROWS*16
  int row = idx >> 4;
  int c = idx & 15;
  int mat = c >> 3, sl = (c >> 2) & 1, h = c & 3;
  int dir = mat * 2 + sl;
  const float* x = (mat ? xV : xH) + (long)row * 256;
  const float* W = mat ? WV : WH;
  int wcol = sl * 532 + 528 + h;
  float s = 0.f;
  #pragma unroll 8
  for (int k = 0; k < 256; ++k) s = fmaf(x[k], W[(long)k * 1064 + wcol], s);
  float dtv = softplusf_(s + sc.dt_bias[dir][h]);
  float dAv = __expf(dtv * (-__expf(sc.A_log[dir][h])));
  long o = ((long)dir * 4 + h) * ROWS + row;
  dtv_arr[o] = dtv;
  dA_arr[o] = dAv;
}

// ---------------- bf16 MFMA GEMM (128x128 tile, async LDS staging) ----------------
struct EpiIn {
  unsigned short* zsil;   // [4][ROWS*256] silu(z)
  unsigned short* xsil;   // [4][ROWS*256] silu(x)
  unsigned short* bc;     // [4][ROWS*16]  silu(B)|silu(C)
};

// A row-major bf16 (lda=K), Bt row-major [n][k] bf16 (ldb=K). 128x128 tile, BK=32.
// MODE 0: fp32 store. MODE 1: out-proj (silu->bf16, col_off=z*256, rowmap for z>=2).
// MODE 2: input-proj routing epilogue.
template <int MODE>
__global__ __launch_bounds__(256) void k_gemm2(
    const unsigned short* __restrict__ Abase, long Astride,
    const unsigned short* __restrict__ Btbase, long Btstride,
    void* __restrict__ Cv, int K, int ldc,
    const int* __restrict__ rowmap, EpiIn ep) {
  __shared__ unsigned short As[128 * 32];
  __shared__ unsigned short Bs[128 * 32];
  const int tid = threadIdx.x;
  const int lane = tid & 63;
  const int wid = tid >> 6;
  const int wm = wid & 1, wn = wid >> 1;
  const int q = lane >> 4, r = lane & 15;
  const int m0 = blockIdx.y * 128;
  const int n0 = blockIdx.x * 128;
  const int z = blockIdx.z;
  const unsigned short* A = Abase + (long)z * Astride;
  const unsigned short* Bt = Btbase + (long)z * Btstride;

  f32x4 acc[4][4] = {};

  for (int kt = 0; kt < K; kt += 32) {
    #pragma unroll
    for (int i = 0; i < 2; ++i) {
      int idx = i * 256 + tid;
      gload_lds16(A + (long)(m0 + (idx >> 2)) * K + kt + (idx & 3) * 8,
                  &As[(size_t)(i * 256 + wid * 64) * 8]);
    }
    #pragma unroll
    for (int i = 0; i < 2; ++i) {
      int idx = i * 256 + tid;
      gload_lds16(Bt + (long)(n0 + (idx >> 2)) * K + kt + (idx & 3) * 8,
                  &Bs[(size_t)(i * 256 + wid * 64) * 8]);
    }
    __syncthreads();
    bf16x8 af[4], bfr[4];
    #pragma unroll
    for (int mi = 0; mi < 4; ++mi)
      af[mi] = *(const bf16x8*)&As[(wm * 64 + mi * 16 + r) * 32 + q * 8];
    #pragma unroll
    for (int ni = 0; ni < 4; ++ni)
      bfr[ni] = *(const bf16x8*)&Bs[(wn * 64 + ni * 16 + r) * 32 + q * 8];
    #pragma unroll
    for (int mi = 0; mi < 4; ++mi)
      #pragma unroll
      for (int ni = 0; ni < 4; ++ni)
        acc[mi][ni] = __builtin_amdgcn_mfma_f32_16x16x32_bf16(af[mi], bfr[ni], acc[mi][ni], 0, 0, 0);
    __syncthreads();
  }

  #pragma unroll
  for (int mi = 0; mi < 4; ++mi) {
    #pragma unroll
    for (int ni = 0; ni < 4; ++ni) {
      #pragma unroll
      for (int j = 0; j < 4; ++j) {
        int row = m0 + wm * 64 + mi * 16 + q * 4 + j;
        int col = n0 + wn * 64 + ni * 16 + r;
        float v = acc[mi][ni][j];
        if (MODE == 0) {
          ((float*)Cv)[(long)row * ldc + col] = v;
        } else if (MODE == 1) {
          int orow = (z >= 2) ? rowmap[row] : row;
          ((unsigned short*)Cv)[(long)orow * ldc + z * 256 + col] = f2bf(siluf(v));
        } else {
          int sl = col >= 544;
          int cc = col - (sl ? 544 : 0);
          if (cc < 532) {
            int dir = z * 2 + sl;
            unsigned short o = f2bf(siluf(v));
            if (cc < 256)
              ep.zsil[((long)dir * ROWS + row) * 256 + cc] = o;
            else if (cc < 512)
              ep.xsil[((long)dir * ROWS + row) * 256 + cc - 256] = o;
            else if (cc < 528)
              ep.bc[((long)dir * ROWS + row) * 16 + cc - 512] = o;
            // cc in [528,532): dt columns, handled exactly by k_dtfix
          }
        }
      }
    }
  }
}

// ---------------- scan kernels ----------------
struct ScanP {
  const unsigned short* xsil;  // [4][ROWS*256]
  const unsigned short* zsil;
  const unsigned short* bc;    // [4][ROWS*16]
  const float* dtv;            // [16][ROWS]  (dir*4+h)
  const float* dA;
  const float* D[4];
};

// phase 1: per-chunk (64 steps) local scan from zero; write end-state S and cum-dA P
__global__ __launch_bounds__(64) void k_scan1(ScanP sp, float* __restrict__ S,
                                              float* __restrict__ P) {
  __shared__ __align__(16) float Bst[64][8];
  __shared__ float dAs[64];
  const int p = threadIdx.x;
  const int c = blockIdx.x;
  const int bh = blockIdx.y;
  const int d = blockIdx.z;
  const int b = bh >> 2, h = bh & 3;
  const int rev = d & 1;
  const int t0 = c * CHUNK;
  {
    const int t = t0 + p;
    const int l = rev ? (L_N - 1 - t) : t;
    const int row = (b << 13) + l;
    uint4 bv = *(const uint4*)(sp.bc + ((long)d * ROWS + row) * 16);
    const unsigned short* bu = (const unsigned short*)&bv;
    float dtvv = sp.dtv[((long)d * 4 + h) * ROWS + row];
    dAs[p] = sp.dA[((long)d * 4 + h) * ROWS + row];
    #pragma unroll
    for (int n = 0; n < 8; ++n) Bst[p][n] = bf2f(bu[n]) * dtvv;
  }
  __syncthreads();

  float st[8] = {0, 0, 0, 0, 0, 0, 0, 0};
  float cumdA = 1.f;
  const int l0 = rev ? (L_N - 1 - t0) : t0;
  const unsigned short* xp = sp.xsil + ((long)d * ROWS + (b << 13) + l0) * 256 + h * 64 + p;
  const long stp = rev ? -256L : 256L;

  #pragma unroll 8
  for (int s = 0; s < 64; ++s) {
    float x = bf2f(xp[(long)s * stp]);
    float dA = dAs[s];
    f32x4 B0 = *(const f32x4*)&Bst[s][0];
    f32x4 B1 = *(const f32x4*)&Bst[s][4];
    cumdA *= dA;
    st[0] = fmaf(dA, st[0], x * B0[0]);
    st[1] = fmaf(dA, st[1], x * B0[1]);
    st[2] = fmaf(dA, st[2], x * B0[2]);
    st[3] = fmaf(dA, st[3], x * B0[3]);
    st[4] = fmaf(dA, st[4], x * B1[0]);
    st[5] = fmaf(dA, st[5], x * B1[1]);
    st[6] = fmaf(dA, st[6], x * B1[2]);
    st[7] = fmaf(dA, st[7], x * B1[3]);
  }
  float* Sp = S + ((((long)d * NCHUNK + c) * 8 + bh) * 64 + p) * 8;
  #pragma unroll
  for (int n = 0; n < 8; ++n) Sp[n] = st[n];
  if (p == 0) P[((long)d * NCHUNK + c) * 8 + bh] = cumdA;
}

// phase 2: sequential chunk-level combine -> carry-in per chunk
__global__ __launch_bounds__(512) void k_scan2(const float* __restrict__ S,
                                               const float* __restrict__ P,
                                               float* __restrict__ carry) {
  const int tid = threadIdx.x;
  const int dbh = blockIdx.x;
  const int d = dbh >> 3, bh = dbh & 7;
  float cy = 0.f;
  carry[(((long)d * NCHUNK + 0) * 8 + bh) * 512 + tid] = 0.f;
  #pragma unroll 4
  for (int c = 1; c < NCHUNK; ++c) {
    const float Pv = P[((long)d * NCHUNK + (c - 1)) * 8 + bh];
    const float Sv = S[(((long)d * NCHUNK + (c - 1)) * 8 + bh) * 512 + tid];
    cy = fmaf(Pv, cy, Sv);
    carry[(((long)d * NCHUNK + c) * 8 + bh) * 512 + tid] = cy;
  }
}

// phase 3: re-scan with carry-in, produce gated y in bf16
__global__ __launch_bounds__(64) void k_scan3(ScanP sp, const float* __restrict__ carry,
                                              unsigned short* __restrict__ ybf) {
  __shared__ __align__(16) float Bst[64][8];
  __shared__ __align__(16) float Cst[64][8];
  __shared__ float dAs[64];
  const int p = threadIdx.x;
  const int c = blockIdx.x;
  const int bh = blockIdx.y;
  const int d = blockIdx.z;
  const int b = bh >> 2, h = bh & 3;
  const int rev = d & 1;
  const float Dv = sp.D[d][h];
  const int t0 = c * CHUNK;
  {
    const int t = t0 + p;
    const int l = rev ? (L_N - 1 - t) : t;
    const int row = (b << 13) + l;
    const unsigned short* bp = sp.bc + ((long)d * ROWS + row) * 16;
    uint4 bv = *(const uint4*)bp;
    uint4 cv = *(const uint4*)(bp + 8);
    const unsigned short* bu = (const unsigned short*)&bv;
    const unsigned short* cu = (const unsigned short*)&cv;
    float dtvv = sp.dtv[((long)d * 4 + h) * ROWS + row];
    dAs[p] = sp.dA[((long)d * 4 + h) * ROWS + row];
    #pragma unroll
    for (int n = 0; n < 8; ++n) Bst[p][n] = bf2f(bu[n]) * dtvv;
    #pragma unroll
    for (int n = 0; n < 8; ++n) Cst[p][n] = bf2f(cu[n]);
  }
  __syncthreads();

  float st[8];
  {
    const float* cp = carry + ((((long)d * NCHUNK + c) * 8 + bh) * 64 + p) * 8;
    #pragma unroll
    for (int n = 0; n < 8; ++n) st[n] = cp[n];
  }

  const int l0 = rev ? (L_N - 1 - t0) : t0;
  const long base = (long)(b << 13) + l0;
  const unsigned short* xp = sp.xsil + ((long)d * ROWS + base) * 256 + h * 64 + p;
  const unsigned short* zp = sp.zsil + ((long)d * ROWS + base) * 256 + h * 64 + p;
  unsigned short* yp = ybf + ((long)d * ROWS + base) * 256 + h * 64 + p;
  const long stp = rev ? -256L : 256L;

  #pragma unroll 8
  for (int s = 0; s < 64; ++s) {
    float x = bf2f(xp[(long)s * stp]);
    float zv = bf2f(zp[(long)s * stp]);
    float dA = dAs[s];
    f32x4 B0 = *(const f32x4*)&Bst[s][0];
    f32x4 B1 = *(const f32x4*)&Bst[s][4];
    f32x4 C0 = *(const f32x4*)&Cst[s][0];
    f32x4 C1 = *(const f32x4*)&Cst[s][4];
    st[0] = fmaf(dA, st[0], x * B0[0]);
    st[1] = fmaf(dA, st[1], x * B0[1]);
    st[2] = fmaf(dA, st[2], x * B0[2]);
    st[3] = fmaf(dA, st[3], x * B0[3]);
    st[4] = fmaf(dA, st[4], x * B1[0]);
    st[5] = fmaf(dA, st[5], x * B1[1]);
    st[6] = fmaf(dA, st[6], x * B1[2]);
    st[7] = fmaf(dA, st[7], x * B1[3]);
    float y01 = fmaf(st[1], C0[1], st[0] * C0[0]);
    float y23 = fmaf(st[3], C0[3], st[2] * C0[2]);
    float y45 = fmaf(st[5], C1[1], st[4] * C1[0]);
    float y67 = fmaf(st[7], C1[3], st[6] * C1[2]);
    float y = (y01 + y23) + (y45 + y67);
    y = fmaf(Dv, x, y) * zv;
    yp[(long)s * stp] = f2bf(y);
  }
}

// ---------------- launch ----------------
extern "C" void kernel_launch(void* const* d_in, const int* in_sizes, int n_in,
                              void* d_out, int out_size, void* d_ws, size_t ws_size,
                              hipStream_t stream) {
  const float* x_H = (const float*)d_in[0];
  const float* x_V = (const float*)d_in[1];
  const float* W_in_H = (const float*)d_in[2];
  const float* W_in_V = (const float*)d_in[3];
  const float* W_out_HF = (const float*)d_in[4];
  const float* W_out_HB = (const float*)d_in[5];
  const float* W_out_VF = (const float*)d_in[6];
  const float* W_out_VB = (const float*)d_in[7];
  const float* W_out = (const float*)d_in[8];
  const float* dt_bias_HF = (const float*)d_in[9];
  const float* A_log_HF = (const float*)d_in[10];
  const float* D_HF = (const float*)d_in[11];
  const float* dt_bias_HB = (const float*)d_in[12];
  const float* A_log_HB = (const float*)d_in[13];
  const float* D_HB = (const float*)d_in[14];
  const float* dt_bias_VF = (const float*)d_in[15];
  const float* A_log_VF = (const float*)d_in[16];
  const float* D_VF = (const float*)d_in[17];
  const float* dt_bias_VB = (const float*)d_in[18];
  const float* A_log_VB = (const float*)d_in[19];
  const float* D_VB = (const float*)d_in[20];
  const int* v2h = (const int*)d_in[21];

  char* ws = (char*)d_ws;
  size_t off = 0;
  auto alloc = [&](size_t bytes) {
    void* pp = ws + off;
    off = (off + bytes + 255) & ~(size_t)255;
    return pp;
  };
  unsigned short* xbf = (unsigned short*)alloc((size_t)2 * ROWS * 256 * 2);      // [2 mats]
  unsigned short* Wt_in = (unsigned short*)alloc((size_t)2 * NPAD * 256 * 2);    // [2 mats]
  unsigned short* Wt_dirs = (unsigned short*)alloc((size_t)4 * 65536 * 2);
  unsigned short* Wt_fin = (unsigned short*)alloc((size_t)256 * 1024 * 2);
  unsigned short* zsil = (unsigned short*)alloc((size_t)4 * ROWS * 256 * 2);
  unsigned short* xsil = (unsigned short*)alloc((size_t)4 * ROWS * 256 * 2);
  unsigned short* bc = (unsigned short*)alloc((size_t)4 * ROWS * 16 * 2);
  float* dtv_arr = (float*)alloc((size_t)16 * ROWS * 4);
  float* dA_arr = (float*)alloc((size_t)16 * ROWS * 4);
  unsigned short* ybf = (unsigned short*)alloc((size_t)4 * ROWS * 256 * 2);
  unsigned short* ycat = (unsigned short*)alloc((size_t)ROWS * 1024 * 2);
  float* S = (float*)alloc((size_t)4 * NCHUNK * 8 * 512 * 4);
  float* P = (float*)alloc((size_t)4 * NCHUNK * 8 * 4);
  float* carry = (float*)alloc((size_t)4 * NCHUNK * 8 * 512 * 4);
  int* rowmap = (int*)alloc((size_t)ROWS * 4);

  // conversions
  k_cvt2<<<dim3(ROWS * 256 / 4 / 256, 2), 256, 0, stream>>>(x_H, x_V, xbf);
  k_cvtT_in<<<2 * NPAD * 256 / 256, 256, 0, stream>>>(W_in_H, W_in_V, Wt_in);
  P4 wdirs;  // cat order: dir0 HF->W_out_HB, dir1 HB->W_out_HF, dir2 VF->W_out_VB, dir3 VB->W_out_VF
  wdirs.p[0] = W_out_HB; wdirs.p[1] = W_out_HF; wdirs.p[2] = W_out_VB; wdirs.p[3] = W_out_VF;
  k_cvtT_dirs<<<1024, 256, 0, stream>>>(wdirs, Wt_dirs);
  k_cvtT_fin<<<1024, 256, 0, stream>>>(W_out, Wt_fin);
  k_rowmap<<<ROWS / 256, 256, 0, stream>>>(v2h, rowmap);

  ScanConsts sc;
  sc.dt_bias[0] = dt_bias_HF; sc.dt_bias[1] = dt_bias_HB;
  sc.dt_bias[2] = dt_bias_VF; sc.dt_bias[3] = dt_bias_VB;
  sc.A_log[0] = A_log_HF; sc.A_log[1] = A_log_HB;
  sc.A_log[2] = A_log_VF; sc.A_log[3] = A_log_VB;
  sc.D[0] = D_HF; sc.D[1] = D_HB; sc.D[2] = D_VF; sc.D[3] = D_VB;

  EpiIn ep; ep.zsil = zsil; ep.xsil = xsil; ep.bc = bc;
  EpiIn ep0 = {};

  // input GEMMs (batched over 2 mats), routing epilogue -> zsil/xsil/bc bf16
  k_gemm2<2><<<dim3(NPAD / 128, ROWS / 128, 2), 256, 0, stream>>>(
      xbf, (long)ROWS * 256, Wt_in, (long)NPAD * 256, nullptr, 256, 0, nullptr, ep);
  // exact fp32 dt -> dtv, dA
  k_dtfix<<<ROWS * 16 / 256, 256, 0, stream>>>(x_H, x_V, W_in_H, W_in_V, sc, dtv_arr, dA_arr);

  ScanP sp;
  sp.xsil = xsil; sp.zsil = zsil; sp.bc = bc; sp.dtv = dtv_arr; sp.dA = dA_arr;
  sp.D[0] = D_HF; sp.D[1] = D_HB; sp.D[2] = D_VF; sp.D[3] = D_VB;

  k_scan1<<<dim3(NCHUNK, 8, 4), 64, 0, stream>>>(sp, S, P);
  k_scan2<<<32, 512, 0, stream>>>(S, P, carry);
  k_scan3<<<dim3(NCHUNK, 8, 4), 64, 0, stream>>>(sp, carry, ybf);

  // out projections (batched over 4 dirs) -> silu bf16 into ycat, V dirs row-scattered
  k_gemm2<1><<<dim3(2, ROWS / 128, 4), 256, 0, stream>>>(
      ybf, (long)ROWS * 256, Wt_dirs, 65536L, ycat, 256, 1024, rowmap, ep0);

  // final GEMM: out = silu(cat) @ W_out
  k_gemm2<0><<<dim3(2, ROWS / 128, 1), 256, 0, stream>>>(
      ycat, 0L, Wt_fin, 0L, d_out, 1024, 256, nullptr, ep0);

  (void)in_sizes; (void)n_in; (void)out_size; (void)ws_size;
}

// Round 4
// 354.250 us; speedup vs baseline: 1.2079x; 1.0753x over previous
//
#include <hip/hip_runtime.h>
#include <hip/hip_bf16.h>

// ---------------- problem constants ----------------
#define B_N 2
#define L_N 8192
#define ROWS 16384                // B_N * L_N
#define CHUNK 64
#define NCHUNK 128                // L_N / CHUNK
#define NPAD 1152                 // input-proj N padded: 2 x 544 + pad to 9*128

typedef __bf16 bf16x8 __attribute__((ext_vector_type(8)));
typedef float f32x4 __attribute__((ext_vector_type(4)));

__device__ __forceinline__ float siluf(float v) { return v / (1.f + __expf(-v)); }
__device__ __forceinline__ float softplusf_(float v) {
  return fmaxf(v, 0.f) + log1pf(__expf(-fabsf(v)));
}
__device__ __forceinline__ unsigned short f2bf(float v) {
  union { float f; unsigned u; } x; x.f = v;
  unsigned r = x.u + 0x7fffu + ((x.u >> 16) & 1u);
  return (unsigned short)(r >> 16);
}
__device__ __forceinline__ float bf2f(unsigned short u) {
  union { unsigned u; float f; } x; x.u = ((unsigned)u) << 16;
  return x.f;
}

// async global->LDS, 16B per lane, LDS dest = wave-uniform base + lane*16
__device__ __forceinline__ void gload_lds16(const unsigned short* g, unsigned short* l) {
  __builtin_amdgcn_global_load_lds(
      (const __attribute__((address_space(1))) unsigned int*)g,
      (__attribute__((address_space(3))) unsigned int*)l, 16, 0, 0);
}

// ---------------- conversion kernels ----------------
// x (fp32) -> bf16, vectorized
__global__ void k_cvt2(const float* __restrict__ xH, const float* __restrict__ xV,
                       unsigned short* __restrict__ dst /* [2][ROWS*256] */) {
  int i = blockIdx.x * 256 + threadIdx.x;     // per float4
  const float* s = blockIdx.y ? xV : xH;
  unsigned short* d = dst + (size_t)blockIdx.y * ROWS * 256;
  float4 v = ((const float4*)s)[i];
  ushort4 o;
  o.x = f2bf(v.x); o.y = f2bf(v.y); o.z = f2bf(v.z); o.w = f2bf(v.w);
  ((ushort4*)d)[i] = o;
}

// W_in (256 x 1064) -> Wt[z][n][k], n in [0,1152): slice0 at [0,532), slice1 at [544,1076), pads zero
__global__ void k_cvtT_in(const float* __restrict__ WH, const float* __restrict__ WV,
                          unsigned short* __restrict__ dst) {
  int i = blockIdx.x * 256 + threadIdx.x;     // 2*1152*256
  int z = i / (NPAD * 256);
  int rem = i - z * (NPAD * 256);
  int n = rem >> 8, k = rem & 255;
  const float* W = z ? WV : WH;
  int sl = n >= 544;
  int cc = n - (sl ? 544 : 0);
  float v = (cc < 532) ? W[(long)k * 1064 + sl * 532 + cc] : 0.f;
  dst[i] = f2bf(v);
}

struct P4 { const float* p[4]; };
// 4 dir out-weights (256x256) -> Wt[d][n][k]
__global__ void k_cvtT_dirs(P4 ws, unsigned short* __restrict__ dst) {
  int i = blockIdx.x * 256 + threadIdx.x;     // 4*65536
  int d = i >> 16;
  int rem = i & 65535;
  int n = rem >> 8, k = rem & 255;
  dst[i] = f2bf(ws.p[d][(long)k * 256 + n]);
}

// W_out (1024x256) -> Wt[n][k] n<256,k<1024
__global__ void k_cvtT_fin(const float* __restrict__ W, unsigned short* __restrict__ dst) {
  int i = blockIdx.x * 256 + threadIdx.x;     // 256*1024, i = n*1024+k
  int n = i >> 10, k = i & 1023;
  dst[i] = f2bf(W[(long)k * 256 + n]);
}

__global__ void k_rowmap(const int* __restrict__ v2h, int* __restrict__ rowmap) {
  int m = blockIdx.x * blockDim.x + threadIdx.x;
  if (m < ROWS) {
    int b = m >> 13;
    rowmap[m] = b * L_N + v2h[m];
  }
}

struct ScanConsts {
  const float* dt_bias[4];
  const float* A_log[4];
  const float* D[4];
};

// exact fp32 dt dot; precompute dtv (softplus) and dA (exp(dt*A)) per (dir,h,row)
__global__ void k_dtfix(const float* __restrict__ xH, const float* __restrict__ xV,
                        const float* __restrict__ WH, const float* __restrict__ WV,
                        ScanConsts sc, float* __restrict__ dtv_arr, float* __restrict__ dA_arr) {
  int idx = blockIdx.x * 256 + threadIdx.x;   // ROWS*16
  int row = idx >> 4;
  int c = idx & 15;
  int mat = c >> 3, sl = (c >> 2) & 1, h = c & 3;
  int dir = mat * 2 + sl;
  const float* x = (mat ? xV : xH) + (long)row * 256;
  const float* W = mat ? WV : WH;
  int wcol = sl * 532 + 528 + h;
  float s = 0.f;
  #pragma unroll 8
  for (int k = 0; k < 256; ++k) s = fmaf(x[k], W[(long)k * 1064 + wcol], s);
  float dtv = softplusf_(s + sc.dt_bias[dir][h]);
  float dAv = __expf(dtv * (-__expf(sc.A_log[dir][h])));
  long o = ((long)dir * 4 + h) * ROWS + row;
  dtv_arr[o] = dtv;
  dA_arr[o] = dAv;
}

// ---------------- bf16 MFMA GEMM (128x128 tile, async LDS staging) ----------------
struct EpiIn {
  unsigned short* zsil;   // [4][ROWS*256] silu(z)
  unsigned short* xsil;   // [4][ROWS*256] silu(x)
  unsigned short* bc;     // [4][ROWS*16]  silu(B)|silu(C)
};

// A row-major bf16 (lda=K), Bt row-major [n][k] bf16 (ldb=K). 128x128 tile, BK=32.
// Grid: x = row tiles (same-A blocks land on same XCD), y = col tiles, z = batch.
// LDS XOR-swizzled: chunk ch of row stored at slot (row*4 + (ch ^ ((row>>1)&3))).
// MODE 0: fp32 store. MODE 1: out-proj (silu->bf16, col z*256, rowmap for z>=2).
// MODE 2: input-proj routing epilogue (wave-uniform 16-col windows).
template <int MODE>
__global__ __launch_bounds__(256) void k_gemm2(
    const unsigned short* __restrict__ Abase, long Astride,
    const unsigned short* __restrict__ Btbase, long Btstride,
    void* __restrict__ Cv, int K, int ldc,
    const int* __restrict__ rowmap, EpiIn ep) {
  __shared__ unsigned short As[128 * 32];
  __shared__ unsigned short Bs[128 * 32];
  const int tid = threadIdx.x;
  const int lane = tid & 63;
  const int wid = tid >> 6;
  const int wm = wid & 1, wn = wid >> 1;
  const int q = lane >> 4, r = lane & 15;
  const int m0 = blockIdx.x * 128;
  const int n0 = blockIdx.y * 128;
  const int z = blockIdx.z;
  const unsigned short* A = Abase + (long)z * Astride;
  const unsigned short* Bt = Btbase + (long)z * Btstride;

  f32x4 acc[4][4] = {};

  const int swr = (r >> 1) & 3;   // read-side swizzle (row>>1)&3 for 16-aligned row bases

  for (int kt = 0; kt < K; kt += 32) {
    #pragma unroll
    for (int i = 0; i < 2; ++i) {
      int idx = i * 256 + tid;
      int row = idx >> 2;
      int ch = (idx & 3) ^ ((row >> 1) & 3);
      gload_lds16(A + (long)(m0 + row) * K + kt + ch * 8,
                  &As[(size_t)(i * 256 + wid * 64) * 8]);
    }
    #pragma unroll
    for (int i = 0; i < 2; ++i) {
      int idx = i * 256 + tid;
      int row = idx >> 2;
      int ch = (idx & 3) ^ ((row >> 1) & 3);
      gload_lds16(Bt + (long)(n0 + row) * K + kt + ch * 8,
                  &Bs[(size_t)(i * 256 + wid * 64) * 8]);
    }
    __syncthreads();
    bf16x8 af[4], bfr[4];
    #pragma unroll
    for (int mi = 0; mi < 4; ++mi)
      af[mi] = *(const bf16x8*)&As[((wm * 64 + mi * 16 + r) * 4 + (q ^ swr)) * 8];
    #pragma unroll
    for (int ni = 0; ni < 4; ++ni)
      bfr[ni] = *(const bf16x8*)&Bs[((wn * 64 + ni * 16 + r) * 4 + (q ^ swr)) * 8];
    #pragma unroll
    for (int mi = 0; mi < 4; ++mi)
      #pragma unroll
      for (int ni = 0; ni < 4; ++ni)
        acc[mi][ni] = __builtin_amdgcn_mfma_f32_16x16x32_bf16(af[mi], bfr[ni], acc[mi][ni], 0, 0, 0);
    __syncthreads();
  }

  if (MODE == 2) {
    // windowed routing epilogue: each ni is a wave-uniform 16-col window
    #pragma unroll
    for (int ni = 0; ni < 4; ++ni) {
      int colw = n0 + wn * 64 + ni * 16;      // window base, multiple of 16
      int sl = colw >= 544;
      int cc0 = colw - (sl ? 544 : 0);
      if (cc0 >= 528) continue;               // dt (handled by k_dtfix) + pad
      int dir = z * 2 + sl;
      unsigned short* dst;
      long rstride;
      if (cc0 < 256) { dst = ep.zsil + (long)dir * ROWS * 256 + cc0 + r; rstride = 256; }
      else if (cc0 < 512) { dst = ep.xsil + (long)dir * ROWS * 256 + (cc0 - 256) + r; rstride = 256; }
      else { dst = ep.bc + (long)dir * ROWS * 16 + (cc0 - 512) + r; rstride = 16; }
      #pragma unroll
      for (int mi = 0; mi < 4; ++mi) {
        int row0 = m0 + wm * 64 + mi * 16 + q * 4;
        #pragma unroll
        for (int j = 0; j < 4; ++j)
          dst[(long)(row0 + j) * rstride] = f2bf(siluf(acc[mi][ni][j]));
      }
    }
  } else {
    #pragma unroll
    for (int mi = 0; mi < 4; ++mi) {
      #pragma unroll
      for (int j = 0; j < 4; ++j) {
        int row = m0 + wm * 64 + mi * 16 + q * 4 + j;
        int orow = (MODE == 1 && z >= 2) ? rowmap[row] : row;
        #pragma unroll
        for (int ni = 0; ni < 4; ++ni) {
          int col = n0 + wn * 64 + ni * 16 + r;
          float v = acc[mi][ni][j];
          if (MODE == 0) {
            ((float*)Cv)[(long)orow * ldc + col] = v;
          } else {
            ((unsigned short*)Cv)[(long)orow * ldc + z * 256 + col] = f2bf(siluf(v));
          }
        }
      }
    }
  }
}

// ---------------- scan kernels ----------------
struct ScanP {
  const unsigned short* xsil;  // [4][ROWS*256]
  const unsigned short* zsil;
  const unsigned short* bc;    // [4][ROWS*16]
  const float* dtv;            // [16][ROWS]  (dir*4+h)
  const float* dA;
  const float* D[4];
};

// phase 1: per-chunk (64 steps) local scan from zero; write end-state S and cum-dA P
__global__ __launch_bounds__(64) void k_scan1(ScanP sp, float* __restrict__ S,
                                              float* __restrict__ P) {
  __shared__ __align__(16) float Bst[64][8];
  __shared__ float dAs[64];
  const int p = threadIdx.x;
  const int c = blockIdx.x;
  const int bh = blockIdx.y;
  const int d = blockIdx.z;
  const int b = bh >> 2, h = bh & 3;
  const int rev = d & 1;
  const int t0 = c * CHUNK;
  {
    const int t = t0 + p;
    const int l = rev ? (L_N - 1 - t) : t;
    const int row = (b << 13) + l;
    uint4 bv = *(const uint4*)(sp.bc + ((long)d * ROWS + row) * 16);
    const unsigned short* bu = (const unsigned short*)&bv;
    float dtvv = sp.dtv[((long)d * 4 + h) * ROWS + row];
    dAs[p] = sp.dA[((long)d * 4 + h) * ROWS + row];
    #pragma unroll
    for (int n = 0; n < 8; ++n) Bst[p][n] = bf2f(bu[n]) * dtvv;
  }
  __syncthreads();

  float st[8] = {0, 0, 0, 0, 0, 0, 0, 0};
  float cumdA = 1.f;
  const int l0 = rev ? (L_N - 1 - t0) : t0;
  const unsigned short* xp = sp.xsil + ((long)d * ROWS + (b << 13) + l0) * 256 + h * 64 + p;
  const long stp = rev ? -256L : 256L;

  #pragma unroll 8
  for (int s = 0; s < 64; ++s) {
    float x = bf2f(xp[(long)s * stp]);
    float dA = dAs[s];
    f32x4 B0 = *(const f32x4*)&Bst[s][0];
    f32x4 B1 = *(const f32x4*)&Bst[s][4];
    cumdA *= dA;
    st[0] = fmaf(dA, st[0], x * B0[0]);
    st[1] = fmaf(dA, st[1], x * B0[1]);
    st[2] = fmaf(dA, st[2], x * B0[2]);
    st[3] = fmaf(dA, st[3], x * B0[3]);
    st[4] = fmaf(dA, st[4], x * B1[0]);
    st[5] = fmaf(dA, st[5], x * B1[1]);
    st[6] = fmaf(dA, st[6], x * B1[2]);
    st[7] = fmaf(dA, st[7], x * B1[3]);
  }
  float* Sp = S + ((((long)d * NCHUNK + c) * 8 + bh) * 64 + p) * 8;
  #pragma unroll
  for (int n = 0; n < 8; ++n) Sp[n] = st[n];
  if (p == 0) P[((long)d * NCHUNK + c) * 8 + bh] = cumdA;
}

// phase 2: sequential chunk-level combine -> carry-in per chunk
__global__ __launch_bounds__(512) void k_scan2(const float* __restrict__ S,
                                               const float* __restrict__ P,
                                               float* __restrict__ carry) {
  const int tid = threadIdx.x;
  const int dbh = blockIdx.x;
  const int d = dbh >> 3, bh = dbh & 7;
  float cy = 0.f;
  carry[(((long)d * NCHUNK + 0) * 8 + bh) * 512 + tid] = 0.f;
  #pragma unroll 4
  for (int c = 1; c < NCHUNK; ++c) {
    const float Pv = P[((long)d * NCHUNK + (c - 1)) * 8 + bh];
    const float Sv = S[(((long)d * NCHUNK + (c - 1)) * 8 + bh) * 512 + tid];
    cy = fmaf(Pv, cy, Sv);
    carry[(((long)d * NCHUNK + c) * 8 + bh) * 512 + tid] = cy;
  }
}

// phase 3: re-scan with carry-in, produce gated y in bf16
__global__ __launch_bounds__(64) void k_scan3(ScanP sp, const float* __restrict__ carry,
                                              unsigned short* __restrict__ ybf) {
  __shared__ __align__(16) float Bst[64][8];
  __shared__ __align__(16) float Cst[64][8];
  __shared__ float dAs[64];
  const int p = threadIdx.x;
  const int c = blockIdx.x;
  const int bh = blockIdx.y;
  const int d = blockIdx.z;
  const int b = bh >> 2, h = bh & 3;
  const int rev = d & 1;
  const float Dv = sp.D[d][h];
  const int t0 = c * CHUNK;
  {
    const int t = t0 + p;
    const int l = rev ? (L_N - 1 - t) : t;
    const int row = (b << 13) + l;
    const unsigned short* bp = sp.bc + ((long)d * ROWS + row) * 16;
    uint4 bv = *(const uint4*)bp;
    uint4 cv = *(const uint4*)(bp + 8);
    const unsigned short* bu = (const unsigned short*)&bv;
    const unsigned short* cu = (const unsigned short*)&cv;
    float dtvv = sp.dtv[((long)d * 4 + h) * ROWS + row];
    dAs[p] = sp.dA[((long)d * 4 + h) * ROWS + row];
    #pragma unroll
    for (int n = 0; n < 8; ++n) Bst[p][n] = bf2f(bu[n]) * dtvv;
    #pragma unroll
    for (int n = 0; n < 8; ++n) Cst[p][n] = bf2f(cu[n]);
  }
  __syncthreads();

  float st[8];
  {
    const float* cp = carry + ((((long)d * NCHUNK + c) * 8 + bh) * 64 + p) * 8;
    #pragma unroll
    for (int n = 0; n < 8; ++n) st[n] = cp[n];
  }

  const int l0 = rev ? (L_N - 1 - t0) : t0;
  const long base = (long)(b << 13) + l0;
  const unsigned short* xp = sp.xsil + ((long)d * ROWS + base) * 256 + h * 64 + p;
  const unsigned short* zp = sp.zsil + ((long)d * ROWS + base) * 256 + h * 64 + p;
  unsigned short* yp = ybf + ((long)d * ROWS + base) * 256 + h * 64 + p;
  const long stp = rev ? -256L : 256L;

  #pragma unroll 8
  for (int s = 0; s < 64; ++s) {
    float x = bf2f(xp[(long)s * stp]);
    float zv = bf2f(zp[(long)s * stp]);
    float dA = dAs[s];
    f32x4 B0 = *(const f32x4*)&Bst[s][0];
    f32x4 B1 = *(const f32x4*)&Bst[s][4];
    f32x4 C0 = *(const f32x4*)&Cst[s][0];
    f32x4 C1 = *(const f32x4*)&Cst[s][4];
    st[0] = fmaf(dA, st[0], x * B0[0]);
    st[1] = fmaf(dA, st[1], x * B0[1]);
    st[2] = fmaf(dA, st[2], x * B0[2]);
    st[3] = fmaf(dA, st[3], x * B0[3]);
    st[4] = fmaf(dA, st[4], x * B1[0]);
    st[5] = fmaf(dA, st[5], x * B1[1]);
    st[6] = fmaf(dA, st[6], x * B1[2]);
    st[7] = fmaf(dA, st[7], x * B1[3]);
    float y01 = fmaf(st[1], C0[1], st[0] * C0[0]);
    float y23 = fmaf(st[3], C0[3], st[2] * C0[2]);
    float y45 = fmaf(st[5], C1[1], st[4] * C1[0]);
    float y67 = fmaf(st[7], C1[3], st[6] * C1[2]);
    float y = (y01 + y23) + (y45 + y67);
    y = fmaf(Dv, x, y) * zv;
    yp[(long)s * stp] = f2bf(y);
  }
}

// ---------------- launch ----------------
extern "C" void kernel_launch(void* const* d_in, const int* in_sizes, int n_in,
                              void* d_out, int out_size, void* d_ws, size_t ws_size,
                              hipStream_t stream) {
  const float* x_H = (const float*)d_in[0];
  const float* x_V = (const float*)d_in[1];
  const float* W_in_H = (const float*)d_in[2];
  const float* W_in_V = (const float*)d_in[3];
  const float* W_out_HF = (const float*)d_in[4];
  const float* W_out_HB = (const float*)d_in[5];
  const float* W_out_VF = (const float*)d_in[6];
  const float* W_out_VB = (const float*)d_in[7];
  const float* W_out = (const float*)d_in[8];
  const float* dt_bias_HF = (const float*)d_in[9];
  const float* A_log_HF = (const float*)d_in[10];
  const float* D_HF = (const float*)d_in[11];
  const float* dt_bias_HB = (const float*)d_in[12];
  const float* A_log_HB = (const float*)d_in[13];
  const float* D_HB = (const float*)d_in[14];
  const float* dt_bias_VF = (const float*)d_in[15];
  const float* A_log_VF = (const float*)d_in[16];
  const float* D_VF = (const float*)d_in[17];
  const float* dt_bias_VB = (const float*)d_in[18];
  const float* A_log_VB = (const float*)d_in[19];
  const float* D_VB = (const float*)d_in[20];
  const int* v2h = (const int*)d_in[21];

  char* ws = (char*)d_ws;
  size_t off = 0;
  auto alloc = [&](size_t bytes) {
    void* pp = ws + off;
    off = (off + bytes + 255) & ~(size_t)255;
    return pp;
  };
  unsigned short* xbf = (unsigned short*)alloc((size_t)2 * ROWS * 256 * 2);      // [2 mats]
  unsigned short* Wt_in = (unsigned short*)alloc((size_t)2 * NPAD * 256 * 2);    // [2 mats]
  unsigned short* Wt_dirs = (unsigned short*)alloc((size_t)4 * 65536 * 2);
  unsigned short* Wt_fin = (unsigned short*)alloc((size_t)256 * 1024 * 2);
  unsigned short* zsil = (unsigned short*)alloc((size_t)4 * ROWS * 256 * 2);
  unsigned short* xsil = (unsigned short*)alloc((size_t)4 * ROWS * 256 * 2);
  unsigned short* bc = (unsigned short*)alloc((size_t)4 * ROWS * 16 * 2);
  float* dtv_arr = (float*)alloc((size_t)16 * ROWS * 4);
  float* dA_arr = (float*)alloc((size_t)16 * ROWS * 4);
  unsigned short* ybf = (unsigned short*)alloc((size_t)4 * ROWS * 256 * 2);
  unsigned short* ycat = (unsigned short*)alloc((size_t)ROWS * 1024 * 2);
  float* S = (float*)alloc((size_t)4 * NCHUNK * 8 * 512 * 4);
  float* P = (float*)alloc((size_t)4 * NCHUNK * 8 * 4);
  float* carry = (float*)alloc((size_t)4 * NCHUNK * 8 * 512 * 4);
  int* rowmap = (int*)alloc((size_t)ROWS * 4);

  // conversions
  k_cvt2<<<dim3(ROWS * 256 / 4 / 256, 2), 256, 0, stream>>>(x_H, x_V, xbf);
  k_cvtT_in<<<2 * NPAD * 256 / 256, 256, 0, stream>>>(W_in_H, W_in_V, Wt_in);
  P4 wdirs;  // cat order: dir0 HF->W_out_HB, dir1 HB->W_out_HF, dir2 VF->W_out_VB, dir3 VB->W_out_VF
  wdirs.p[0] = W_out_HB; wdirs.p[1] = W_out_HF; wdirs.p[2] = W_out_VB; wdirs.p[3] = W_out_VF;
  k_cvtT_dirs<<<1024, 256, 0, stream>>>(wdirs, Wt_dirs);
  k_cvtT_fin<<<1024, 256, 0, stream>>>(W_out, Wt_fin);
  k_rowmap<<<ROWS / 256, 256, 0, stream>>>(v2h, rowmap);

  ScanConsts sc;
  sc.dt_bias[0] = dt_bias_HF; sc.dt_bias[1] = dt_bias_HB;
  sc.dt_bias[2] = dt_bias_VF; sc.dt_bias[3] = dt_bias_VB;
  sc.A_log[0] = A_log_HF; sc.A_log[1] = A_log_HB;
  sc.A_log[2] = A_log_VF; sc.A_log[3] = A_log_VB;
  sc.D[0] = D_HF; sc.D[1] = D_HB; sc.D[2] = D_VF; sc.D[3] = D_VB;

  EpiIn ep; ep.zsil = zsil; ep.xsil = xsil; ep.bc = bc;
  EpiIn ep0 = {};

  // input GEMMs (batched over 2 mats), routing epilogue -> zsil/xsil/bc bf16
  k_gemm2<2><<<dim3(ROWS / 128, NPAD / 128, 2), 256, 0, stream>>>(
      xbf, (long)ROWS * 256, Wt_in, (long)NPAD * 256, nullptr, 256, 0, nullptr, ep);
  // exact fp32 dt -> dtv, dA
  k_dtfix<<<ROWS * 16 / 256, 256, 0, stream>>>(x_H, x_V, W_in_H, W_in_V, sc, dtv_arr, dA_arr);

  ScanP sp;
  sp.xsil = xsil; sp.zsil = zsil; sp.bc = bc; sp.dtv = dtv_arr; sp.dA = dA_arr;
  sp.D[0] = D_HF; sp.D[1] = D_HB; sp.D[2] = D_VF; sp.D[3] = D_VB;

  k_scan1<<<dim3(NCHUNK, 8, 4), 64, 0, stream>>>(sp, S, P);
  k_scan2<<<32, 512, 0, stream>>>(S, P, carry);
  k_scan3<<<dim3(NCHUNK, 8, 4), 64, 0, stream>>>(sp, carry, ybf);

  // out projections (batched over 4 dirs) -> silu bf16 into ycat, V dirs row-scattered
  k_gemm2<1><<<dim3(ROWS / 128, 2, 4), 256, 0, stream>>>(
      ybf, (long)ROWS * 256, Wt_dirs, 65536L, ycat, 256, 1024, rowmap, ep0);

  // final GEMM: out = silu(cat) @ W_out
  k_gemm2<0><<<dim3(ROWS / 128, 2, 1), 256, 0, stream>>>(
      ycat, 0L, Wt_fin, 0L, d_out, 1024, 256, nullptr, ep0);

  (void)in_sizes; (void)n_in; (void)out_size; (void)ws_size;
}

// Round 6
// 337.036 us; speedup vs baseline: 1.2696x; 1.0511x over previous
//
#include <hip/hip_runtime.h>
#include <hip/hip_bf16.h>

// ---------------- problem constants ----------------
#define B_N 2
#define L_N 8192
#define ROWS 16384                // B_N * L_N
#define CHUNK 64
#define NCHUNK 128                // L_N / CHUNK
#define NPAD 1152                 // input-proj N padded: 2 x 544 + pad to 9*128

typedef __bf16 bf16x8 __attribute__((ext_vector_type(8)));
typedef float f32x4 __attribute__((ext_vector_type(4)));

__device__ __forceinline__ float siluf(float v) { return v / (1.f + __expf(-v)); }
__device__ __forceinline__ float softplusf_(float v) {
  return fmaxf(v, 0.f) + log1pf(__expf(-fabsf(v)));
}
__device__ __forceinline__ unsigned short f2bf(float v) {
  union { float f; unsigned u; } x; x.f = v;
  unsigned r = x.u + 0x7fffu + ((x.u >> 16) & 1u);
  return (unsigned short)(r >> 16);
}
__device__ __forceinline__ float bf2f(unsigned short u) {
  union { unsigned u; float f; } x; x.u = ((unsigned)u) << 16;
  return x.f;
}

// async global->LDS, 16B per lane, LDS dest = wave-uniform base + lane*16
__device__ __forceinline__ void gload_lds16(const unsigned short* g, unsigned short* l) {
  __builtin_amdgcn_global_load_lds(
      (const __attribute__((address_space(1))) unsigned int*)g,
      (__attribute__((address_space(3))) unsigned int*)l, 16, 0, 0);
}

// ---------------- conversion kernels ----------------
// x (fp32) -> bf16, vectorized
__global__ void k_cvt2(const float* __restrict__ xH, const float* __restrict__ xV,
                       unsigned short* __restrict__ dst /* [2][ROWS*256] */) {
  int i = blockIdx.x * 256 + threadIdx.x;     // per float4
  const float* s = blockIdx.y ? xV : xH;
  unsigned short* d = dst + (size_t)blockIdx.y * ROWS * 256;
  float4 v = ((const float4*)s)[i];
  ushort4 o;
  o.x = f2bf(v.x); o.y = f2bf(v.y); o.z = f2bf(v.z); o.w = f2bf(v.w);
  ((ushort4*)d)[i] = o;
}

// W_in (256 x 1064) -> Wt[z][n][k], n in [0,1152): slice0 at [0,532), slice1 at [544,1076), pads zero
__global__ void k_cvtT_in(const float* __restrict__ WH, const float* __restrict__ WV,
                          unsigned short* __restrict__ dst) {
  int i = blockIdx.x * 256 + threadIdx.x;     // 2*1152*256
  int z = i / (NPAD * 256);
  int rem = i - z * (NPAD * 256);
  int n = rem >> 8, k = rem & 255;
  const float* W = z ? WV : WH;
  int sl = n >= 544;
  int cc = n - (sl ? 544 : 0);
  float v = (cc < 532) ? W[(long)k * 1064 + sl * 532 + cc] : 0.f;
  dst[i] = f2bf(v);
}

struct P4 { const float* p[4]; };
// fused small prep: Wt_dirs (blocks 0..1023), Wt_fin (1024..2047), rowmap (2048..2111)
__global__ void k_prep(P4 ws, const float* __restrict__ W_out, const int* __restrict__ v2h,
                       unsigned short* __restrict__ Wt_dirs, unsigned short* __restrict__ Wt_fin,
                       int* __restrict__ rowmap) {
  int bid = blockIdx.x;
  int tid = threadIdx.x;
  if (bid < 1024) {
    int i = bid * 256 + tid;                  // 4*65536
    int d = i >> 16;
    int rem = i & 65535;
    int n = rem >> 8, k = rem & 255;
    Wt_dirs[i] = f2bf(ws.p[d][(long)k * 256 + n]);
  } else if (bid < 2048) {
    int i = (bid - 1024) * 256 + tid;         // 256*1024, i = n*1024+k
    int n = i >> 10, k = i & 1023;
    Wt_fin[i] = f2bf(W_out[(long)k * 256 + n]);
  } else {
    int m = (bid - 2048) * 256 + tid;
    if (m < ROWS) {
      int b = m >> 13;
      rowmap[m] = b * L_N + v2h[m];
    }
  }
}

struct ScanConsts {
  const float* dt_bias[4];
  const float* A_log[4];
  const float* D[4];
};

// exact fp32 dt dot with LDS staging; precompute dtv (softplus) and dA (exp(dt*A))
__global__ __launch_bounds__(256) void k_dtfix(
    const float* __restrict__ xH, const float* __restrict__ xV,
    const float* __restrict__ WH, const float* __restrict__ WV,
    ScanConsts sc, float* __restrict__ dtv_arr, float* __restrict__ dA_arr) {
  __shared__ float xs[32][257];
  __shared__ float Wsm[8][260];
  const int mat = blockIdx.y;
  const float* x = mat ? xV : xH;
  const float* W = mat ? WV : WH;
  const int r0 = blockIdx.x * 32;
  for (int i = threadIdx.x; i < 2048; i += 256) {
    int c = i >> 8, k = i & 255;              // c = sl*4+h
    int sl = c >> 2, h = c & 3;
    Wsm[c][k] = W[(long)k * 1064 + sl * 532 + 528 + h];
  }
  for (int i = threadIdx.x; i < 32 * 64; i += 256) {
    int rl = i >> 6, kq = (i & 63) * 4;
    float4 v = *(const float4*)(x + (long)(r0 + rl) * 256 + kq);
    xs[rl][kq + 0] = v.x; xs[rl][kq + 1] = v.y; xs[rl][kq + 2] = v.z; xs[rl][kq + 3] = v.w;
  }
  __syncthreads();
  const int rl = threadIdx.x >> 3, c = threadIdx.x & 7;
  float s = 0.f;
  #pragma unroll 8
  for (int k = 0; k < 256; ++k) s = fmaf(xs[rl][k], Wsm[c][k], s);
  const int sl = c >> 2, h = c & 3;
  const int dir = mat * 2 + sl;
  float dtv = softplusf_(s + sc.dt_bias[dir][h]);
  float dAv = __expf(dtv * (-__expf(sc.A_log[dir][h])));
  long o = ((long)dir * 4 + h) * ROWS + (r0 + rl);
  dtv_arr[o] = dtv;
  dA_arr[o] = dAv;
}

// ---------------- bf16 MFMA GEMM (128x128 tile, BK=32, async LDS staging) ----------------
struct EpiIn {
  unsigned short* zsil;   // [4][ROWS*256] silu(z)
  unsigned short* xsil;   // [4][ROWS*256] silu(x)
  unsigned short* bc;     // [4][ROWS*16]  silu(B)|silu(C)
};

// A row-major bf16 (lda=K), Bt row-major [n][k] bf16 (ldb=K). Grid: x=row tiles, y=col tiles, z=batch.
// K-loop: R4-proven BK=32 staging, XOR chunk swizzle ch^((row>>1)&3).
// MODE 0: fp32 direct store. MODE 1/2: per-wave 16-row LDS transpose (dedicated buffer,
// wave-internal only, explicit lgkmcnt wait) -> 16B/lane contiguous bf16 stores.
// MODE 1: out-proj (silu, col z*256, rowmap for z>=2). MODE 2: input-proj routing.
template <int MODE>
__global__ __launch_bounds__(256) void k_gemm2(
    const unsigned short* __restrict__ Abase, long Astride,
    const unsigned short* __restrict__ Btbase, long Btstride,
    void* __restrict__ Cv, int K, int ldc,
    const int* __restrict__ rowmap, EpiIn ep) {
  __shared__ unsigned short As[128 * 32];
  __shared__ unsigned short Bs[128 * 32];
  const int tid = threadIdx.x;
  const int lane = tid & 63;
  const int wid = tid >> 6;
  const int wm = wid & 1, wn = wid >> 1;
  const int q = lane >> 4, r = lane & 15;
  const int m0 = blockIdx.x * 128;
  const int n0 = blockIdx.y * 128;
  const int z = blockIdx.z;
  const unsigned short* A = Abase + (long)z * Astride;
  const unsigned short* Bt = Btbase + (long)z * Btstride;

  f32x4 acc[4][4] = {};
  const int swr = (r >> 1) & 3;               // read-side swizzle

  for (int kt = 0; kt < K; kt += 32) {
    #pragma unroll
    for (int i = 0; i < 2; ++i) {
      int idx = i * 256 + tid;
      int row = idx >> 2;
      int ch = (idx & 3) ^ ((row >> 1) & 3);
      gload_lds16(A + (long)(m0 + row) * K + kt + ch * 8,
                  &As[(size_t)(i * 256 + wid * 64) * 8]);
    }
    #pragma unroll
    for (int i = 0; i < 2; ++i) {
      int idx = i * 256 + tid;
      int row = idx >> 2;
      int ch = (idx & 3) ^ ((row >> 1) & 3);
      gload_lds16(Bt + (long)(n0 + row) * K + kt + ch * 8,
                  &Bs[(size_t)(i * 256 + wid * 64) * 8]);
    }
    __syncthreads();
    bf16x8 af[4], bfr[4];
    #pragma unroll
    for (int mi = 0; mi < 4; ++mi)
      af[mi] = *(const bf16x8*)&As[((wm * 64 + mi * 16 + r) * 4 + (q ^ swr)) * 8];
    #pragma unroll
    for (int ni = 0; ni < 4; ++ni)
      bfr[ni] = *(const bf16x8*)&Bs[((wn * 64 + ni * 16 + r) * 4 + (q ^ swr)) * 8];
    #pragma unroll
    for (int mi = 0; mi < 4; ++mi)
      #pragma unroll
      for (int ni = 0; ni < 4; ++ni)
        acc[mi][ni] = __builtin_amdgcn_mfma_f32_16x16x32_bf16(af[mi], bfr[ni], acc[mi][ni], 0, 0, 0);
    __syncthreads();
  }

  if (MODE == 0) {
    #pragma unroll
    for (int mi = 0; mi < 4; ++mi)
      #pragma unroll
      for (int j = 0; j < 4; ++j) {
        int row = m0 + wm * 64 + mi * 16 + q * 4 + j;
        #pragma unroll
        for (int ni = 0; ni < 4; ++ni) {
          int col = n0 + wn * 64 + ni * 16 + r;
          ((float*)Cv)[(long)row * ldc + col] = acc[mi][ni][j];
        }
      }
  } else {
    // per-wave dedicated transpose region: 16 rows x 72 cols (pad 72 -> 16B-aligned rows)
    __shared__ unsigned short trs[4][16 * 72];
    unsigned short* tr = trs[wid];
    #pragma unroll
    for (int mi = 0; mi < 4; ++mi) {
      #pragma unroll
      for (int ni = 0; ni < 4; ++ni)
        #pragma unroll
        for (int j = 0; j < 4; ++j)
          tr[(q * 4 + j) * 72 + ni * 16 + r] = f2bf(siluf(acc[mi][ni][j]));
      asm volatile("s_waitcnt lgkmcnt(0)" ::: "memory");
      #pragma unroll
      for (int pass = 0; pass < 2; ++pass) {
        int rl = pass * 8 + (lane >> 3);
        int c8 = (lane & 7) * 8;
        bf16x8 v = *(const bf16x8*)&tr[rl * 72 + c8];
        int row = m0 + wm * 64 + mi * 16 + rl;
        int col = n0 + wn * 64 + c8;
        if (MODE == 1) {
          int orow = (z >= 2) ? rowmap[row] : row;
          *(bf16x8*)((unsigned short*)Cv + (long)orow * ldc + z * 256 + col) = v;
        } else {
          int sl = col >= 544;
          int cc = col - (sl ? 544 : 0);
          if (cc < 528) {
            int dir = z * 2 + sl;
            if (cc < 256)
              *(bf16x8*)(ep.zsil + ((long)dir * ROWS + row) * 256 + cc) = v;
            else if (cc < 512)
              *(bf16x8*)(ep.xsil + ((long)dir * ROWS + row) * 256 + cc - 256) = v;
            else
              *(bf16x8*)(ep.bc + ((long)dir * ROWS + row) * 16 + cc - 512) = v;
          }
        }
      }
      asm volatile("s_waitcnt lgkmcnt(0)" ::: "memory");
    }
  }
}

// ---------------- scan kernels ----------------
struct ScanP {
  const unsigned short* xsil;  // [4][ROWS*256]
  const unsigned short* zsil;
  const unsigned short* bc;    // [4][ROWS*16]
  const float* dtv;            // [16][ROWS]  (dir*4+h)
  const float* dA;
  const float* D[4];
};

// phase 1: per-chunk (64 steps) local scan from zero; write end-state S and cum-dA P
__global__ __launch_bounds__(64) void k_scan1(ScanP sp, float* __restrict__ S,
                                              float* __restrict__ P) {
  __shared__ __align__(16) float Bst[64][8];
  __shared__ float dAs[64];
  const int p = threadIdx.x;
  const int c = blockIdx.x;
  const int bh = blockIdx.y;
  const int d = blockIdx.z;
  const int b = bh >> 2, h = bh & 3;
  const int rev = d & 1;
  const int t0 = c * CHUNK;
  {
    const int t = t0 + p;
    const int l = rev ? (L_N - 1 - t) : t;
    const int row = (b << 13) + l;
    uint4 bv = *(const uint4*)(sp.bc + ((long)d * ROWS + row) * 16);
    const unsigned short* bu = (const unsigned short*)&bv;
    float dtvv = sp.dtv[((long)d * 4 + h) * ROWS + row];
    dAs[p] = sp.dA[((long)d * 4 + h) * ROWS + row];
    #pragma unroll
    for (int n = 0; n < 8; ++n) Bst[p][n] = bf2f(bu[n]) * dtvv;
  }
  __syncthreads();

  float st[8] = {0, 0, 0, 0, 0, 0, 0, 0};
  float cumdA = 1.f;
  const int l0 = rev ? (L_N - 1 - t0) : t0;
  const unsigned short* xp = sp.xsil + ((long)d * ROWS + (b << 13) + l0) * 256 + h * 64 + p;
  const long stp = rev ? -256L : 256L;

  #pragma unroll 8
  for (int s = 0; s < 64; ++s) {
    float x = bf2f(xp[(long)s * stp]);
    float dA = dAs[s];
    f32x4 B0 = *(const f32x4*)&Bst[s][0];
    f32x4 B1 = *(const f32x4*)&Bst[s][4];
    cumdA *= dA;
    st[0] = fmaf(dA, st[0], x * B0[0]);
    st[1] = fmaf(dA, st[1], x * B0[1]);
    st[2] = fmaf(dA, st[2], x * B0[2]);
    st[3] = fmaf(dA, st[3], x * B0[3]);
    st[4] = fmaf(dA, st[4], x * B1[0]);
    st[5] = fmaf(dA, st[5], x * B1[1]);
    st[6] = fmaf(dA, st[6], x * B1[2]);
    st[7] = fmaf(dA, st[7], x * B1[3]);
  }
  float* Sp = S + ((((long)d * NCHUNK + c) * 8 + bh) * 64 + p) * 8;
  #pragma unroll
  for (int n = 0; n < 8; ++n) Sp[n] = st[n];
  if (p == 0) P[((long)d * NCHUNK + c) * 8 + bh] = cumdA;
}

// phase 2: sequential chunk-level combine -> carry-in per chunk
__global__ __launch_bounds__(512) void k_scan2(const float* __restrict__ S,
                                               const float* __restrict__ P,
                                               float* __restrict__ carry) {
  const int tid = threadIdx.x;
  const int dbh = blockIdx.x;
  const int d = dbh >> 3, bh = dbh & 7;
  float cy = 0.f;
  carry[(((long)d * NCHUNK + 0) * 8 + bh) * 512 + tid] = 0.f;
  #pragma unroll 4
  for (int c = 1; c < NCHUNK; ++c) {
    const float Pv = P[((long)d * NCHUNK + (c - 1)) * 8 + bh];
    const float Sv = S[(((long)d * NCHUNK + (c - 1)) * 8 + bh) * 512 + tid];
    cy = fmaf(Pv, cy, Sv);
    carry[(((long)d * NCHUNK + c) * 8 + bh) * 512 + tid] = cy;
  }
}

// phase 3: re-scan with carry-in, produce gated y in bf16
__global__ __launch_bounds__(64) void k_scan3(ScanP sp, const float* __restrict__ carry,
                                              unsigned short* __restrict__ ybf) {
  __shared__ __align__(16) float Bst[64][8];
  __shared__ __align__(16) float Cst[64][8];
  __shared__ float dAs[64];
  const int p = threadIdx.x;
  const int c = blockIdx.x;
  const int bh = blockIdx.y;
  const int d = blockIdx.z;
  const int b = bh >> 2, h = bh & 3;
  const int rev = d & 1;
  const float Dv = sp.D[d][h];
  const int t0 = c * CHUNK;
  {
    const int t = t0 + p;
    const int l = rev ? (L_N - 1 - t) : t;
    const int row = (b << 13) + l;
    const unsigned short* bp = sp.bc + ((long)d * ROWS + row) * 16;
    uint4 bv = *(const uint4*)bp;
    uint4 cv = *(const uint4*)(bp + 8);
    const unsigned short* bu = (const unsigned short*)&bv;
    const unsigned short* cu = (const unsigned short*)&cv;
    float dtvv = sp.dtv[((long)d * 4 + h) * ROWS + row];
    dAs[p] = sp.dA[((long)d * 4 + h) * ROWS + row];
    #pragma unroll
    for (int n = 0; n < 8; ++n) Bst[p][n] = bf2f(bu[n]) * dtvv;
    #pragma unroll
    for (int n = 0; n < 8; ++n) Cst[p][n] = bf2f(cu[n]);
  }
  __syncthreads();

  float st[8];
  {
    const float* cp = carry + ((((long)d * NCHUNK + c) * 8 + bh) * 64 + p) * 8;
    #pragma unroll
    for (int n = 0; n < 8; ++n) st[n] = cp[n];
  }

  const int l0 = rev ? (L_N - 1 - t0) : t0;
  const long base = (long)(b << 13) + l0;
  const unsigned short* xp = sp.xsil + ((long)d * ROWS + base) * 256 + h * 64 + p;
  const unsigned short* zp = sp.zsil + ((long)d * ROWS + base) * 256 + h * 64 + p;
  unsigned short* yp = ybf + ((long)d * ROWS + base) * 256 + h * 64 + p;
  const long stp = rev ? -256L : 256L;

  #pragma unroll 8
  for (int s = 0; s < 64; ++s) {
    float x = bf2f(xp[(long)s * stp]);
    float zv = bf2f(zp[(long)s * stp]);
    float dA = dAs[s];
    f32x4 B0 = *(const f32x4*)&Bst[s][0];
    f32x4 B1 = *(const f32x4*)&Bst[s][4];
    f32x4 C0 = *(const f32x4*)&Cst[s][0];
    f32x4 C1 = *(const f32x4*)&Cst[s][4];
    st[0] = fmaf(dA, st[0], x * B0[0]);
    st[1] = fmaf(dA, st[1], x * B0[1]);
    st[2] = fmaf(dA, st[2], x * B0[2]);
    st[3] = fmaf(dA, st[3], x * B0[3]);
    st[4] = fmaf(dA, st[4], x * B1[0]);
    st[5] = fmaf(dA, st[5], x * B1[1]);
    st[6] = fmaf(dA, st[6], x * B1[2]);
    st[7] = fmaf(dA, st[7], x * B1[3]);
    float y01 = fmaf(st[1], C0[1], st[0] * C0[0]);
    float y23 = fmaf(st[3], C0[3], st[2] * C0[2]);
    float y45 = fmaf(st[5], C1[1], st[4] * C1[0]);
    float y67 = fmaf(st[7], C1[3], st[6] * C1[2]);
    float y = (y01 + y23) + (y45 + y67);
    y = fmaf(Dv, x, y) * zv;
    yp[(long)s * stp] = f2bf(y);
  }
}

// ---------------- launch ----------------
extern "C" void kernel_launch(void* const* d_in, const int* in_sizes, int n_in,
                              void* d_out, int out_size, void* d_ws, size_t ws_size,
                              hipStream_t stream) {
  const float* x_H = (const float*)d_in[0];
  const float* x_V = (const float*)d_in[1];
  const float* W_in_H = (const float*)d_in[2];
  const float* W_in_V = (const float*)d_in[3];
  const float* W_out_HF = (const float*)d_in[4];
  const float* W_out_HB = (const float*)d_in[5];
  const float* W_out_VF = (const float*)d_in[6];
  const float* W_out_VB = (const float*)d_in[7];
  const float* W_out = (const float*)d_in[8];
  const float* dt_bias_HF = (const float*)d_in[9];
  const float* A_log_HF = (const float*)d_in[10];
  const float* D_HF = (const float*)d_in[11];
  const float* dt_bias_HB = (const float*)d_in[12];
  const float* A_log_HB = (const float*)d_in[13];
  const float* D_HB = (const float*)d_in[14];
  const float* dt_bias_VF = (const float*)d_in[15];
  const float* A_log_VF = (const float*)d_in[16];
  const float* D_VF = (const float*)d_in[17];
  const float* dt_bias_VB = (const float*)d_in[18];
  const float* A_log_VB = (const float*)d_in[19];
  const float* D_VB = (const float*)d_in[20];
  const int* v2h = (const int*)d_in[21];

  char* ws = (char*)d_ws;
  size_t off = 0;
  auto alloc = [&](size_t bytes) {
    void* pp = ws + off;
    off = (off + bytes + 255) & ~(size_t)255;
    return pp;
  };
  unsigned short* xbf = (unsigned short*)alloc((size_t)2 * ROWS * 256 * 2);      // [2 mats]
  unsigned short* Wt_in = (unsigned short*)alloc((size_t)2 * NPAD * 256 * 2);    // [2 mats]
  unsigned short* Wt_dirs = (unsigned short*)alloc((size_t)4 * 65536 * 2);
  unsigned short* Wt_fin = (unsigned short*)alloc((size_t)256 * 1024 * 2);
  unsigned short* zsil = (unsigned short*)alloc((size_t)4 * ROWS * 256 * 2);
  unsigned short* xsil = (unsigned short*)alloc((size_t)4 * ROWS * 256 * 2);
  unsigned short* bc = (unsigned short*)alloc((size_t)4 * ROWS * 16 * 2);
  float* dtv_arr = (float*)alloc((size_t)16 * ROWS * 4);
  float* dA_arr = (float*)alloc((size_t)16 * ROWS * 4);
  unsigned short* ybf = (unsigned short*)alloc((size_t)4 * ROWS * 256 * 2);
  unsigned short* ycat = (unsigned short*)alloc((size_t)ROWS * 1024 * 2);
  float* S = (float*)alloc((size_t)4 * NCHUNK * 8 * 512 * 4);
  float* P = (float*)alloc((size_t)4 * NCHUNK * 8 * 4);
  float* carry = (float*)alloc((size_t)4 * NCHUNK * 8 * 512 * 4);
  int* rowmap = (int*)alloc((size_t)ROWS * 4);

  // conversions
  k_cvt2<<<dim3(ROWS * 256 / 4 / 256, 2), 256, 0, stream>>>(x_H, x_V, xbf);
  k_cvtT_in<<<2 * NPAD * 256 / 256, 256, 0, stream>>>(W_in_H, W_in_V, Wt_in);
  P4 wdirs;  // cat order: dir0 HF->W_out_HB, dir1 HB->W_out_HF, dir2 VF->W_out_VB, dir3 VB->W_out_VF
  wdirs.p[0] = W_out_HB; wdirs.p[1] = W_out_HF; wdirs.p[2] = W_out_VB; wdirs.p[3] = W_out_VF;
  k_prep<<<2112, 256, 0, stream>>>(wdirs, W_out, v2h, Wt_dirs, Wt_fin, rowmap);

  ScanConsts sc;
  sc.dt_bias[0] = dt_bias_HF; sc.dt_bias[1] = dt_bias_HB;
  sc.dt_bias[2] = dt_bias_VF; sc.dt_bias[3] = dt_bias_VB;
  sc.A_log[0] = A_log_HF; sc.A_log[1] = A_log_HB;
  sc.A_log[2] = A_log_VF; sc.A_log[3] = A_log_VB;
  sc.D[0] = D_HF; sc.D[1] = D_HB; sc.D[2] = D_VF; sc.D[3] = D_VB;

  EpiIn ep; ep.zsil = zsil; ep.xsil = xsil; ep.bc = bc;
  EpiIn ep0 = {};

  // input GEMMs (batched over 2 mats), routing epilogue -> zsil/xsil/bc bf16
  k_gemm2<2><<<dim3(ROWS / 128, NPAD / 128, 2), 256, 0, stream>>>(
      xbf, (long)ROWS * 256, Wt_in, (long)NPAD * 256, nullptr, 256, 0, nullptr, ep);
  // exact fp32 dt -> dtv, dA
  k_dtfix<<<dim3(ROWS / 32, 2), 256, 0, stream>>>(x_H, x_V, W_in_H, W_in_V, sc, dtv_arr, dA_arr);

  ScanP sp;
  sp.xsil = xsil; sp.zsil = zsil; sp.bc = bc; sp.dtv = dtv_arr; sp.dA = dA_arr;
  sp.D[0] = D_HF; sp.D[1] = D_HB; sp.D[2] = D_VF; sp.D[3] = D_VB;

  k_scan1<<<dim3(NCHUNK, 8, 4), 64, 0, stream>>>(sp, S, P);
  k_scan2<<<32, 512, 0, stream>>>(S, P, carry);
  k_scan3<<<dim3(NCHUNK, 8, 4), 64, 0, stream>>>(sp, carry, ybf);

  // out projections (batched over 4 dirs) -> silu bf16 into ycat, V dirs row-scattered
  k_gemm2<1><<<dim3(ROWS / 128, 2, 4), 256, 0, stream>>>(
      ybf, (long)ROWS * 256, Wt_dirs, 65536L, ycat, 256, 1024, rowmap, ep0);

  // final GEMM: out = silu(cat) @ W_out
  k_gemm2<0><<<dim3(ROWS / 128, 2, 1), 256, 0, stream>>>(
      ycat, 0L, Wt_fin, 0L, d_out, 1024, 256, nullptr, ep0);

  (void)in_sizes; (void)n_in; (void)out_size; (void)ws_size;
}

// Round 7
// 334.925 us; speedup vs baseline: 1.2776x; 1.0063x over previous
//
#include <hip/hip_runtime.h>
#include <hip/hip_bf16.h>

// ---------------- problem constants ----------------
#define B_N 2
#define L_N 8192
#define ROWS 16384                // B_N * L_N
#define CHUNK 64
#define NCHUNK 128                // L_N / CHUNK
#define NPAD 1152                 // input-proj N padded: 2 x 544 + pad to 9*128

typedef __bf16 bf16x8 __attribute__((ext_vector_type(8)));
typedef float f32x4 __attribute__((ext_vector_type(4)));

__device__ __forceinline__ float siluf(float v) { return v / (1.f + __expf(-v)); }
__device__ __forceinline__ float softplusf_(float v) {
  return fmaxf(v, 0.f) + log1pf(__expf(-fabsf(v)));
}
__device__ __forceinline__ unsigned short f2bf(float v) {
  union { float f; unsigned u; } x; x.f = v;
  unsigned r = x.u + 0x7fffu + ((x.u >> 16) & 1u);
  return (unsigned short)(r >> 16);
}
__device__ __forceinline__ float bf2f(unsigned short u) {
  union { unsigned u; float f; } x; x.u = ((unsigned)u) << 16;
  return x.f;
}

// async global->LDS, 16B per lane, LDS dest = wave-uniform base + lane*16
__device__ __forceinline__ void gload_lds16(const unsigned short* g, unsigned short* l) {
  __builtin_amdgcn_global_load_lds(
      (const __attribute__((address_space(1))) unsigned int*)g,
      (__attribute__((address_space(3))) unsigned int*)l, 16, 0, 0);
}

// ---------------- conversion kernels ----------------
// x (fp32) -> bf16, vectorized
__global__ void k_cvt2(const float* __restrict__ xH, const float* __restrict__ xV,
                       unsigned short* __restrict__ dst /* [2][ROWS*256] */) {
  int i = blockIdx.x * 256 + threadIdx.x;     // per float4
  const float* s = blockIdx.y ? xV : xH;
  unsigned short* d = dst + (size_t)blockIdx.y * ROWS * 256;
  float4 v = ((const float4*)s)[i];
  ushort4 o;
  o.x = f2bf(v.x); o.y = f2bf(v.y); o.z = f2bf(v.z); o.w = f2bf(v.w);
  ((ushort4*)d)[i] = o;
}

// W_in (256 x 1064) -> Wt[z][n][k], n in [0,1152): slice0 at [0,532), slice1 at [544,1076), pads zero
__global__ void k_cvtT_in(const float* __restrict__ WH, const float* __restrict__ WV,
                          unsigned short* __restrict__ dst) {
  int i = blockIdx.x * 256 + threadIdx.x;     // 2*1152*256
  int z = i / (NPAD * 256);
  int rem = i - z * (NPAD * 256);
  int n = rem >> 8, k = rem & 255;
  const float* W = z ? WV : WH;
  int sl = n >= 544;
  int cc = n - (sl ? 544 : 0);
  float v = (cc < 532) ? W[(long)k * 1064 + sl * 532 + cc] : 0.f;
  dst[i] = f2bf(v);
}

struct P4 { const float* p[4]; };
// fused small prep: Wt_dirs (blocks 0..1023), Wt_fin (1024..2047), inv perm (2048..2111)
__global__ void k_prep(P4 ws, const float* __restrict__ W_out, const int* __restrict__ v2h,
                       unsigned short* __restrict__ Wt_dirs, unsigned short* __restrict__ Wt_fin,
                       int* __restrict__ inv) {
  int bid = blockIdx.x;
  int tid = threadIdx.x;
  if (bid < 1024) {
    int i = bid * 256 + tid;                  // 4*65536
    int d = i >> 16;
    int rem = i & 65535;
    int n = rem >> 8, k = rem & 255;
    Wt_dirs[i] = f2bf(ws.p[d][(long)k * 256 + n]);
  } else if (bid < 2048) {
    int i = (bid - 1024) * 256 + tid;         // 256*1024, i = n*1024+k
    int n = i >> 10, k = i & 1023;
    Wt_fin[i] = f2bf(W_out[(long)k * 256 + n]);
  } else {
    int m = (bid - 2048) * 256 + tid;
    if (m < ROWS) {
      int b = m >> 13;
      inv[b * L_N + v2h[m]] = m;              // inverse of the v->h scatter
    }
  }
}

struct ScanConsts {
  const float* dt_bias[4];
  const float* A_log[4];
  const float* D[4];
};

// exact fp32 dt dot with LDS staging; precompute dtv (softplus) and dA (exp(dt*A))
__global__ __launch_bounds__(256) void k_dtfix(
    const float* __restrict__ xH, const float* __restrict__ xV,
    const float* __restrict__ WH, const float* __restrict__ WV,
    ScanConsts sc, float* __restrict__ dtv_arr, float* __restrict__ dA_arr) {
  __shared__ float xs[32][257];
  __shared__ float Wsm[8][260];
  const int mat = blockIdx.y;
  const float* x = mat ? xV : xH;
  const float* W = mat ? WV : WH;
  const int r0 = blockIdx.x * 32;
  for (int i = threadIdx.x; i < 2048; i += 256) {
    int c = i >> 8, k = i & 255;              // c = sl*4+h
    int sl = c >> 2, h = c & 3;
    Wsm[c][k] = W[(long)k * 1064 + sl * 532 + 528 + h];
  }
  for (int i = threadIdx.x; i < 32 * 64; i += 256) {
    int rl = i >> 6, kq = (i & 63) * 4;
    float4 v = *(const float4*)(x + (long)(r0 + rl) * 256 + kq);
    xs[rl][kq + 0] = v.x; xs[rl][kq + 1] = v.y; xs[rl][kq + 2] = v.z; xs[rl][kq + 3] = v.w;
  }
  __syncthreads();
  const int rl = threadIdx.x >> 3, c = threadIdx.x & 7;
  float s = 0.f;
  #pragma unroll 8
  for (int k = 0; k < 256; ++k) s = fmaf(xs[rl][k], Wsm[c][k], s);
  const int sl = c >> 2, h = c & 3;
  const int dir = mat * 2 + sl;
  float dtv = softplusf_(s + sc.dt_bias[dir][h]);
  float dAv = __expf(dtv * (-__expf(sc.A_log[dir][h])));
  long o = ((long)dir * 4 + h) * ROWS + (r0 + rl);
  dtv_arr[o] = dtv;
  dA_arr[o] = dAv;
}

// ---------------- bf16 MFMA GEMM (128x128 tile, BK=32, async LDS staging) ----------------
struct EpiIn {
  unsigned short* zsil;   // [4][ROWS*256] silu(z)
  unsigned short* xsil;   // [4][ROWS*256] silu(x)
  unsigned short* bc;     // [4][ROWS*16]  silu(B)|silu(C)
};

// A row-major bf16 (lda=K), Bt row-major [n][k] bf16 (ldb=K). Grid: x=row tiles, y=col tiles, z=batch.
// K-loop: BK=32 staging, XOR chunk swizzle ch^((row>>1)&3).
// MODE 2: input-proj routing via per-wave 16-row LDS transpose.
template <int MODE>
__global__ __launch_bounds__(256) void k_gemm2(
    const unsigned short* __restrict__ Abase, long Astride,
    const unsigned short* __restrict__ Btbase, long Btstride,
    void* __restrict__ Cv, int K, int ldc,
    const int* __restrict__ rowmap, EpiIn ep) {
  __shared__ unsigned short As[128 * 32];
  __shared__ unsigned short Bs[128 * 32];
  const int tid = threadIdx.x;
  const int lane = tid & 63;
  const int wid = tid >> 6;
  const int wm = wid & 1, wn = wid >> 1;
  const int q = lane >> 4, r = lane & 15;
  const int m0 = blockIdx.x * 128;
  const int n0 = blockIdx.y * 128;
  const int z = blockIdx.z;
  const unsigned short* A = Abase + (long)z * Astride;
  const unsigned short* Bt = Btbase + (long)z * Btstride;

  f32x4 acc[4][4] = {};
  const int swr = (r >> 1) & 3;               // read-side swizzle

  for (int kt = 0; kt < K; kt += 32) {
    #pragma unroll
    for (int i = 0; i < 2; ++i) {
      int idx = i * 256 + tid;
      int row = idx >> 2;
      int ch = (idx & 3) ^ ((row >> 1) & 3);
      gload_lds16(A + (long)(m0 + row) * K + kt + ch * 8,
                  &As[(size_t)(i * 256 + wid * 64) * 8]);
    }
    #pragma unroll
    for (int i = 0; i < 2; ++i) {
      int idx = i * 256 + tid;
      int row = idx >> 2;
      int ch = (idx & 3) ^ ((row >> 1) & 3);
      gload_lds16(Bt + (long)(n0 + row) * K + kt + ch * 8,
                  &Bs[(size_t)(i * 256 + wid * 64) * 8]);
    }
    __syncthreads();
    bf16x8 af[4], bfr[4];
    #pragma unroll
    for (int mi = 0; mi < 4; ++mi)
      af[mi] = *(const bf16x8*)&As[((wm * 64 + mi * 16 + r) * 4 + (q ^ swr)) * 8];
    #pragma unroll
    for (int ni = 0; ni < 4; ++ni)
      bfr[ni] = *(const bf16x8*)&Bs[((wn * 64 + ni * 16 + r) * 4 + (q ^ swr)) * 8];
    #pragma unroll
    for (int mi = 0; mi < 4; ++mi)
      #pragma unroll
      for (int ni = 0; ni < 4; ++ni)
        acc[mi][ni] = __builtin_amdgcn_mfma_f32_16x16x32_bf16(af[mi], bfr[ni], acc[mi][ni], 0, 0, 0);
    __syncthreads();
  }

  if (MODE == 0) {
    #pragma unroll
    for (int mi = 0; mi < 4; ++mi)
      #pragma unroll
      for (int j = 0; j < 4; ++j) {
        int row = m0 + wm * 64 + mi * 16 + q * 4 + j;
        #pragma unroll
        for (int ni = 0; ni < 4; ++ni) {
          int col = n0 + wn * 64 + ni * 16 + r;
          ((float*)Cv)[(long)row * ldc + col] = acc[mi][ni][j];
        }
      }
  } else {
    // per-wave dedicated transpose region: 16 rows x 72 cols (pad 72 -> 16B-aligned rows)
    __shared__ unsigned short trs[4][16 * 72];
    unsigned short* tr = trs[wid];
    #pragma unroll
    for (int mi = 0; mi < 4; ++mi) {
      #pragma unroll
      for (int ni = 0; ni < 4; ++ni)
        #pragma unroll
        for (int j = 0; j < 4; ++j)
          tr[(q * 4 + j) * 72 + ni * 16 + r] = f2bf(siluf(acc[mi][ni][j]));
      asm volatile("s_waitcnt lgkmcnt(0)" ::: "memory");
      #pragma unroll
      for (int pass = 0; pass < 2; ++pass) {
        int rl = pass * 8 + (lane >> 3);
        int c8 = (lane & 7) * 8;
        bf16x8 v = *(const bf16x8*)&tr[rl * 72 + c8];
        int row = m0 + wm * 64 + mi * 16 + rl;
        int col = n0 + wn * 64 + c8;
        int sl = col >= 544;
        int cc = col - (sl ? 544 : 0);
        if (cc < 528) {
          int dir = z * 2 + sl;
          if (cc < 256)
            *(bf16x8*)(ep.zsil + ((long)dir * ROWS + row) * 256 + cc) = v;
          else if (cc < 512)
            *(bf16x8*)(ep.xsil + ((long)dir * ROWS + row) * 256 + cc - 256) = v;
          else
            *(bf16x8*)(ep.bc + ((long)dir * ROWS + row) * 16 + cc - 512) = v;
        }
      }
      asm volatile("s_waitcnt lgkmcnt(0)" ::: "memory");
    }
  }
}

// ---------------- fused out-proj + final GEMM ----------------
// Per block: 64 out-rows x 256 out-cols. For each dir d:
//   T = silu(y_d[rows] @ Wd)  (64x256, bf16 in LDS)  then  out_acc += T @ Wout[d*256:,:]
// V dirs (d>=2) gather y rows via inv permutation. Single fp32 store at end.
__global__ __launch_bounds__(256) void k_fuse(
    const unsigned short* __restrict__ ybf,      // [4][ROWS][256]
    const unsigned short* __restrict__ Wt_dirs,  // [4][256 n][256 k]
    const unsigned short* __restrict__ Wt_fin,   // [256 c][1024 k] (k = d*256+kk)
    const int* __restrict__ inv,
    float* __restrict__ out) {
  __shared__ unsigned short Tl[64][264];         // silu'd T, row-major, pad 264
  __shared__ unsigned short As1[64 * 32];        // y-tile staging
  __shared__ unsigned short Bs1[256 * 32];       // weight staging (both gemms)
  __shared__ int arow[64];
  const int tid = threadIdx.x;
  const int lane = tid & 63;
  const int wid = tid >> 6;
  const int q = lane >> 4, r = lane & 15;
  const int r0 = blockIdx.x * 64;
  const int swr = (r >> 1) & 3;

  if (tid < 64) arow[tid] = inv[r0 + tid];
  __syncthreads();

  f32x4 acc_o[4][4] = {};

  for (int d = 0; d < 4; ++d) {
    const unsigned short* yd = ybf + (long)d * ROWS * 256;
    const unsigned short* Wd = Wt_dirs + (long)d * 65536;

    f32x4 acc_t[4][4] = {};
    // ---- first GEMM: T = y_d[rows,:] @ Wd  (K=256) ----
    for (int kt = 0; kt < 256; kt += 32) {
      {
        int row = tid >> 2;
        int ch = (tid & 3) ^ ((row >> 1) & 3);
        int ar = (d < 2) ? (r0 + row) : arow[row];
        gload_lds16(yd + (long)ar * 256 + kt + ch * 8, &As1[(size_t)(wid * 64) * 8]);
      }
      #pragma unroll
      for (int i = 0; i < 4; ++i) {
        int idx = i * 256 + tid;
        int row = idx >> 2;
        int ch = (idx & 3) ^ ((row >> 1) & 3);
        gload_lds16(Wd + (long)row * 256 + kt + ch * 8,
                    &Bs1[(size_t)(i * 256 + wid * 64) * 8]);
      }
      __syncthreads();
      bf16x8 af[4], bfr[4];
      #pragma unroll
      for (int mi = 0; mi < 4; ++mi)
        af[mi] = *(const bf16x8*)&As1[((mi * 16 + r) * 4 + (q ^ swr)) * 8];
      #pragma unroll
      for (int ni = 0; ni < 4; ++ni)
        bfr[ni] = *(const bf16x8*)&Bs1[((wid * 64 + ni * 16 + r) * 4 + (q ^ swr)) * 8];
      #pragma unroll
      for (int mi = 0; mi < 4; ++mi)
        #pragma unroll
        for (int ni = 0; ni < 4; ++ni)
          acc_t[mi][ni] = __builtin_amdgcn_mfma_f32_16x16x32_bf16(af[mi], bfr[ni], acc_t[mi][ni], 0, 0, 0);
      __syncthreads();
    }
    // ---- write silu(T) to LDS (row-major) ----
    #pragma unroll
    for (int mi = 0; mi < 4; ++mi)
      #pragma unroll
      for (int ni = 0; ni < 4; ++ni)
        #pragma unroll
        for (int j = 0; j < 4; ++j)
          Tl[mi * 16 + q * 4 + j][wid * 64 + ni * 16 + r] = f2bf(siluf(acc_t[mi][ni][j]));
    __syncthreads();
    // ---- second GEMM: out_acc += T @ Wout[d*256+kk][c], A from Tl ----
    for (int kt = 0; kt < 256; kt += 32) {
      #pragma unroll
      for (int i = 0; i < 4; ++i) {
        int idx = i * 256 + tid;
        int row = idx >> 2;                    // out col c
        int ch = (idx & 3) ^ ((row >> 1) & 3);
        gload_lds16(Wt_fin + (long)row * 1024 + d * 256 + kt + ch * 8,
                    &Bs1[(size_t)(i * 256 + wid * 64) * 8]);
      }
      __syncthreads();
      bf16x8 af[4], bfr[4];
      #pragma unroll
      for (int mi = 0; mi < 4; ++mi)
        af[mi] = *(const bf16x8*)&Tl[mi * 16 + r][kt + q * 8];
      #pragma unroll
      for (int ni = 0; ni < 4; ++ni)
        bfr[ni] = *(const bf16x8*)&Bs1[((wid * 64 + ni * 16 + r) * 4 + (q ^ swr)) * 8];
      #pragma unroll
      for (int mi = 0; mi < 4; ++mi)
        #pragma unroll
        for (int ni = 0; ni < 4; ++ni)
          acc_o[mi][ni] = __builtin_amdgcn_mfma_f32_16x16x32_bf16(af[mi], bfr[ni], acc_o[mi][ni], 0, 0, 0);
      __syncthreads();
    }
  }

  #pragma unroll
  for (int mi = 0; mi < 4; ++mi)
    #pragma unroll
    for (int j = 0; j < 4; ++j) {
      int row = r0 + mi * 16 + q * 4 + j;
      #pragma unroll
      for (int ni = 0; ni < 4; ++ni) {
        int col = wid * 64 + ni * 16 + r;
        out[(long)row * 256 + col] = acc_o[mi][ni][j];
      }
    }
}

// ---------------- scan kernels ----------------
struct ScanP {
  const unsigned short* xsil;  // [4][ROWS*256]
  const unsigned short* zsil;
  const unsigned short* bc;    // [4][ROWS*16]
  const float* dtv;            // [16][ROWS]  (dir*4+h)
  const float* dA;
  const float* D[4];
};

// phase 1: per-chunk (64 steps) local scan from zero; write end-state S and cum-dA P
__global__ __launch_bounds__(64) void k_scan1(ScanP sp, float* __restrict__ S,
                                              float* __restrict__ P) {
  __shared__ __align__(16) float Bst[64][8];
  __shared__ float dAs[64];
  const int p = threadIdx.x;
  const int c = blockIdx.x;
  const int bh = blockIdx.y;
  const int d = blockIdx.z;
  const int b = bh >> 2, h = bh & 3;
  const int rev = d & 1;
  const int t0 = c * CHUNK;
  {
    const int t = t0 + p;
    const int l = rev ? (L_N - 1 - t) : t;
    const int row = (b << 13) + l;
    uint4 bv = *(const uint4*)(sp.bc + ((long)d * ROWS + row) * 16);
    const unsigned short* bu = (const unsigned short*)&bv;
    float dtvv = sp.dtv[((long)d * 4 + h) * ROWS + row];
    dAs[p] = sp.dA[((long)d * 4 + h) * ROWS + row];
    #pragma unroll
    for (int n = 0; n < 8; ++n) Bst[p][n] = bf2f(bu[n]) * dtvv;
  }
  __syncthreads();

  float st[8] = {0, 0, 0, 0, 0, 0, 0, 0};
  float cumdA = 1.f;
  const int l0 = rev ? (L_N - 1 - t0) : t0;
  const unsigned short* xp = sp.xsil + ((long)d * ROWS + (b << 13) + l0) * 256 + h * 64 + p;
  const long stp = rev ? -256L : 256L;

  #pragma unroll 8
  for (int s = 0; s < 64; ++s) {
    float x = bf2f(xp[(long)s * stp]);
    float dA = dAs[s];
    f32x4 B0 = *(const f32x4*)&Bst[s][0];
    f32x4 B1 = *(const f32x4*)&Bst[s][4];
    cumdA *= dA;
    st[0] = fmaf(dA, st[0], x * B0[0]);
    st[1] = fmaf(dA, st[1], x * B0[1]);
    st[2] = fmaf(dA, st[2], x * B0[2]);
    st[3] = fmaf(dA, st[3], x * B0[3]);
    st[4] = fmaf(dA, st[4], x * B1[0]);
    st[5] = fmaf(dA, st[5], x * B1[1]);
    st[6] = fmaf(dA, st[6], x * B1[2]);
    st[7] = fmaf(dA, st[7], x * B1[3]);
  }
  float* Sp = S + ((((long)d * NCHUNK + c) * 8 + bh) * 64 + p) * 8;
  #pragma unroll
  for (int n = 0; n < 8; ++n) Sp[n] = st[n];
  if (p == 0) P[((long)d * NCHUNK + c) * 8 + bh] = cumdA;
}

// phase 2: sequential chunk-level combine -> carry-in per chunk
__global__ __launch_bounds__(512) void k_scan2(const float* __restrict__ S,
                                               const float* __restrict__ P,
                                               float* __restrict__ carry) {
  const int tid = threadIdx.x;
  const int dbh = blockIdx.x;
  const int d = dbh >> 3, bh = dbh & 7;
  float cy = 0.f;
  carry[(((long)d * NCHUNK + 0) * 8 + bh) * 512 + tid] = 0.f;
  #pragma unroll 4
  for (int c = 1; c < NCHUNK; ++c) {
    const float Pv = P[((long)d * NCHUNK + (c - 1)) * 8 + bh];
    const float Sv = S[(((long)d * NCHUNK + (c - 1)) * 8 + bh) * 512 + tid];
    cy = fmaf(Pv, cy, Sv);
    carry[(((long)d * NCHUNK + c) * 8 + bh) * 512 + tid] = cy;
  }
}

// phase 3: re-scan with carry-in, produce gated y in bf16
__global__ __launch_bounds__(64) void k_scan3(ScanP sp, const float* __restrict__ carry,
                                              unsigned short* __restrict__ ybf) {
  __shared__ __align__(16) float Bst[64][8];
  __shared__ __align__(16) float Cst[64][8];
  __shared__ float dAs[64];
  const int p = threadIdx.x;
  const int c = blockIdx.x;
  const int bh = blockIdx.y;
  const int d = blockIdx.z;
  const int b = bh >> 2, h = bh & 3;
  const int rev = d & 1;
  const float Dv = sp.D[d][h];
  const int t0 = c * CHUNK;
  {
    const int t = t0 + p;
    const int l = rev ? (L_N - 1 - t) : t;
    const int row = (b << 13) + l;
    const unsigned short* bp = sp.bc + ((long)d * ROWS + row) * 16;
    uint4 bv = *(const uint4*)bp;
    uint4 cv = *(const uint4*)(bp + 8);
    const unsigned short* bu = (const unsigned short*)&bv;
    const unsigned short* cu = (const unsigned short*)&cv;
    float dtvv = sp.dtv[((long)d * 4 + h) * ROWS + row];
    dAs[p] = sp.dA[((long)d * 4 + h) * ROWS + row];
    #pragma unroll
    for (int n = 0; n < 8; ++n) Bst[p][n] = bf2f(bu[n]) * dtvv;
    #pragma unroll
    for (int n = 0; n < 8; ++n) Cst[p][n] = bf2f(cu[n]);
  }
  __syncthreads();

  float st[8];
  {
    const float* cp = carry + ((((long)d * NCHUNK + c) * 8 + bh) * 64 + p) * 8;
    #pragma unroll
    for (int n = 0; n < 8; ++n) st[n] = cp[n];
  }

  const int l0 = rev ? (L_N - 1 - t0) : t0;
  const long base = (long)(b << 13) + l0;
  const unsigned short* xp = sp.xsil + ((long)d * ROWS + base) * 256 + h * 64 + p;
  const unsigned short* zp = sp.zsil + ((long)d * ROWS + base) * 256 + h * 64 + p;
  unsigned short* yp = ybf + ((long)d * ROWS + base) * 256 + h * 64 + p;
  const long stp = rev ? -256L : 256L;

  #pragma unroll 8
  for (int s = 0; s < 64; ++s) {
    float x = bf2f(xp[(long)s * stp]);
    float zv = bf2f(zp[(long)s * stp]);
    float dA = dAs[s];
    f32x4 B0 = *(const f32x4*)&Bst[s][0];
    f32x4 B1 = *(const f32x4*)&Bst[s][4];
    f32x4 C0 = *(const f32x4*)&Cst[s][0];
    f32x4 C1 = *(const f32x4*)&Cst[s][4];
    st[0] = fmaf(dA, st[0], x * B0[0]);
    st[1] = fmaf(dA, st[1], x * B0[1]);
    st[2] = fmaf(dA, st[2], x * B0[2]);
    st[3] = fmaf(dA, st[3], x * B0[3]);
    st[4] = fmaf(dA, st[4], x * B1[0]);
    st[5] = fmaf(dA, st[5], x * B1[1]);
    st[6] = fmaf(dA, st[6], x * B1[2]);
    st[7] = fmaf(dA, st[7], x * B1[3]);
    float y01 = fmaf(st[1], C0[1], st[0] * C0[0]);
    float y23 = fmaf(st[3], C0[3], st[2] * C0[2]);
    float y45 = fmaf(st[5], C1[1], st[4] * C1[0]);
    float y67 = fmaf(st[7], C1[3], st[6] * C1[2]);
    float y = (y01 + y23) + (y45 + y67);
    y = fmaf(Dv, x, y) * zv;
    yp[(long)s * stp] = f2bf(y);
  }
}

// ---------------- launch ----------------
extern "C" void kernel_launch(void* const* d_in, const int* in_sizes, int n_in,
                              void* d_out, int out_size, void* d_ws, size_t ws_size,
                              hipStream_t stream) {
  const float* x_H = (const float*)d_in[0];
  const float* x_V = (const float*)d_in[1];
  const float* W_in_H = (const float*)d_in[2];
  const float* W_in_V = (const float*)d_in[3];
  const float* W_out_HF = (const float*)d_in[4];
  const float* W_out_HB = (const float*)d_in[5];
  const float* W_out_VF = (const float*)d_in[6];
  const float* W_out_VB = (const float*)d_in[7];
  const float* W_out = (const float*)d_in[8];
  const float* dt_bias_HF = (const float*)d_in[9];
  const float* A_log_HF = (const float*)d_in[10];
  const float* D_HF = (const float*)d_in[11];
  const float* dt_bias_HB = (const float*)d_in[12];
  const float* A_log_HB = (const float*)d_in[13];
  const float* D_HB = (const float*)d_in[14];
  const float* dt_bias_VF = (const float*)d_in[15];
  const float* A_log_VF = (const float*)d_in[16];
  const float* D_VF = (const float*)d_in[17];
  const float* dt_bias_VB = (const float*)d_in[18];
  const float* A_log_VB = (const float*)d_in[19];
  const float* D_VB = (const float*)d_in[20];
  const int* v2h = (const int*)d_in[21];

  char* ws = (char*)d_ws;
  size_t off = 0;
  auto alloc = [&](size_t bytes) {
    void* pp = ws + off;
    off = (off + bytes + 255) & ~(size_t)255;
    return pp;
  };
  unsigned short* xbf = (unsigned short*)alloc((size_t)2 * ROWS * 256 * 2);      // [2 mats]
  unsigned short* Wt_in = (unsigned short*)alloc((size_t)2 * NPAD * 256 * 2);    // [2 mats]
  unsigned short* Wt_dirs = (unsigned short*)alloc((size_t)4 * 65536 * 2);
  unsigned short* Wt_fin = (unsigned short*)alloc((size_t)256 * 1024 * 2);
  unsigned short* zsil = (unsigned short*)alloc((size_t)4 * ROWS * 256 * 2);
  unsigned short* xsil = (unsigned short*)alloc((size_t)4 * ROWS * 256 * 2);
  unsigned short* bc = (unsigned short*)alloc((size_t)4 * ROWS * 16 * 2);
  float* dtv_arr = (float*)alloc((size_t)16 * ROWS * 4);
  float* dA_arr = (float*)alloc((size_t)16 * ROWS * 4);
  unsigned short* ybf = (unsigned short*)alloc((size_t)4 * ROWS * 256 * 2);
  float* S = (float*)alloc((size_t)4 * NCHUNK * 8 * 512 * 4);
  float* P = (float*)alloc((size_t)4 * NCHUNK * 8 * 4);
  float* carry = (float*)alloc((size_t)4 * NCHUNK * 8 * 512 * 4);
  int* inv = (int*)alloc((size_t)ROWS * 4);

  // conversions
  k_cvt2<<<dim3(ROWS * 256 / 4 / 256, 2), 256, 0, stream>>>(x_H, x_V, xbf);
  k_cvtT_in<<<2 * NPAD * 256 / 256, 256, 0, stream>>>(W_in_H, W_in_V, Wt_in);
  P4 wdirs;  // cat order: dir0 HF->W_out_HB, dir1 HB->W_out_HF, dir2 VF->W_out_VB, dir3 VB->W_out_VF
  wdirs.p[0] = W_out_HB; wdirs.p[1] = W_out_HF; wdirs.p[2] = W_out_VB; wdirs.p[3] = W_out_VF;
  k_prep<<<2112, 256, 0, stream>>>(wdirs, W_out, v2h, Wt_dirs, Wt_fin, inv);

  ScanConsts sc;
  sc.dt_bias[0] = dt_bias_HF; sc.dt_bias[1] = dt_bias_HB;
  sc.dt_bias[2] = dt_bias_VF; sc.dt_bias[3] = dt_bias_VB;
  sc.A_log[0] = A_log_HF; sc.A_log[1] = A_log_HB;
  sc.A_log[2] = A_log_VF; sc.A_log[3] = A_log_VB;
  sc.D[0] = D_HF; sc.D[1] = D_HB; sc.D[2] = D_VF; sc.D[3] = D_VB;

  EpiIn ep; ep.zsil = zsil; ep.xsil = xsil; ep.bc = bc;

  // input GEMMs (batched over 2 mats), routing epilogue -> zsil/xsil/bc bf16
  k_gemm2<2><<<dim3(ROWS / 128, NPAD / 128, 2), 256, 0, stream>>>(
      xbf, (long)ROWS * 256, Wt_in, (long)NPAD * 256, nullptr, 256, 0, nullptr, ep);
  // exact fp32 dt -> dtv, dA
  k_dtfix<<<dim3(ROWS / 32, 2), 256, 0, stream>>>(x_H, x_V, W_in_H, W_in_V, sc, dtv_arr, dA_arr);

  ScanP sp;
  sp.xsil = xsil; sp.zsil = zsil; sp.bc = bc; sp.dtv = dtv_arr; sp.dA = dA_arr;
  sp.D[0] = D_HF; sp.D[1] = D_HB; sp.D[2] = D_VF; sp.D[3] = D_VB;

  k_scan1<<<dim3(NCHUNK, 8, 4), 64, 0, stream>>>(sp, S, P);
  k_scan2<<<32, 512, 0, stream>>>(S, P, carry);
  k_scan3<<<dim3(NCHUNK, 8, 4), 64, 0, stream>>>(sp, carry, ybf);

  // fused out-proj + final GEMM -> d_out (fp32)
  k_fuse<<<ROWS / 64, 256, 0, stream>>>(ybf, Wt_dirs, Wt_fin, inv, (float*)d_out);

  (void)in_sizes; (void)n_in; (void)out_size; (void)ws_size;
}

// Round 8
// 317.086 us; speedup vs baseline: 1.3495x; 1.0563x over previous
//
#include <hip/hip_runtime.h>
#include <hip/hip_bf16.h>

// ---------------- problem constants ----------------
#define B_N 2
#define L_N 8192
#define ROWS 16384                // B_N * L_N
#define CHUNK 64
#define NCHUNK 128                // L_N / CHUNK
#define NPAD 1152                 // input-proj N padded: 2 x 544 + pad to 9*128

typedef __bf16 bf16x8 __attribute__((ext_vector_type(8)));
typedef float f32x4 __attribute__((ext_vector_type(4)));

__device__ __forceinline__ float siluf(float v) { return v / (1.f + __expf(-v)); }
__device__ __forceinline__ float softplusf_(float v) {
  return fmaxf(v, 0.f) + log1pf(__expf(-fabsf(v)));
}
__device__ __forceinline__ unsigned short f2bf(float v) {
  union { float f; unsigned u; } x; x.f = v;
  unsigned r = x.u + 0x7fffu + ((x.u >> 16) & 1u);
  return (unsigned short)(r >> 16);
}
__device__ __forceinline__ float bf2f(unsigned short u) {
  union { unsigned u; float f; } x; x.u = ((unsigned)u) << 16;
  return x.f;
}

// async global->LDS, 16B per lane, LDS dest = wave-uniform base + lane*16
__device__ __forceinline__ void gload_lds16(const unsigned short* g, unsigned short* l) {
  __builtin_amdgcn_global_load_lds(
      (const __attribute__((address_space(1))) unsigned int*)g,
      (__attribute__((address_space(3))) unsigned int*)l, 16, 0, 0);
}

struct P4 { const float* p[4]; };

// ---------------- fused prep: xbf cvt | Wt_in | Wt_dirs | Wt_fin | inv ----------------
// blocks [0,8192): x->bf16 (2 mats); [8192,10496): Wt_in; [10496,11520): Wt_dirs;
// [11520,12544): Wt_fin; [12544,12608): inv
__global__ void k_prep_all(const float* __restrict__ xH, const float* __restrict__ xV,
                           const float* __restrict__ WH, const float* __restrict__ WV,
                           P4 ws, const float* __restrict__ W_out, const int* __restrict__ v2h,
                           unsigned short* __restrict__ xbf, unsigned short* __restrict__ Wt_in,
                           unsigned short* __restrict__ Wt_dirs, unsigned short* __restrict__ Wt_fin,
                           int* __restrict__ inv) {
  int bid = blockIdx.x;
  int tid = threadIdx.x;
  if (bid < 8192) {
    int mat = bid >> 12;
    int i = (bid & 4095) * 256 + tid;         // float4 index
    const float* s = mat ? xV : xH;
    float4 v = ((const float4*)s)[i];
    ushort4 o;
    o.x = f2bf(v.x); o.y = f2bf(v.y); o.z = f2bf(v.z); o.w = f2bf(v.w);
    ((ushort4*)(xbf + (size_t)mat * ROWS * 256))[i] = o;
  } else if (bid < 10496) {
    int i = (bid - 8192) * 256 + tid;         // 2*1152*256
    int z = i / (NPAD * 256);
    int rem = i - z * (NPAD * 256);
    int n = rem >> 8, k = rem & 255;
    const float* W = z ? WV : WH;
    int sl = n >= 544;
    int cc = n - (sl ? 544 : 0);
    float v = (cc < 532) ? W[(long)k * 1064 + sl * 532 + cc] : 0.f;
    Wt_in[i] = f2bf(v);
  } else if (bid < 11520) {
    int i = (bid - 10496) * 256 + tid;        // 4*65536
    int d = i >> 16;
    int rem = i & 65535;
    int n = rem >> 8, k = rem & 255;
    Wt_dirs[i] = f2bf(ws.p[d][(long)k * 256 + n]);
  } else if (bid < 12544) {
    int i = (bid - 11520) * 256 + tid;        // 256*1024, i = n*1024+k
    int n = i >> 10, k = i & 1023;
    Wt_fin[i] = f2bf(W_out[(long)k * 256 + n]);
  } else {
    int m = (bid - 12544) * 256 + tid;
    if (m < ROWS) {
      int b = m >> 13;
      inv[b * L_N + v2h[m]] = m;              // inverse of the v->h scatter
    }
  }
}

struct ScanConsts {
  const float* dt_bias[4];
  const float* A_log[4];
  const float* D[4];
};

// exact fp32 dt dot with LDS staging; precompute dtv (softplus) and dA (exp(dt*A))
__global__ __launch_bounds__(256) void k_dtfix(
    const float* __restrict__ xH, const float* __restrict__ xV,
    const float* __restrict__ WH, const float* __restrict__ WV,
    ScanConsts sc, float* __restrict__ dtv_arr, float* __restrict__ dA_arr) {
  __shared__ float xs[32][257];
  __shared__ float Wsm[8][260];
  const int mat = blockIdx.y;
  const float* x = mat ? xV : xH;
  const float* W = mat ? WV : WH;
  const int r0 = blockIdx.x * 32;
  for (int i = threadIdx.x; i < 2048; i += 256) {
    int c = i >> 8, k = i & 255;              // c = sl*4+h
    int sl = c >> 2, h = c & 3;
    Wsm[c][k] = W[(long)k * 1064 + sl * 532 + 528 + h];
  }
  for (int i = threadIdx.x; i < 32 * 64; i += 256) {
    int rl = i >> 6, kq = (i & 63) * 4;
    float4 v = *(const float4*)(x + (long)(r0 + rl) * 256 + kq);
    xs[rl][kq + 0] = v.x; xs[rl][kq + 1] = v.y; xs[rl][kq + 2] = v.z; xs[rl][kq + 3] = v.w;
  }
  __syncthreads();
  const int rl = threadIdx.x >> 3, c = threadIdx.x & 7;
  float s = 0.f;
  #pragma unroll 8
  for (int k = 0; k < 256; ++k) s = fmaf(xs[rl][k], Wsm[c][k], s);
  const int sl = c >> 2, h = c & 3;
  const int dir = mat * 2 + sl;
  float dtv = softplusf_(s + sc.dt_bias[dir][h]);
  float dAv = __expf(dtv * (-__expf(sc.A_log[dir][h])));
  long o = ((long)dir * 4 + h) * ROWS + (r0 + rl);
  dtv_arr[o] = dtv;
  dA_arr[o] = dAv;
}

// ---------------- bf16 MFMA GEMM (128x128 tile, BK=32, async LDS staging) ----------------
struct EpiIn {
  unsigned short* zsil;   // [4][ROWS*256] silu(z)
  unsigned short* xsil;   // [4][ROWS*256] silu(x)
  unsigned short* bc;     // [4][ROWS*16]  silu(B)|silu(C)
};

// input-proj GEMM: A row-major bf16 (lda=K=256), Bt [n][k]. Routing epilogue via
// per-wave 16-row LDS transpose. Grid: x=row tiles, y=col tiles, z=mat.
__global__ __launch_bounds__(256) void k_gemm_in(
    const unsigned short* __restrict__ Abase, const unsigned short* __restrict__ Btbase,
    EpiIn ep) {
  __shared__ unsigned short As[128 * 32];
  __shared__ unsigned short Bs[128 * 32];
  __shared__ unsigned short trs[4][16 * 72];
  const int tid = threadIdx.x;
  const int lane = tid & 63;
  const int wid = tid >> 6;
  const int wm = wid & 1, wn = wid >> 1;
  const int q = lane >> 4, r = lane & 15;
  const int m0 = blockIdx.x * 128;
  const int n0 = blockIdx.y * 128;
  const int z = blockIdx.z;
  const unsigned short* A = Abase + (long)z * ROWS * 256;
  const unsigned short* Bt = Btbase + (long)z * NPAD * 256;

  f32x4 acc[4][4] = {};
  const int swr = (r >> 1) & 3;               // read-side swizzle

  for (int kt = 0; kt < 256; kt += 32) {
    #pragma unroll
    for (int i = 0; i < 2; ++i) {
      int idx = i * 256 + tid;
      int row = idx >> 2;
      int ch = (idx & 3) ^ ((row >> 1) & 3);
      gload_lds16(A + (long)(m0 + row) * 256 + kt + ch * 8,
                  &As[(size_t)(i * 256 + wid * 64) * 8]);
    }
    #pragma unroll
    for (int i = 0; i < 2; ++i) {
      int idx = i * 256 + tid;
      int row = idx >> 2;
      int ch = (idx & 3) ^ ((row >> 1) & 3);
      gload_lds16(Bt + (long)(n0 + row) * 256 + kt + ch * 8,
                  &Bs[(size_t)(i * 256 + wid * 64) * 8]);
    }
    __syncthreads();
    bf16x8 af[4], bfr[4];
    #pragma unroll
    for (int mi = 0; mi < 4; ++mi)
      af[mi] = *(const bf16x8*)&As[((wm * 64 + mi * 16 + r) * 4 + (q ^ swr)) * 8];
    #pragma unroll
    for (int ni = 0; ni < 4; ++ni)
      bfr[ni] = *(const bf16x8*)&Bs[((wn * 64 + ni * 16 + r) * 4 + (q ^ swr)) * 8];
    #pragma unroll
    for (int mi = 0; mi < 4; ++mi)
      #pragma unroll
      for (int ni = 0; ni < 4; ++ni)
        acc[mi][ni] = __builtin_amdgcn_mfma_f32_16x16x32_bf16(af[mi], bfr[ni], acc[mi][ni], 0, 0, 0);
    __syncthreads();
  }

  // per-wave dedicated transpose region: 16 rows x 72 cols
  unsigned short* tr = trs[wid];
  #pragma unroll
  for (int mi = 0; mi < 4; ++mi) {
    #pragma unroll
    for (int ni = 0; ni < 4; ++ni)
      #pragma unroll
      for (int j = 0; j < 4; ++j)
        tr[(q * 4 + j) * 72 + ni * 16 + r] = f2bf(siluf(acc[mi][ni][j]));
    asm volatile("s_waitcnt lgkmcnt(0)" ::: "memory");
    #pragma unroll
    for (int pass = 0; pass < 2; ++pass) {
      int rl = pass * 8 + (lane >> 3);
      int c8 = (lane & 7) * 8;
      bf16x8 v = *(const bf16x8*)&tr[rl * 72 + c8];
      int row = m0 + wm * 64 + mi * 16 + rl;
      int col = n0 + wn * 64 + c8;
      int sl = col >= 544;
      int cc = col - (sl ? 544 : 0);
      if (cc < 528) {
        int dir = z * 2 + sl;
        if (cc < 256)
          *(bf16x8*)(ep.zsil + ((long)dir * ROWS + row) * 256 + cc) = v;
        else if (cc < 512)
          *(bf16x8*)(ep.xsil + ((long)dir * ROWS + row) * 256 + cc - 256) = v;
        else
          *(bf16x8*)(ep.bc + ((long)dir * ROWS + row) * 16 + cc - 512) = v;
      }
    }
    asm volatile("s_waitcnt lgkmcnt(0)" ::: "memory");
  }
}

// ---------------- fused out-proj + final GEMM, split by dir pair ----------------
// Grid (ROWS/64, 2). Block (rb, pair): for d in {2*pair, 2*pair+1}:
//   T = silu(y_d[rows] @ Wd); partial += T @ Wout[d*256:,:]
// pair 1 (V dirs) gathers y rows via inv. Writes fp32 partial; k_red sums the two.
__global__ __launch_bounds__(256) void k_fuse(
    const unsigned short* __restrict__ ybf,      // [4][ROWS][256]
    const unsigned short* __restrict__ Wt_dirs,  // [4][256 n][256 k]
    const unsigned short* __restrict__ Wt_fin,   // [256 c][1024 k] (k = d*256+kk)
    const int* __restrict__ inv,
    float* __restrict__ pbuf) {                  // [2][ROWS*256]
  __shared__ unsigned short Tl[64][264];         // silu'd T, row-major, pad 264
  __shared__ unsigned short As1[64 * 32];        // y-tile staging
  __shared__ unsigned short Bs1[256 * 32];       // weight staging (both gemms)
  __shared__ int arow[64];
  const int tid = threadIdx.x;
  const int lane = tid & 63;
  const int wid = tid >> 6;
  const int q = lane >> 4, r = lane & 15;
  const int r0 = blockIdx.x * 64;
  const int pair = blockIdx.y;
  const int swr = (r >> 1) & 3;

  if (tid < 64) arow[tid] = pair ? inv[r0 + tid] : (r0 + tid);
  __syncthreads();

  f32x4 acc_o[4][4] = {};

  #pragma unroll
  for (int dd = 0; dd < 2; ++dd) {
    const int d = pair * 2 + dd;
    const unsigned short* yd = ybf + (long)d * ROWS * 256;
    const unsigned short* Wd = Wt_dirs + (long)d * 65536;

    f32x4 acc_t[4][4] = {};
    // ---- first GEMM: T = y_d[rows,:] @ Wd  (K=256) ----
    for (int kt = 0; kt < 256; kt += 32) {
      {
        int row = tid >> 2;
        int ch = (tid & 3) ^ ((row >> 1) & 3);
        gload_lds16(yd + (long)arow[row] * 256 + kt + ch * 8, &As1[(size_t)(wid * 64) * 8]);
      }
      #pragma unroll
      for (int i = 0; i < 4; ++i) {
        int idx = i * 256 + tid;
        int row = idx >> 2;
        int ch = (idx & 3) ^ ((row >> 1) & 3);
        gload_lds16(Wd + (long)row * 256 + kt + ch * 8,
                    &Bs1[(size_t)(i * 256 + wid * 64) * 8]);
      }
      __syncthreads();
      bf16x8 af[4], bfr[4];
      #pragma unroll
      for (int mi = 0; mi < 4; ++mi)
        af[mi] = *(const bf16x8*)&As1[((mi * 16 + r) * 4 + (q ^ swr)) * 8];
      #pragma unroll
      for (int ni = 0; ni < 4; ++ni)
        bfr[ni] = *(const bf16x8*)&Bs1[((wid * 64 + ni * 16 + r) * 4 + (q ^ swr)) * 8];
      #pragma unroll
      for (int mi = 0; mi < 4; ++mi)
        #pragma unroll
        for (int ni = 0; ni < 4; ++ni)
          acc_t[mi][ni] = __builtin_amdgcn_mfma_f32_16x16x32_bf16(af[mi], bfr[ni], acc_t[mi][ni], 0, 0, 0);
      __syncthreads();
    }
    // ---- write silu(T) to LDS (row-major) ----
    #pragma unroll
    for (int mi = 0; mi < 4; ++mi)
      #pragma unroll
      for (int ni = 0; ni < 4; ++ni)
        #pragma unroll
        for (int j = 0; j < 4; ++j)
          Tl[mi * 16 + q * 4 + j][wid * 64 + ni * 16 + r] = f2bf(siluf(acc_t[mi][ni][j]));
    __syncthreads();
    // ---- second GEMM: acc_o += T @ Wout[d*256+kk][c], A from Tl ----
    for (int kt = 0; kt < 256; kt += 32) {
      #pragma unroll
      for (int i = 0; i < 4; ++i) {
        int idx = i * 256 + tid;
        int row = idx >> 2;                    // out col c
        int ch = (idx & 3) ^ ((row >> 1) & 3);
        gload_lds16(Wt_fin + (long)row * 1024 + d * 256 + kt + ch * 8,
                    &Bs1[(size_t)(i * 256 + wid * 64) * 8]);
      }
      __syncthreads();
      bf16x8 af[4], bfr[4];
      #pragma unroll
      for (int mi = 0; mi < 4; ++mi)
        af[mi] = *(const bf16x8*)&Tl[mi * 16 + r][kt + q * 8];
      #pragma unroll
      for (int ni = 0; ni < 4; ++ni)
        bfr[ni] = *(const bf16x8*)&Bs1[((wid * 64 + ni * 16 + r) * 4 + (q ^ swr)) * 8];
      #pragma unroll
      for (int mi = 0; mi < 4; ++mi)
        #pragma unroll
        for (int ni = 0; ni < 4; ++ni)
          acc_o[mi][ni] = __builtin_amdgcn_mfma_f32_16x16x32_bf16(af[mi], bfr[ni], acc_o[mi][ni], 0, 0, 0);
      __syncthreads();
    }
  }

  float* pout = pbuf + (long)pair * ROWS * 256;
  #pragma unroll
  for (int mi = 0; mi < 4; ++mi)
    #pragma unroll
    for (int j = 0; j < 4; ++j) {
      int row = r0 + mi * 16 + q * 4 + j;
      #pragma unroll
      for (int ni = 0; ni < 4; ++ni) {
        int col = wid * 64 + ni * 16 + r;
        pout[(long)row * 256 + col] = acc_o[mi][ni][j];
      }
    }
}

// sum the two pair partials into d_out
__global__ void k_red(const float* __restrict__ pbuf, float* __restrict__ out) {
  int i = blockIdx.x * 256 + threadIdx.x;     // float4 index, ROWS*256/4 total
  float4 a = ((const float4*)pbuf)[i];
  float4 b = ((const float4*)(pbuf + (size_t)ROWS * 256))[i];
  float4 o;
  o.x = a.x + b.x; o.y = a.y + b.y; o.z = a.z + b.z; o.w = a.w + b.w;
  ((float4*)out)[i] = o;
}

// ---------------- scan kernels ----------------
struct ScanP {
  const unsigned short* xsil;  // [4][ROWS*256]
  const unsigned short* zsil;
  const unsigned short* bc;    // [4][ROWS*16]
  const float* dtv;            // [16][ROWS]  (dir*4+h)
  const float* dA;
  const float* D[4];
};

// phase 1: per-chunk (64 steps) local scan from zero; write end-state S and cum-dA P
__global__ __launch_bounds__(64) void k_scan1(ScanP sp, float* __restrict__ S,
                                              float* __restrict__ P) {
  __shared__ __align__(16) float Bst[64][8];
  __shared__ float dAs[64];
  const int p = threadIdx.x;
  const int c = blockIdx.x;
  const int bh = blockIdx.y;
  const int d = blockIdx.z;
  const int b = bh >> 2, h = bh & 3;
  const int rev = d & 1;
  const int t0 = c * CHUNK;
  {
    const int t = t0 + p;
    const int l = rev ? (L_N - 1 - t) : t;
    const int row = (b << 13) + l;
    uint4 bv = *(const uint4*)(sp.bc + ((long)d * ROWS + row) * 16);
    const unsigned short* bu = (const unsigned short*)&bv;
    float dtvv = sp.dtv[((long)d * 4 + h) * ROWS + row];
    dAs[p] = sp.dA[((long)d * 4 + h) * ROWS + row];
    #pragma unroll
    for (int n = 0; n < 8; ++n) Bst[p][n] = bf2f(bu[n]) * dtvv;
  }
  __syncthreads();

  float st[8] = {0, 0, 0, 0, 0, 0, 0, 0};
  float cumdA = 1.f;
  const int l0 = rev ? (L_N - 1 - t0) : t0;
  const unsigned short* xp = sp.xsil + ((long)d * ROWS + (b << 13) + l0) * 256 + h * 64 + p;
  const long stp = rev ? -256L : 256L;

  #pragma unroll 8
  for (int s = 0; s < 64; ++s) {
    float x = bf2f(xp[(long)s * stp]);
    float dA = dAs[s];
    f32x4 B0 = *(const f32x4*)&Bst[s][0];
    f32x4 B1 = *(const f32x4*)&Bst[s][4];
    cumdA *= dA;
    st[0] = fmaf(dA, st[0], x * B0[0]);
    st[1] = fmaf(dA, st[1], x * B0[1]);
    st[2] = fmaf(dA, st[2], x * B0[2]);
    st[3] = fmaf(dA, st[3], x * B0[3]);
    st[4] = fmaf(dA, st[4], x * B1[0]);
    st[5] = fmaf(dA, st[5], x * B1[1]);
    st[6] = fmaf(dA, st[6], x * B1[2]);
    st[7] = fmaf(dA, st[7], x * B1[3]);
  }
  float* Sp = S + ((((long)d * NCHUNK + c) * 8 + bh) * 64 + p) * 8;
  #pragma unroll
  for (int n = 0; n < 8; ++n) Sp[n] = st[n];
  if (p == 0) P[((long)d * NCHUNK + c) * 8 + bh] = cumdA;
}

// phase 2: sequential chunk-level combine -> carry-in per chunk
__global__ __launch_bounds__(512) void k_scan2(const float* __restrict__ S,
                                               const float* __restrict__ P,
                                               float* __restrict__ carry) {
  const int tid = threadIdx.x;
  const int dbh = blockIdx.x;
  const int d = dbh >> 3, bh = dbh & 7;
  float cy = 0.f;
  carry[(((long)d * NCHUNK + 0) * 8 + bh) * 512 + tid] = 0.f;
  #pragma unroll 4
  for (int c = 1; c < NCHUNK; ++c) {
    const float Pv = P[((long)d * NCHUNK + (c - 1)) * 8 + bh];
    const float Sv = S[(((long)d * NCHUNK + (c - 1)) * 8 + bh) * 512 + tid];
    cy = fmaf(Pv, cy, Sv);
    carry[(((long)d * NCHUNK + c) * 8 + bh) * 512 + tid] = cy;
  }
}

// phase 3: re-scan with carry-in, produce gated y in bf16
__global__ __launch_bounds__(64) void k_scan3(ScanP sp, const float* __restrict__ carry,
                                              unsigned short* __restrict__ ybf) {
  __shared__ __align__(16) float Bst[64][8];
  __shared__ __align__(16) float Cst[64][8];
  __shared__ float dAs[64];
  const int p = threadIdx.x;
  const int c = blockIdx.x;
  const int bh = blockIdx.y;
  const int d = blockIdx.z;
  const int b = bh >> 2, h = bh & 3;
  const int rev = d & 1;
  const float Dv = sp.D[d][h];
  const int t0 = c * CHUNK;
  {
    const int t = t0 + p;
    const int l = rev ? (L_N - 1 - t) : t;
    const int row = (b << 13) + l;
    const unsigned short* bp = sp.bc + ((long)d * ROWS + row) * 16;
    uint4 bv = *(const uint4*)bp;
    uint4 cv = *(const uint4*)(bp + 8);
    const unsigned short* bu = (const unsigned short*)&bv;
    const unsigned short* cu = (const unsigned short*)&cv;
    float dtvv = sp.dtv[((long)d * 4 + h) * ROWS + row];
    dAs[p] = sp.dA[((long)d * 4 + h) * ROWS + row];
    #pragma unroll
    for (int n = 0; n < 8; ++n) Bst[p][n] = bf2f(bu[n]) * dtvv;
    #pragma unroll
    for (int n = 0; n < 8; ++n) Cst[p][n] = bf2f(cu[n]);
  }
  __syncthreads();

  float st[8];
  {
    const float* cp = carry + ((((long)d * NCHUNK + c) * 8 + bh) * 64 + p) * 8;
    #pragma unroll
    for (int n = 0; n < 8; ++n) st[n] = cp[n];
  }

  const int l0 = rev ? (L_N - 1 - t0) : t0;
  const long base = (long)(b << 13) + l0;
  const unsigned short* xp = sp.xsil + ((long)d * ROWS + base) * 256 + h * 64 + p;
  const unsigned short* zp = sp.zsil + ((long)d * ROWS + base) * 256 + h * 64 + p;
  unsigned short* yp = ybf + ((long)d * ROWS + base) * 256 + h * 64 + p;
  const long stp = rev ? -256L : 256L;

  #pragma unroll 8
  for (int s = 0; s < 64; ++s) {
    float x = bf2f(xp[(long)s * stp]);
    float zv = bf2f(zp[(long)s * stp]);
    float dA = dAs[s];
    f32x4 B0 = *(const f32x4*)&Bst[s][0];
    f32x4 B1 = *(const f32x4*)&Bst[s][4];
    f32x4 C0 = *(const f32x4*)&Cst[s][0];
    f32x4 C1 = *(const f32x4*)&Cst[s][4];
    st[0] = fmaf(dA, st[0], x * B0[0]);
    st[1] = fmaf(dA, st[1], x * B0[1]);
    st[2] = fmaf(dA, st[2], x * B0[2]);
    st[3] = fmaf(dA, st[3], x * B0[3]);
    st[4] = fmaf(dA, st[4], x * B1[0]);
    st[5] = fmaf(dA, st[5], x * B1[1]);
    st[6] = fmaf(dA, st[6], x * B1[2]);
    st[7] = fmaf(dA, st[7], x * B1[3]);
    float y01 = fmaf(st[1], C0[1], st[0] * C0[0]);
    float y23 = fmaf(st[3], C0[3], st[2] * C0[2]);
    float y45 = fmaf(st[5], C1[1], st[4] * C1[0]);
    float y67 = fmaf(st[7], C1[3], st[6] * C1[2]);
    float y = (y01 + y23) + (y45 + y67);
    y = fmaf(Dv, x, y) * zv;
    yp[(long)s * stp] = f2bf(y);
  }
}

// ---------------- launch ----------------
extern "C" void kernel_launch(void* const* d_in, const int* in_sizes, int n_in,
                              void* d_out, int out_size, void* d_ws, size_t ws_size,
                              hipStream_t stream) {
  const float* x_H = (const float*)d_in[0];
  const float* x_V = (const float*)d_in[1];
  const float* W_in_H = (const float*)d_in[2];
  const float* W_in_V = (const float*)d_in[3];
  const float* W_out_HF = (const float*)d_in[4];
  const float* W_out_HB = (const float*)d_in[5];
  const float* W_out_VF = (const float*)d_in[6];
  const float* W_out_VB = (const float*)d_in[7];
  const float* W_out = (const float*)d_in[8];
  const float* dt_bias_HF = (const float*)d_in[9];
  const float* A_log_HF = (const float*)d_in[10];
  const float* D_HF = (const float*)d_in[11];
  const float* dt_bias_HB = (const float*)d_in[12];
  const float* A_log_HB = (const float*)d_in[13];
  const float* D_HB = (const float*)d_in[14];
  const float* dt_bias_VF = (const float*)d_in[15];
  const float* A_log_VF = (const float*)d_in[16];
  const float* D_VF = (const float*)d_in[17];
  const float* dt_bias_VB = (const float*)d_in[18];
  const float* A_log_VB = (const float*)d_in[19];
  const float* D_VB = (const float*)d_in[20];
  const int* v2h = (const int*)d_in[21];

  char* ws = (char*)d_ws;
  size_t off = 0;
  auto alloc = [&](size_t bytes) {
    void* pp = ws + off;
    off = (off + bytes + 255) & ~(size_t)255;
    return pp;
  };
  unsigned short* xbf = (unsigned short*)alloc((size_t)2 * ROWS * 256 * 2);      // [2 mats]
  unsigned short* Wt_in = (unsigned short*)alloc((size_t)2 * NPAD * 256 * 2);    // [2 mats]
  unsigned short* Wt_dirs = (unsigned short*)alloc((size_t)4 * 65536 * 2);
  unsigned short* Wt_fin = (unsigned short*)alloc((size_t)256 * 1024 * 2);
  unsigned short* zsil = (unsigned short*)alloc((size_t)4 * ROWS * 256 * 2);
  unsigned short* xsil = (unsigned short*)alloc((size_t)4 * ROWS * 256 * 2);
  unsigned short* bc = (unsigned short*)alloc((size_t)4 * ROWS * 16 * 2);
  float* dtv_arr = (float*)alloc((size_t)16 * ROWS * 4);
  float* dA_arr = (float*)alloc((size_t)16 * ROWS * 4);
  unsigned short* ybf = (unsigned short*)alloc((size_t)4 * ROWS * 256 * 2);
  float* S = (float*)alloc((size_t)4 * NCHUNK * 8 * 512 * 4);
  float* P = (float*)alloc((size_t)4 * NCHUNK * 8 * 4);
  float* carry = (float*)alloc((size_t)4 * NCHUNK * 8 * 512 * 4);
  int* inv = (int*)alloc((size_t)ROWS * 4);
  float* pbuf = (float*)alloc((size_t)2 * ROWS * 256 * 4);

  P4 wdirs;  // cat order: dir0 HF->W_out_HB, dir1 HB->W_out_HF, dir2 VF->W_out_VB, dir3 VB->W_out_VF
  wdirs.p[0] = W_out_HB; wdirs.p[1] = W_out_HF; wdirs.p[2] = W_out_VB; wdirs.p[3] = W_out_VF;
  k_prep_all<<<12608, 256, 0, stream>>>(x_H, x_V, W_in_H, W_in_V, wdirs, W_out, v2h,
                                        xbf, Wt_in, Wt_dirs, Wt_fin, inv);

  ScanConsts sc;
  sc.dt_bias[0] = dt_bias_HF; sc.dt_bias[1] = dt_bias_HB;
  sc.dt_bias[2] = dt_bias_VF; sc.dt_bias[3] = dt_bias_VB;
  sc.A_log[0] = A_log_HF; sc.A_log[1] = A_log_HB;
  sc.A_log[2] = A_log_VF; sc.A_log[3] = A_log_VB;
  sc.D[0] = D_HF; sc.D[1] = D_HB; sc.D[2] = D_VF; sc.D[3] = D_VB;

  EpiIn ep; ep.zsil = zsil; ep.xsil = xsil; ep.bc = bc;

  // input GEMMs (batched over 2 mats), routing epilogue -> zsil/xsil/bc bf16
  k_gemm_in<<<dim3(ROWS / 128, NPAD / 128, 2), 256, 0, stream>>>(xbf, Wt_in, ep);
  // exact fp32 dt -> dtv, dA
  k_dtfix<<<dim3(ROWS / 32, 2), 256, 0, stream>>>(x_H, x_V, W_in_H, W_in_V, sc, dtv_arr, dA_arr);

  ScanP sp;
  sp.xsil = xsil; sp.zsil = zsil; sp.bc = bc; sp.dtv = dtv_arr; sp.dA = dA_arr;
  sp.D[0] = D_HF; sp.D[1] = D_HB; sp.D[2] = D_VF; sp.D[3] = D_VB;

  k_scan1<<<dim3(NCHUNK, 8, 4), 64, 0, stream>>>(sp, S, P);
  k_scan2<<<32, 512, 0, stream>>>(S, P, carry);
  k_scan3<<<dim3(NCHUNK, 8, 4), 64, 0, stream>>>(sp, carry, ybf);

  // fused out-proj + final GEMM, split by dir pair -> fp32 partials
  k_fuse<<<dim3(ROWS / 64, 2), 256, 0, stream>>>(ybf, Wt_dirs, Wt_fin, inv, pbuf);
  // sum partials -> d_out
  k_red<<<ROWS * 256 / 4 / 256, 256, 0, stream>>>(pbuf, (float*)d_out);

  (void)in_sizes; (void)n_in; (void)out_size; (void)ws_size;
}

// Round 9
// 285.888 us; speedup vs baseline: 1.4968x; 1.1091x over previous
//
#include <hip/hip_runtime.h>
#include <hip/hip_bf16.h>

// ---------------- problem constants ----------------
#define B_N 2
#define L_N 8192
#define ROWS 16384                // B_N * L_N
#define CHUNK 32
#define NCHUNK 256                // L_N / CHUNK
#define NPAD 1152                 // input-proj N padded: 2 x 544 + pad to 9*128

typedef __bf16 bf16x8 __attribute__((ext_vector_type(8)));
typedef float f32x4 __attribute__((ext_vector_type(4)));

__device__ __forceinline__ float siluf(float v) { return v / (1.f + __expf(-v)); }
__device__ __forceinline__ float softplusf_(float v) {
  return fmaxf(v, 0.f) + log1pf(__expf(-fabsf(v)));
}
__device__ __forceinline__ unsigned short f2bf(float v) {
  union { float f; unsigned u; } x; x.f = v;
  unsigned r = x.u + 0x7fffu + ((x.u >> 16) & 1u);
  return (unsigned short)(r >> 16);
}
__device__ __forceinline__ float bf2f(unsigned short u) {
  union { unsigned u; float f; } x; x.u = ((unsigned)u) << 16;
  return x.f;
}

// async global->LDS, 16B per lane, LDS dest = wave-uniform base + lane*16
__device__ __forceinline__ void gload_lds16(const unsigned short* g, unsigned short* l) {
  __builtin_amdgcn_global_load_lds(
      (const __attribute__((address_space(1))) unsigned int*)g,
      (__attribute__((address_space(3))) unsigned int*)l, 16, 0, 0);
}

struct P4 { const float* p[4]; };

// ---------------- fused prep: xbf cvt | Wt_in | Wt_dirs | Wt_fin | inv ----------------
__global__ void k_prep_all(const float* __restrict__ xH, const float* __restrict__ xV,
                           const float* __restrict__ WH, const float* __restrict__ WV,
                           P4 ws, const float* __restrict__ W_out, const int* __restrict__ v2h,
                           unsigned short* __restrict__ xbf, unsigned short* __restrict__ Wt_in,
                           unsigned short* __restrict__ Wt_dirs, unsigned short* __restrict__ Wt_fin,
                           int* __restrict__ inv) {
  int bid = blockIdx.x;
  int tid = threadIdx.x;
  if (bid < 8192) {
    int mat = bid >> 12;
    int i = (bid & 4095) * 256 + tid;         // float4 index
    const float* s = mat ? xV : xH;
    float4 v = ((const float4*)s)[i];
    ushort4 o;
    o.x = f2bf(v.x); o.y = f2bf(v.y); o.z = f2bf(v.z); o.w = f2bf(v.w);
    ((ushort4*)(xbf + (size_t)mat * ROWS * 256))[i] = o;
  } else if (bid < 10496) {
    int i = (bid - 8192) * 256 + tid;         // 2*1152*256
    int z = i / (NPAD * 256);
    int rem = i - z * (NPAD * 256);
    int n = rem >> 8, k = rem & 255;
    const float* W = z ? WV : WH;
    int sl = n >= 544;
    int cc = n - (sl ? 544 : 0);
    float v = (cc < 532) ? W[(long)k * 1064 + sl * 532 + cc] : 0.f;
    Wt_in[i] = f2bf(v);
  } else if (bid < 11520) {
    int i = (bid - 10496) * 256 + tid;        // 4*65536
    int d = i >> 16;
    int rem = i & 65535;
    int n = rem >> 8, k = rem & 255;
    Wt_dirs[i] = f2bf(ws.p[d][(long)k * 256 + n]);
  } else if (bid < 12544) {
    int i = (bid - 11520) * 256 + tid;        // 256*1024, i = n*1024+k
    int n = i >> 10, k = i & 1023;
    Wt_fin[i] = f2bf(W_out[(long)k * 256 + n]);
  } else {
    int m = (bid - 12544) * 256 + tid;
    if (m < ROWS) {
      int b = m >> 13;
      inv[b * L_N + v2h[m]] = m;              // inverse of the v->h scatter
    }
  }
}

struct ScanConsts {
  const float* dt_bias[4];
  const float* A_log[4];
  const float* D[4];
};

// exact fp32 dt dot with LDS staging; precompute dtv (softplus) and dA (exp(dt*A))
__global__ __launch_bounds__(256) void k_dtfix(
    const float* __restrict__ xH, const float* __restrict__ xV,
    const float* __restrict__ WH, const float* __restrict__ WV,
    ScanConsts sc, float* __restrict__ dtv_arr, float* __restrict__ dA_arr) {
  __shared__ float xs[32][257];
  __shared__ float Wsm[8][260];
  const int mat = blockIdx.y;
  const float* x = mat ? xV : xH;
  const float* W = mat ? WV : WH;
  const int r0 = blockIdx.x * 32;
  for (int i = threadIdx.x; i < 2048; i += 256) {
    int c = i >> 8, k = i & 255;              // c = sl*4+h
    int sl = c >> 2, h = c & 3;
    Wsm[c][k] = W[(long)k * 1064 + sl * 532 + 528 + h];
  }
  for (int i = threadIdx.x; i < 32 * 64; i += 256) {
    int rl = i >> 6, kq = (i & 63) * 4;
    float4 v = *(const float4*)(x + (long)(r0 + rl) * 256 + kq);
    xs[rl][kq + 0] = v.x; xs[rl][kq + 1] = v.y; xs[rl][kq + 2] = v.z; xs[rl][kq + 3] = v.w;
  }
  __syncthreads();
  const int rl = threadIdx.x >> 3, c = threadIdx.x & 7;
  float s = 0.f;
  #pragma unroll 8
  for (int k = 0; k < 256; ++k) s = fmaf(xs[rl][k], Wsm[c][k], s);
  const int sl = c >> 2, h = c & 3;
  const int dir = mat * 2 + sl;
  float dtv = softplusf_(s + sc.dt_bias[dir][h]);
  float dAv = __expf(dtv * (-__expf(sc.A_log[dir][h])));
  long o = ((long)dir * 4 + h) * ROWS + (r0 + rl);
  dtv_arr[o] = dtv;
  dA_arr[o] = dAv;
}

// ---------------- bf16 MFMA GEMM (128x128 tile, BK=32, async LDS staging) ----------------
struct EpiIn {
  unsigned short* zsil;   // [4][ROWS*256] silu(z)
  unsigned short* xsil;   // [4][ROWS*256] silu(x)
  unsigned short* bc;     // [4][ROWS*16]  silu(B)|silu(C)
};

// input-proj GEMM: A row-major bf16 (lda=K=256), Bt [n][k]. Routing epilogue via
// per-wave 16-row LDS transpose. Grid: x=row tiles, y=col tiles, z=mat.
__global__ __launch_bounds__(256) void k_gemm_in(
    const unsigned short* __restrict__ Abase, const unsigned short* __restrict__ Btbase,
    EpiIn ep) {
  __shared__ unsigned short As[128 * 32];
  __shared__ unsigned short Bs[128 * 32];
  __shared__ unsigned short trs[4][16 * 72];
  const int tid = threadIdx.x;
  const int lane = tid & 63;
  const int wid = tid >> 6;
  const int wm = wid & 1, wn = wid >> 1;
  const int q = lane >> 4, r = lane & 15;
  const int m0 = blockIdx.x * 128;
  const int n0 = blockIdx.y * 128;
  const int z = blockIdx.z;
  const unsigned short* A = Abase + (long)z * ROWS * 256;
  const unsigned short* Bt = Btbase + (long)z * NPAD * 256;

  f32x4 acc[4][4] = {};
  const int swr = (r >> 1) & 3;               // read-side swizzle

  for (int kt = 0; kt < 256; kt += 32) {
    #pragma unroll
    for (int i = 0; i < 2; ++i) {
      int idx = i * 256 + tid;
      int row = idx >> 2;
      int ch = (idx & 3) ^ ((row >> 1) & 3);
      gload_lds16(A + (long)(m0 + row) * 256 + kt + ch * 8,
                  &As[(size_t)(i * 256 + wid * 64) * 8]);
    }
    #pragma unroll
    for (int i = 0; i < 2; ++i) {
      int idx = i * 256 + tid;
      int row = idx >> 2;
      int ch = (idx & 3) ^ ((row >> 1) & 3);
      gload_lds16(Bt + (long)(n0 + row) * 256 + kt + ch * 8,
                  &Bs[(size_t)(i * 256 + wid * 64) * 8]);
    }
    __syncthreads();
    bf16x8 af[4], bfr[4];
    #pragma unroll
    for (int mi = 0; mi < 4; ++mi)
      af[mi] = *(const bf16x8*)&As[((wm * 64 + mi * 16 + r) * 4 + (q ^ swr)) * 8];
    #pragma unroll
    for (int ni = 0; ni < 4; ++ni)
      bfr[ni] = *(const bf16x8*)&Bs[((wn * 64 + ni * 16 + r) * 4 + (q ^ swr)) * 8];
    #pragma unroll
    for (int mi = 0; mi < 4; ++mi)
      #pragma unroll
      for (int ni = 0; ni < 4; ++ni)
        acc[mi][ni] = __builtin_amdgcn_mfma_f32_16x16x32_bf16(af[mi], bfr[ni], acc[mi][ni], 0, 0, 0);
    __syncthreads();
  }

  // per-wave dedicated transpose region: 16 rows x 72 cols
  unsigned short* tr = trs[wid];
  #pragma unroll
  for (int mi = 0; mi < 4; ++mi) {
    #pragma unroll
    for (int ni = 0; ni < 4; ++ni)
      #pragma unroll
      for (int j = 0; j < 4; ++j)
        tr[(q * 4 + j) * 72 + ni * 16 + r] = f2bf(siluf(acc[mi][ni][j]));
    asm volatile("s_waitcnt lgkmcnt(0)" ::: "memory");
    #pragma unroll
    for (int pass = 0; pass < 2; ++pass) {
      int rl = pass * 8 + (lane >> 3);
      int c8 = (lane & 7) * 8;
      bf16x8 v = *(const bf16x8*)&tr[rl * 72 + c8];
      int row = m0 + wm * 64 + mi * 16 + rl;
      int col = n0 + wn * 64 + c8;
      int sl = col >= 544;
      int cc = col - (sl ? 544 : 0);
      if (cc < 528) {
        int dir = z * 2 + sl;
        if (cc < 256)
          *(bf16x8*)(ep.zsil + ((long)dir * ROWS + row) * 256 + cc) = v;
        else if (cc < 512)
          *(bf16x8*)(ep.xsil + ((long)dir * ROWS + row) * 256 + cc - 256) = v;
        else
          *(bf16x8*)(ep.bc + ((long)dir * ROWS + row) * 16 + cc - 512) = v;
      }
    }
    asm volatile("s_waitcnt lgkmcnt(0)" ::: "memory");
  }
}

// ---------------- fused out-proj + final GEMM, split by dir pair ----------------
__global__ __launch_bounds__(256) void k_fuse(
    const unsigned short* __restrict__ ybf,      // [4][ROWS][256]
    const unsigned short* __restrict__ Wt_dirs,  // [4][256 n][256 k]
    const unsigned short* __restrict__ Wt_fin,   // [256 c][1024 k] (k = d*256+kk)
    const int* __restrict__ inv,
    float* __restrict__ pbuf) {                  // [2][ROWS*256]
  __shared__ unsigned short Tl[64][264];         // silu'd T, row-major, pad 264
  __shared__ unsigned short As1[64 * 32];        // y-tile staging
  __shared__ unsigned short Bs1[256 * 32];       // weight staging (both gemms)
  __shared__ int arow[64];
  const int tid = threadIdx.x;
  const int lane = tid & 63;
  const int wid = tid >> 6;
  const int q = lane >> 4, r = lane & 15;
  const int r0 = blockIdx.x * 64;
  const int pair = blockIdx.y;
  const int swr = (r >> 1) & 3;

  if (tid < 64) arow[tid] = pair ? inv[r0 + tid] : (r0 + tid);
  __syncthreads();

  f32x4 acc_o[4][4] = {};

  #pragma unroll
  for (int dd = 0; dd < 2; ++dd) {
    const int d = pair * 2 + dd;
    const unsigned short* yd = ybf + (long)d * ROWS * 256;
    const unsigned short* Wd = Wt_dirs + (long)d * 65536;

    f32x4 acc_t[4][4] = {};
    // ---- first GEMM: T = y_d[rows,:] @ Wd  (K=256) ----
    for (int kt = 0; kt < 256; kt += 32) {
      {
        int row = tid >> 2;
        int ch = (tid & 3) ^ ((row >> 1) & 3);
        gload_lds16(yd + (long)arow[row] * 256 + kt + ch * 8, &As1[(size_t)(wid * 64) * 8]);
      }
      #pragma unroll
      for (int i = 0; i < 4; ++i) {
        int idx = i * 256 + tid;
        int row = idx >> 2;
        int ch = (idx & 3) ^ ((row >> 1) & 3);
        gload_lds16(Wd + (long)row * 256 + kt + ch * 8,
                    &Bs1[(size_t)(i * 256 + wid * 64) * 8]);
      }
      __syncthreads();
      bf16x8 af[4], bfr[4];
      #pragma unroll
      for (int mi = 0; mi < 4; ++mi)
        af[mi] = *(const bf16x8*)&As1[((mi * 16 + r) * 4 + (q ^ swr)) * 8];
      #pragma unroll
      for (int ni = 0; ni < 4; ++ni)
        bfr[ni] = *(const bf16x8*)&Bs1[((wid * 64 + ni * 16 + r) * 4 + (q ^ swr)) * 8];
      #pragma unroll
      for (int mi = 0; mi < 4; ++mi)
        #pragma unroll
        for (int ni = 0; ni < 4; ++ni)
          acc_t[mi][ni] = __builtin_amdgcn_mfma_f32_16x16x32_bf16(af[mi], bfr[ni], acc_t[mi][ni], 0, 0, 0);
      __syncthreads();
    }
    // ---- write silu(T) to LDS (row-major) ----
    #pragma unroll
    for (int mi = 0; mi < 4; ++mi)
      #pragma unroll
      for (int ni = 0; ni < 4; ++ni)
        #pragma unroll
        for (int j = 0; j < 4; ++j)
          Tl[mi * 16 + q * 4 + j][wid * 64 + ni * 16 + r] = f2bf(siluf(acc_t[mi][ni][j]));
    __syncthreads();
    // ---- second GEMM: acc_o += T @ Wout[d*256+kk][c], A from Tl ----
    for (int kt = 0; kt < 256; kt += 32) {
      #pragma unroll
      for (int i = 0; i < 4; ++i) {
        int idx = i * 256 + tid;
        int row = idx >> 2;                    // out col c
        int ch = (idx & 3) ^ ((row >> 1) & 3);
        gload_lds16(Wt_fin + (long)row * 1024 + d * 256 + kt + ch * 8,
                    &Bs1[(size_t)(i * 256 + wid * 64) * 8]);
      }
      __syncthreads();
      bf16x8 af[4], bfr[4];
      #pragma unroll
      for (int mi = 0; mi < 4; ++mi)
        af[mi] = *(const bf16x8*)&Tl[mi * 16 + r][kt + q * 8];
      #pragma unroll
      for (int ni = 0; ni < 4; ++ni)
        bfr[ni] = *(const bf16x8*)&Bs1[((wid * 64 + ni * 16 + r) * 4 + (q ^ swr)) * 8];
      #pragma unroll
      for (int mi = 0; mi < 4; ++mi)
        #pragma unroll
        for (int ni = 0; ni < 4; ++ni)
          acc_o[mi][ni] = __builtin_amdgcn_mfma_f32_16x16x32_bf16(af[mi], bfr[ni], acc_o[mi][ni], 0, 0, 0);
      __syncthreads();
    }
  }

  float* pout = pbuf + (long)pair * ROWS * 256;
  #pragma unroll
  for (int mi = 0; mi < 4; ++mi)
    #pragma unroll
    for (int j = 0; j < 4; ++j) {
      int row = r0 + mi * 16 + q * 4 + j;
      #pragma unroll
      for (int ni = 0; ni < 4; ++ni) {
        int col = wid * 64 + ni * 16 + r;
        pout[(long)row * 256 + col] = acc_o[mi][ni][j];
      }
    }
}

// sum the two pair partials into d_out
__global__ void k_red(const float* __restrict__ pbuf, float* __restrict__ out) {
  int i = blockIdx.x * 256 + threadIdx.x;     // float4 index, ROWS*256/4 total
  float4 a = ((const float4*)pbuf)[i];
  float4 b = ((const float4*)(pbuf + (size_t)ROWS * 256))[i];
  float4 o;
  o.x = a.x + b.x; o.y = a.y + b.y; o.z = a.z + b.z; o.w = a.w + b.w;
  ((float4*)out)[i] = o;
}

// ---------------- scan kernels ----------------
struct ScanP {
  const unsigned short* xsil;  // [4][ROWS*256]
  const unsigned short* zsil;
  const unsigned short* bc;    // [4][ROWS*16]
  const float* dtv;            // [16][ROWS]  (dir*4+h)
  const float* dA;
  const float* D[4];
};

// phase 1: per-chunk (32 steps) local scan from zero; write end-state S and cum-dA P
__global__ __launch_bounds__(64) void k_scan1(ScanP sp, float* __restrict__ S,
                                              float* __restrict__ P) {
  __shared__ __align__(16) float Bst[CHUNK][8];
  __shared__ float dAs[CHUNK];
  const int p = threadIdx.x;
  const int c = blockIdx.x;
  const int bh = blockIdx.y;
  const int d = blockIdx.z;
  const int b = bh >> 2, h = bh & 3;
  const int rev = d & 1;
  const int t0 = c * CHUNK;
  if (p < CHUNK) {
    const int t = t0 + p;
    const int l = rev ? (L_N - 1 - t) : t;
    const int row = (b << 13) + l;
    uint4 bv = *(const uint4*)(sp.bc + ((long)d * ROWS + row) * 16);
    const unsigned short* bu = (const unsigned short*)&bv;
    float dtvv = sp.dtv[((long)d * 4 + h) * ROWS + row];
    dAs[p] = sp.dA[((long)d * 4 + h) * ROWS + row];
    #pragma unroll
    for (int n = 0; n < 8; ++n) Bst[p][n] = bf2f(bu[n]) * dtvv;
  }
  __syncthreads();

  float st[8] = {0, 0, 0, 0, 0, 0, 0, 0};
  float cumdA = 1.f;
  const int l0 = rev ? (L_N - 1 - t0) : t0;
  const unsigned short* xp = sp.xsil + ((long)d * ROWS + (b << 13) + l0) * 256 + h * 64 + p;
  const long stp = rev ? -256L : 256L;

  // double-buffered 8-step load groups
  unsigned short xa[8], xb[8];
  #pragma unroll
  for (int j = 0; j < 8; ++j) xa[j] = xp[(long)j * stp];
  #pragma unroll
  for (int g = 0; g < 4; ++g) {
    if (g < 3) {
      #pragma unroll
      for (int j = 0; j < 8; ++j) xb[j] = xp[(long)((g + 1) * 8 + j) * stp];
    }
    #pragma unroll
    for (int j = 0; j < 8; ++j) {
      int s = g * 8 + j;
      float x = bf2f(xa[j]);
      float dA = dAs[s];
      f32x4 B0 = *(const f32x4*)&Bst[s][0];
      f32x4 B1 = *(const f32x4*)&Bst[s][4];
      cumdA *= dA;
      st[0] = fmaf(dA, st[0], x * B0[0]);
      st[1] = fmaf(dA, st[1], x * B0[1]);
      st[2] = fmaf(dA, st[2], x * B0[2]);
      st[3] = fmaf(dA, st[3], x * B0[3]);
      st[4] = fmaf(dA, st[4], x * B1[0]);
      st[5] = fmaf(dA, st[5], x * B1[1]);
      st[6] = fmaf(dA, st[6], x * B1[2]);
      st[7] = fmaf(dA, st[7], x * B1[3]);
    }
    #pragma unroll
    for (int j = 0; j < 8; ++j) xa[j] = xb[j];
  }
  float* Sp = S + ((((long)d * NCHUNK + c) * 8 + bh) * 64 + p) * 8;
  #pragma unroll
  for (int n = 0; n < 8; ++n) Sp[n] = st[n];
  if (p == 0) P[((long)d * NCHUNK + c) * 8 + bh] = cumdA;
}

// phase 2: sequential chunk-level combine -> carry-in per chunk (P preloaded to LDS)
__global__ __launch_bounds__(512) void k_scan2(const float* __restrict__ S,
                                               const float* __restrict__ P,
                                               float* __restrict__ carry) {
  __shared__ float Pl[NCHUNK];
  const int tid = threadIdx.x;
  const int dbh = blockIdx.x;
  const int d = dbh >> 3, bh = dbh & 7;
  if (tid < NCHUNK) Pl[tid] = P[((long)d * NCHUNK + tid) * 8 + bh];
  __syncthreads();
  float cy = 0.f;
  carry[(((long)d * NCHUNK + 0) * 8 + bh) * 512 + tid] = 0.f;
  #pragma unroll 8
  for (int c = 1; c < NCHUNK; ++c) {
    const float Sv = S[(((long)d * NCHUNK + (c - 1)) * 8 + bh) * 512 + tid];
    cy = fmaf(Pl[c - 1], cy, Sv);
    carry[(((long)d * NCHUNK + c) * 8 + bh) * 512 + tid] = cy;
  }
}

// phase 3: re-scan with carry-in, produce gated y in bf16
__global__ __launch_bounds__(64) void k_scan3(ScanP sp, const float* __restrict__ carry,
                                              unsigned short* __restrict__ ybf) {
  __shared__ __align__(16) float Bst[CHUNK][8];
  __shared__ __align__(16) float Cst[CHUNK][8];
  __shared__ float dAs[CHUNK];
  const int p = threadIdx.x;
  const int c = blockIdx.x;
  const int bh = blockIdx.y;
  const int d = blockIdx.z;
  const int b = bh >> 2, h = bh & 3;
  const int rev = d & 1;
  const float Dv = sp.D[d][h];
  const int t0 = c * CHUNK;
  if (p < CHUNK) {
    const int t = t0 + p;
    const int l = rev ? (L_N - 1 - t) : t;
    const int row = (b << 13) + l;
    const unsigned short* bp = sp.bc + ((long)d * ROWS + row) * 16;
    uint4 bv = *(const uint4*)bp;
    uint4 cv = *(const uint4*)(bp + 8);
    const unsigned short* bu = (const unsigned short*)&bv;
    const unsigned short* cu = (const unsigned short*)&cv;
    float dtvv = sp.dtv[((long)d * 4 + h) * ROWS + row];
    dAs[p] = sp.dA[((long)d * 4 + h) * ROWS + row];
    #pragma unroll
    for (int n = 0; n < 8; ++n) Bst[p][n] = bf2f(bu[n]) * dtvv;
    #pragma unroll
    for (int n = 0; n < 8; ++n) Cst[p][n] = bf2f(cu[n]);
  }
  __syncthreads();

  float st[8];
  {
    const float* cp = carry + ((((long)d * NCHUNK + c) * 8 + bh) * 64 + p) * 8;
    #pragma unroll
    for (int n = 0; n < 8; ++n) st[n] = cp[n];
  }

  const int l0 = rev ? (L_N - 1 - t0) : t0;
  const long base = (long)(b << 13) + l0;
  const unsigned short* xp = sp.xsil + ((long)d * ROWS + base) * 256 + h * 64 + p;
  const unsigned short* zp = sp.zsil + ((long)d * ROWS + base) * 256 + h * 64 + p;
  unsigned short* yp = ybf + ((long)d * ROWS + base) * 256 + h * 64 + p;
  const long stp = rev ? -256L : 256L;

  // double-buffered 8-step load groups (x and z)
  unsigned short xa[8], xb[8], za[8], zb[8];
  #pragma unroll
  for (int j = 0; j < 8; ++j) { xa[j] = xp[(long)j * stp]; za[j] = zp[(long)j * stp]; }
  #pragma unroll
  for (int g = 0; g < 4; ++g) {
    if (g < 3) {
      #pragma unroll
      for (int j = 0; j < 8; ++j) {
        xb[j] = xp[(long)((g + 1) * 8 + j) * stp];
        zb[j] = zp[(long)((g + 1) * 8 + j) * stp];
      }
    }
    #pragma unroll
    for (int j = 0; j < 8; ++j) {
      int s = g * 8 + j;
      float x = bf2f(xa[j]);
      float zv = bf2f(za[j]);
      float dA = dAs[s];
      f32x4 B0 = *(const f32x4*)&Bst[s][0];
      f32x4 B1 = *(const f32x4*)&Bst[s][4];
      f32x4 C0 = *(const f32x4*)&Cst[s][0];
      f32x4 C1 = *(const f32x4*)&Cst[s][4];
      st[0] = fmaf(dA, st[0], x * B0[0]);
      st[1] = fmaf(dA, st[1], x * B0[1]);
      st[2] = fmaf(dA, st[2], x * B0[2]);
      st[3] = fmaf(dA, st[3], x * B0[3]);
      st[4] = fmaf(dA, st[4], x * B1[0]);
      st[5] = fmaf(dA, st[5], x * B1[1]);
      st[6] = fmaf(dA, st[6], x * B1[2]);
      st[7] = fmaf(dA, st[7], x * B1[3]);
      float y01 = fmaf(st[1], C0[1], st[0] * C0[0]);
      float y23 = fmaf(st[3], C0[3], st[2] * C0[2]);
      float y45 = fmaf(st[5], C1[1], st[4] * C1[0]);
      float y67 = fmaf(st[7], C1[3], st[6] * C1[2]);
      float y = (y01 + y23) + (y45 + y67);
      y = fmaf(Dv, x, y) * zv;
      yp[(long)s * stp] = f2bf(y);
    }
    #pragma unroll
    for (int j = 0; j < 8; ++j) { xa[j] = xb[j]; za[j] = zb[j]; }
  }
}

// ---------------- launch ----------------
extern "C" void kernel_launch(void* const* d_in, const int* in_sizes, int n_in,
                              void* d_out, int out_size, void* d_ws, size_t ws_size,
                              hipStream_t stream) {
  const float* x_H = (const float*)d_in[0];
  const float* x_V = (const float*)d_in[1];
  const float* W_in_H = (const float*)d_in[2];
  const float* W_in_V = (const float*)d_in[3];
  const float* W_out_HF = (const float*)d_in[4];
  const float* W_out_HB = (const float*)d_in[5];
  const float* W_out_VF = (const float*)d_in[6];
  const float* W_out_VB = (const float*)d_in[7];
  const float* W_out = (const float*)d_in[8];
  const float* dt_bias_HF = (const float*)d_in[9];
  const float* A_log_HF = (const float*)d_in[10];
  const float* D_HF = (const float*)d_in[11];
  const float* dt_bias_HB = (const float*)d_in[12];
  const float* A_log_HB = (const float*)d_in[13];
  const float* D_HB = (const float*)d_in[14];
  const float* dt_bias_VF = (const float*)d_in[15];
  const float* A_log_VF = (const float*)d_in[16];
  const float* D_VF = (const float*)d_in[17];
  const float* dt_bias_VB = (const float*)d_in[18];
  const float* A_log_VB = (const float*)d_in[19];
  const float* D_VB = (const float*)d_in[20];
  const int* v2h = (const int*)d_in[21];

  char* ws = (char*)d_ws;
  size_t off = 0;
  auto alloc = [&](size_t bytes) {
    void* pp = ws + off;
    off = (off + bytes + 255) & ~(size_t)255;
    return pp;
  };
  unsigned short* xbf = (unsigned short*)alloc((size_t)2 * ROWS * 256 * 2);      // [2 mats]
  unsigned short* Wt_in = (unsigned short*)alloc((size_t)2 * NPAD * 256 * 2);    // [2 mats]
  unsigned short* Wt_dirs = (unsigned short*)alloc((size_t)4 * 65536 * 2);
  unsigned short* Wt_fin = (unsigned short*)alloc((size_t)256 * 1024 * 2);
  unsigned short* zsil = (unsigned short*)alloc((size_t)4 * ROWS * 256 * 2);
  unsigned short* xsil = (unsigned short*)alloc((size_t)4 * ROWS * 256 * 2);
  unsigned short* bc = (unsigned short*)alloc((size_t)4 * ROWS * 16 * 2);
  float* dtv_arr = (float*)alloc((size_t)16 * ROWS * 4);
  float* dA_arr = (float*)alloc((size_t)16 * ROWS * 4);
  unsigned short* ybf = (unsigned short*)alloc((size_t)4 * ROWS * 256 * 2);
  float* S = (float*)alloc((size_t)4 * NCHUNK * 8 * 512 * 4);
  float* P = (float*)alloc((size_t)4 * NCHUNK * 8 * 4);
  float* carry = (float*)alloc((size_t)4 * NCHUNK * 8 * 512 * 4);
  int* inv = (int*)alloc((size_t)ROWS * 4);
  float* pbuf = (float*)alloc((size_t)2 * ROWS * 256 * 4);

  P4 wdirs;  // cat order: dir0 HF->W_out_HB, dir1 HB->W_out_HF, dir2 VF->W_out_VB, dir3 VB->W_out_VF
  wdirs.p[0] = W_out_HB; wdirs.p[1] = W_out_HF; wdirs.p[2] = W_out_VB; wdirs.p[3] = W_out_VF;
  k_prep_all<<<12608, 256, 0, stream>>>(x_H, x_V, W_in_H, W_in_V, wdirs, W_out, v2h,
                                        xbf, Wt_in, Wt_dirs, Wt_fin, inv);

  ScanConsts sc;
  sc.dt_bias[0] = dt_bias_HF; sc.dt_bias[1] = dt_bias_HB;
  sc.dt_bias[2] = dt_bias_VF; sc.dt_bias[3] = dt_bias_VB;
  sc.A_log[0] = A_log_HF; sc.A_log[1] = A_log_HB;
  sc.A_log[2] = A_log_VF; sc.A_log[3] = A_log_VB;
  sc.D[0] = D_HF; sc.D[1] = D_HB; sc.D[2] = D_VF; sc.D[3] = D_VB;

  EpiIn ep; ep.zsil = zsil; ep.xsil = xsil; ep.bc = bc;

  // input GEMMs (batched over 2 mats), routing epilogue -> zsil/xsil/bc bf16
  k_gemm_in<<<dim3(ROWS / 128, NPAD / 128, 2), 256, 0, stream>>>(xbf, Wt_in, ep);
  // exact fp32 dt -> dtv, dA
  k_dtfix<<<dim3(ROWS / 32, 2), 256, 0, stream>>>(x_H, x_V, W_in_H, W_in_V, sc, dtv_arr, dA_arr);

  ScanP sp;
  sp.xsil = xsil; sp.zsil = zsil; sp.bc = bc; sp.dtv = dtv_arr; sp.dA = dA_arr;
  sp.D[0] = D_HF; sp.D[1] = D_HB; sp.D[2] = D_VF; sp.D[3] = D_VB;

  k_scan1<<<dim3(NCHUNK, 8, 4), 64, 0, stream>>>(sp, S, P);
  k_scan2<<<32, 512, 0, stream>>>(S, P, carry);
  k_scan3<<<dim3(NCHUNK, 8, 4), 64, 0, stream>>>(sp, carry, ybf);

  // fused out-proj + final GEMM, split by dir pair -> fp32 partials
  k_fuse<<<dim3(ROWS / 64, 2), 256, 0, stream>>>(ybf, Wt_dirs, Wt_fin, inv, pbuf);
  // sum partials -> d_out
  k_red<<<ROWS * 256 / 4 / 256, 256, 0, stream>>>(pbuf, (float*)d_out);

  (void)in_sizes; (void)n_in; (void)out_size; (void)ws_size;
}

// Round 10
// 275.614 us; speedup vs baseline: 1.5526x; 1.0373x over previous
//
#include <hip/hip_runtime.h>
#include <hip/hip_bf16.h>

// ---------------- problem constants ----------------
#define B_N 2
#define L_N 8192
#define ROWS 16384                // B_N * L_N
#define CHUNK 32
#define NCHUNK 256                // L_N / CHUNK
#define NPAD 1152                 // input-proj N padded: 2 x 544 + pad to 9*128

typedef __bf16 bf16x8 __attribute__((ext_vector_type(8)));
typedef float f32x4 __attribute__((ext_vector_type(4)));

// fast silu: 1-ulp rcp instead of IEEE divide (saves ~6 VALU ops/element)
__device__ __forceinline__ float siluf(float v) {
  return v * __builtin_amdgcn_rcpf(1.f + __expf(-v));
}
__device__ __forceinline__ float softplusf_(float v) {
  return fmaxf(v, 0.f) + log1pf(__expf(-fabsf(v)));
}
// native bf16 convert (gfx950 HW cvt, RNE)
__device__ __forceinline__ unsigned short f2bf(float v) {
  union { __bf16 b; unsigned short u; } x;
  x.b = (__bf16)v;
  return x.u;
}
__device__ __forceinline__ float bf2f(unsigned short u) {
  union { unsigned u; float f; } x; x.u = ((unsigned)u) << 16;
  return x.f;
}

// async global->LDS, 16B per lane, LDS dest = wave-uniform base + lane*16
__device__ __forceinline__ void gload_lds16(const unsigned short* g, unsigned short* l) {
  __builtin_amdgcn_global_load_lds(
      (const __attribute__((address_space(1))) unsigned int*)g,
      (__attribute__((address_space(3))) unsigned int*)l, 16, 0, 0);
}

struct P4 { const float* p[4]; };

// ---------------- fused prep: xbf cvt | Wt_in | Wt_dirs | Wt_fin | inv ----------------
__global__ void k_prep_all(const float* __restrict__ xH, const float* __restrict__ xV,
                           const float* __restrict__ WH, const float* __restrict__ WV,
                           P4 ws, const float* __restrict__ W_out, const int* __restrict__ v2h,
                           unsigned short* __restrict__ xbf, unsigned short* __restrict__ Wt_in,
                           unsigned short* __restrict__ Wt_dirs, unsigned short* __restrict__ Wt_fin,
                           int* __restrict__ inv) {
  int bid = blockIdx.x;
  int tid = threadIdx.x;
  if (bid < 8192) {
    int mat = bid >> 12;
    int i = (bid & 4095) * 256 + tid;         // float4 index
    const float* s = mat ? xV : xH;
    float4 v = ((const float4*)s)[i];
    ushort4 o;
    o.x = f2bf(v.x); o.y = f2bf(v.y); o.z = f2bf(v.z); o.w = f2bf(v.w);
    ((ushort4*)(xbf + (size_t)mat * ROWS * 256))[i] = o;
  } else if (bid < 10496) {
    int i = (bid - 8192) * 256 + tid;         // 2*1152*256
    int z = i / (NPAD * 256);
    int rem = i - z * (NPAD * 256);
    int n = rem >> 8, k = rem & 255;
    const float* W = z ? WV : WH;
    int sl = n >= 544;
    int cc = n - (sl ? 544 : 0);
    float v = (cc < 532) ? W[(long)k * 1064 + sl * 532 + cc] : 0.f;
    Wt_in[i] = f2bf(v);
  } else if (bid < 11520) {
    int i = (bid - 10496) * 256 + tid;        // 4*65536
    int d = i >> 16;
    int rem = i & 65535;
    int n = rem >> 8, k = rem & 255;
    Wt_dirs[i] = f2bf(ws.p[d][(long)k * 256 + n]);
  } else if (bid < 12544) {
    int i = (bid - 11520) * 256 + tid;        // 256*1024, i = n*1024+k
    int n = i >> 10, k = i & 1023;
    Wt_fin[i] = f2bf(W_out[(long)k * 256 + n]);
  } else {
    int m = (bid - 12544) * 256 + tid;
    if (m < ROWS) {
      int b = m >> 13;
      inv[b * L_N + v2h[m]] = m;              // inverse of the v->h scatter
    }
  }
}

struct ScanConsts {
  const float* dt_bias[4];
  const float* A_log[4];
  const float* D[4];
};

// exact fp32 dt dot with LDS staging; precompute dtv (softplus) and dA (exp(dt*A))
__global__ __launch_bounds__(256) void k_dtfix(
    const float* __restrict__ xH, const float* __restrict__ xV,
    const float* __restrict__ WH, const float* __restrict__ WV,
    ScanConsts sc, float* __restrict__ dtv_arr, float* __restrict__ dA_arr) {
  __shared__ float xs[32][257];
  __shared__ float Wsm[8][260];
  const int mat = blockIdx.y;
  const float* x = mat ? xV : xH;
  const float* W = mat ? WV : WH;
  const int r0 = blockIdx.x * 32;
  for (int i = threadIdx.x; i < 2048; i += 256) {
    int c = i >> 8, k = i & 255;              // c = sl*4+h
    int sl = c >> 2, h = c & 3;
    Wsm[c][k] = W[(long)k * 1064 + sl * 532 + 528 + h];
  }
  for (int i = threadIdx.x; i < 32 * 64; i += 256) {
    int rl = i >> 6, kq = (i & 63) * 4;
    float4 v = *(const float4*)(x + (long)(r0 + rl) * 256 + kq);
    xs[rl][kq + 0] = v.x; xs[rl][kq + 1] = v.y; xs[rl][kq + 2] = v.z; xs[rl][kq + 3] = v.w;
  }
  __syncthreads();
  const int rl = threadIdx.x >> 3, c = threadIdx.x & 7;
  float s = 0.f;
  #pragma unroll 8
  for (int k = 0; k < 256; ++k) s = fmaf(xs[rl][k], Wsm[c][k], s);
  const int sl = c >> 2, h = c & 3;
  const int dir = mat * 2 + sl;
  float dtv = softplusf_(s + sc.dt_bias[dir][h]);
  float dAv = __expf(dtv * (-__expf(sc.A_log[dir][h])));
  long o = ((long)dir * 4 + h) * ROWS + (r0 + rl);
  dtv_arr[o] = dtv;
  dA_arr[o] = dAv;
}

// ---------------- bf16 MFMA GEMM (128x128 tile, BK=32, async LDS staging) ----------------
struct EpiIn {
  unsigned short* zsil;   // [4][ROWS*256] silu(z)
  unsigned short* xsil;   // [4][ROWS*256] silu(x)
  unsigned short* bc;     // [4][ROWS*16]  silu(B)|silu(C)
};

// input-proj GEMM: A row-major bf16 (lda=K=256), Bt [n][k]. Routing epilogue via
// per-wave 16-row LDS transpose. Grid: x=row tiles, y=col tiles, z=mat.
__global__ __launch_bounds__(256) void k_gemm_in(
    const unsigned short* __restrict__ Abase, const unsigned short* __restrict__ Btbase,
    EpiIn ep) {
  __shared__ unsigned short As[128 * 32];
  __shared__ unsigned short Bs[128 * 32];
  __shared__ unsigned short trs[4][16 * 72];
  const int tid = threadIdx.x;
  const int lane = tid & 63;
  const int wid = tid >> 6;
  const int wm = wid & 1, wn = wid >> 1;
  const int q = lane >> 4, r = lane & 15;
  const int m0 = blockIdx.x * 128;
  const int n0 = blockIdx.y * 128;
  const int z = blockIdx.z;
  const unsigned short* A = Abase + (long)z * ROWS * 256;
  const unsigned short* Bt = Btbase + (long)z * NPAD * 256;

  f32x4 acc[4][4] = {};
  const int swr = (r >> 1) & 3;               // read-side swizzle

  for (int kt = 0; kt < 256; kt += 32) {
    #pragma unroll
    for (int i = 0; i < 2; ++i) {
      int idx = i * 256 + tid;
      int row = idx >> 2;
      int ch = (idx & 3) ^ ((row >> 1) & 3);
      gload_lds16(A + (long)(m0 + row) * 256 + kt + ch * 8,
                  &As[(size_t)(i * 256 + wid * 64) * 8]);
    }
    #pragma unroll
    for (int i = 0; i < 2; ++i) {
      int idx = i * 256 + tid;
      int row = idx >> 2;
      int ch = (idx & 3) ^ ((row >> 1) & 3);
      gload_lds16(Bt + (long)(n0 + row) * 256 + kt + ch * 8,
                  &Bs[(size_t)(i * 256 + wid * 64) * 8]);
    }
    __syncthreads();
    bf16x8 af[4], bfr[4];
    #pragma unroll
    for (int mi = 0; mi < 4; ++mi)
      af[mi] = *(const bf16x8*)&As[((wm * 64 + mi * 16 + r) * 4 + (q ^ swr)) * 8];
    #pragma unroll
    for (int ni = 0; ni < 4; ++ni)
      bfr[ni] = *(const bf16x8*)&Bs[((wn * 64 + ni * 16 + r) * 4 + (q ^ swr)) * 8];
    #pragma unroll
    for (int mi = 0; mi < 4; ++mi)
      #pragma unroll
      for (int ni = 0; ni < 4; ++ni)
        acc[mi][ni] = __builtin_amdgcn_mfma_f32_16x16x32_bf16(af[mi], bfr[ni], acc[mi][ni], 0, 0, 0);
    __syncthreads();
  }

  // per-wave dedicated transpose region: 16 rows x 72 cols
  unsigned short* tr = trs[wid];
  #pragma unroll
  for (int mi = 0; mi < 4; ++mi) {
    #pragma unroll
    for (int ni = 0; ni < 4; ++ni)
      #pragma unroll
      for (int j = 0; j < 4; ++j)
        tr[(q * 4 + j) * 72 + ni * 16 + r] = f2bf(siluf(acc[mi][ni][j]));
    asm volatile("s_waitcnt lgkmcnt(0)" ::: "memory");
    #pragma unroll
    for (int pass = 0; pass < 2; ++pass) {
      int rl = pass * 8 + (lane >> 3);
      int c8 = (lane & 7) * 8;
      bf16x8 v = *(const bf16x8*)&tr[rl * 72 + c8];
      int row = m0 + wm * 64 + mi * 16 + rl;
      int col = n0 + wn * 64 + c8;
      int sl = col >= 544;
      int cc = col - (sl ? 544 : 0);
      if (cc < 528) {
        int dir = z * 2 + sl;
        if (cc < 256)
          *(bf16x8*)(ep.zsil + ((long)dir * ROWS + row) * 256 + cc) = v;
        else if (cc < 512)
          *(bf16x8*)(ep.xsil + ((long)dir * ROWS + row) * 256 + cc - 256) = v;
        else
          *(bf16x8*)(ep.bc + ((long)dir * ROWS + row) * 16 + cc - 512) = v;
      }
    }
    asm volatile("s_waitcnt lgkmcnt(0)" ::: "memory");
  }
}

// ---------------- fused out-proj + final GEMM, split by dir pair ----------------
__global__ __launch_bounds__(256) void k_fuse(
    const unsigned short* __restrict__ ybf,      // [4][ROWS][256]
    const unsigned short* __restrict__ Wt_dirs,  // [4][256 n][256 k]
    const unsigned short* __restrict__ Wt_fin,   // [256 c][1024 k] (k = d*256+kk)
    const int* __restrict__ inv,
    float* __restrict__ pbuf) {                  // [2][ROWS*256]
  __shared__ unsigned short Tl[64][264];         // silu'd T, row-major, pad 264
  __shared__ unsigned short As1[64 * 32];        // y-tile staging
  __shared__ unsigned short Bs1[256 * 32];       // weight staging (both gemms)
  __shared__ int arow[64];
  const int tid = threadIdx.x;
  const int lane = tid & 63;
  const int wid = tid >> 6;
  const int q = lane >> 4, r = lane & 15;
  const int r0 = blockIdx.x * 64;
  const int pair = blockIdx.y;
  const int swr = (r >> 1) & 3;

  if (tid < 64) arow[tid] = pair ? inv[r0 + tid] : (r0 + tid);
  __syncthreads();

  f32x4 acc_o[4][4] = {};

  #pragma unroll
  for (int dd = 0; dd < 2; ++dd) {
    const int d = pair * 2 + dd;
    const unsigned short* yd = ybf + (long)d * ROWS * 256;
    const unsigned short* Wd = Wt_dirs + (long)d * 65536;

    f32x4 acc_t[4][4] = {};
    // ---- first GEMM: T = y_d[rows,:] @ Wd  (K=256) ----
    for (int kt = 0; kt < 256; kt += 32) {
      {
        int row = tid >> 2;
        int ch = (tid & 3) ^ ((row >> 1) & 3);
        gload_lds16(yd + (long)arow[row] * 256 + kt + ch * 8, &As1[(size_t)(wid * 64) * 8]);
      }
      #pragma unroll
      for (int i = 0; i < 4; ++i) {
        int idx = i * 256 + tid;
        int row = idx >> 2;
        int ch = (idx & 3) ^ ((row >> 1) & 3);
        gload_lds16(Wd + (long)row * 256 + kt + ch * 8,
                    &Bs1[(size_t)(i * 256 + wid * 64) * 8]);
      }
      __syncthreads();
      bf16x8 af[4], bfr[4];
      #pragma unroll
      for (int mi = 0; mi < 4; ++mi)
        af[mi] = *(const bf16x8*)&As1[((mi * 16 + r) * 4 + (q ^ swr)) * 8];
      #pragma unroll
      for (int ni = 0; ni < 4; ++ni)
        bfr[ni] = *(const bf16x8*)&Bs1[((wid * 64 + ni * 16 + r) * 4 + (q ^ swr)) * 8];
      #pragma unroll
      for (int mi = 0; mi < 4; ++mi)
        #pragma unroll
        for (int ni = 0; ni < 4; ++ni)
          acc_t[mi][ni] = __builtin_amdgcn_mfma_f32_16x16x32_bf16(af[mi], bfr[ni], acc_t[mi][ni], 0, 0, 0);
      __syncthreads();
    }
    // ---- write silu(T) to LDS (row-major) ----
    #pragma unroll
    for (int mi = 0; mi < 4; ++mi)
      #pragma unroll
      for (int ni = 0; ni < 4; ++ni)
        #pragma unroll
        for (int j = 0; j < 4; ++j)
          Tl[mi * 16 + q * 4 + j][wid * 64 + ni * 16 + r] = f2bf(siluf(acc_t[mi][ni][j]));
    __syncthreads();
    // ---- second GEMM: acc_o += T @ Wout[d*256+kk][c], A from Tl ----
    for (int kt = 0; kt < 256; kt += 32) {
      #pragma unroll
      for (int i = 0; i < 4; ++i) {
        int idx = i * 256 + tid;
        int row = idx >> 2;                    // out col c
        int ch = (idx & 3) ^ ((row >> 1) & 3);
        gload_lds16(Wt_fin + (long)row * 1024 + d * 256 + kt + ch * 8,
                    &Bs1[(size_t)(i * 256 + wid * 64) * 8]);
      }
      __syncthreads();
      bf16x8 af[4], bfr[4];
      #pragma unroll
      for (int mi = 0; mi < 4; ++mi)
        af[mi] = *(const bf16x8*)&Tl[mi * 16 + r][kt + q * 8];
      #pragma unroll
      for (int ni = 0; ni < 4; ++ni)
        bfr[ni] = *(const bf16x8*)&Bs1[((wid * 64 + ni * 16 + r) * 4 + (q ^ swr)) * 8];
      #pragma unroll
      for (int mi = 0; mi < 4; ++mi)
        #pragma unroll
        for (int ni = 0; ni < 4; ++ni)
          acc_o[mi][ni] = __builtin_amdgcn_mfma_f32_16x16x32_bf16(af[mi], bfr[ni], acc_o[mi][ni], 0, 0, 0);
      __syncthreads();
    }
  }

  float* pout = pbuf + (long)pair * ROWS * 256;
  #pragma unroll
  for (int mi = 0; mi < 4; ++mi)
    #pragma unroll
    for (int j = 0; j < 4; ++j) {
      int row = r0 + mi * 16 + q * 4 + j;
      #pragma unroll
      for (int ni = 0; ni < 4; ++ni) {
        int col = wid * 64 + ni * 16 + r;
        pout[(long)row * 256 + col] = acc_o[mi][ni][j];
      }
    }
}

// sum the two pair partials into d_out
__global__ void k_red(const float* __restrict__ pbuf, float* __restrict__ out) {
  int i = blockIdx.x * 256 + threadIdx.x;     // float4 index, ROWS*256/4 total
  float4 a = ((const float4*)pbuf)[i];
  float4 b = ((const float4*)(pbuf + (size_t)ROWS * 256))[i];
  float4 o;
  o.x = a.x + b.x; o.y = a.y + b.y; o.z = a.z + b.z; o.w = a.w + b.w;
  ((float4*)out)[i] = o;
}

// ---------------- scan kernels ----------------
struct ScanP {
  const unsigned short* xsil;  // [4][ROWS*256]
  const unsigned short* zsil;
  const unsigned short* bc;    // [4][ROWS*16]
  const float* dtv;            // [16][ROWS]  (dir*4+h)
  const float* dA;
  const float* D[4];
};

// phase 1: per-chunk (32 steps) local scan from zero; write end-state S and cum-dA P
__global__ __launch_bounds__(64) void k_scan1(ScanP sp, float* __restrict__ S,
                                              float* __restrict__ P) {
  __shared__ __align__(16) float Bst[CHUNK][8];
  __shared__ float dAs[CHUNK];
  const int p = threadIdx.x;
  const int c = blockIdx.x;
  const int bh = blockIdx.y;
  const int d = blockIdx.z;
  const int b = bh >> 2, h = bh & 3;
  const int rev = d & 1;
  const int t0 = c * CHUNK;
  if (p < CHUNK) {
    const int t = t0 + p;
    const int l = rev ? (L_N - 1 - t) : t;
    const int row = (b << 13) + l;
    uint4 bv = *(const uint4*)(sp.bc + ((long)d * ROWS + row) * 16);
    const unsigned short* bu = (const unsigned short*)&bv;
    float dtvv = sp.dtv[((long)d * 4 + h) * ROWS + row];
    dAs[p] = sp.dA[((long)d * 4 + h) * ROWS + row];
    #pragma unroll
    for (int n = 0; n < 8; ++n) Bst[p][n] = bf2f(bu[n]) * dtvv;
  }
  __syncthreads();

  float st[8] = {0, 0, 0, 0, 0, 0, 0, 0};
  float cumdA = 1.f;
  const int l0 = rev ? (L_N - 1 - t0) : t0;
  const unsigned short* xp = sp.xsil + ((long)d * ROWS + (b << 13) + l0) * 256 + h * 64 + p;
  const long stp = rev ? -256L : 256L;

  // double-buffered 8-step load groups
  unsigned short xa[8], xb[8];
  #pragma unroll
  for (int j = 0; j < 8; ++j) xa[j] = xp[(long)j * stp];
  #pragma unroll
  for (int g = 0; g < 4; ++g) {
    if (g < 3) {
      #pragma unroll
      for (int j = 0; j < 8; ++j) xb[j] = xp[(long)((g + 1) * 8 + j) * stp];
    }
    #pragma unroll
    for (int j = 0; j < 8; ++j) {
      int s = g * 8 + j;
      float x = bf2f(xa[j]);
      float dA = dAs[s];
      f32x4 B0 = *(const f32x4*)&Bst[s][0];
      f32x4 B1 = *(const f32x4*)&Bst[s][4];
      cumdA *= dA;
      st[0] = fmaf(dA, st[0], x * B0[0]);
      st[1] = fmaf(dA, st[1], x * B0[1]);
      st[2] = fmaf(dA, st[2], x * B0[2]);
      st[3] = fmaf(dA, st[3], x * B0[3]);
      st[4] = fmaf(dA, st[4], x * B1[0]);
      st[5] = fmaf(dA, st[5], x * B1[1]);
      st[6] = fmaf(dA, st[6], x * B1[2]);
      st[7] = fmaf(dA, st[7], x * B1[3]);
    }
    #pragma unroll
    for (int j = 0; j < 8; ++j) xa[j] = xb[j];
  }
  float* Sp = S + ((((long)d * NCHUNK + c) * 8 + bh) * 64 + p) * 8;
  #pragma unroll
  for (int n = 0; n < 8; ++n) Sp[n] = st[n];
  if (p == 0) P[((long)d * NCHUNK + c) * 8 + bh] = cumdA;
}

// phase 2: sequential chunk-level combine -> carry-in per chunk (P preloaded to LDS)
__global__ __launch_bounds__(512) void k_scan2(const float* __restrict__ S,
                                               const float* __restrict__ P,
                                               float* __restrict__ carry) {
  __shared__ float Pl[NCHUNK];
  const int tid = threadIdx.x;
  const int dbh = blockIdx.x;
  const int d = dbh >> 3, bh = dbh & 7;
  if (tid < NCHUNK) Pl[tid] = P[((long)d * NCHUNK + tid) * 8 + bh];
  __syncthreads();
  float cy = 0.f;
  carry[(((long)d * NCHUNK + 0) * 8 + bh) * 512 + tid] = 0.f;
  #pragma unroll 8
  for (int c = 1; c < NCHUNK; ++c) {
    const float Sv = S[(((long)d * NCHUNK + (c - 1)) * 8 + bh) * 512 + tid];
    cy = fmaf(Pl[c - 1], cy, Sv);
    carry[(((long)d * NCHUNK + c) * 8 + bh) * 512 + tid] = cy;
  }
}

// phase 3: re-scan with carry-in, produce gated y in bf16
__global__ __launch_bounds__(64) void k_scan3(ScanP sp, const float* __restrict__ carry,
                                              unsigned short* __restrict__ ybf) {
  __shared__ __align__(16) float Bst[CHUNK][8];
  __shared__ __align__(16) float Cst[CHUNK][8];
  __shared__ float dAs[CHUNK];
  const int p = threadIdx.x;
  const int c = blockIdx.x;
  const int bh = blockIdx.y;
  const int d = blockIdx.z;
  const int b = bh >> 2, h = bh & 3;
  const int rev = d & 1;
  const float Dv = sp.D[d][h];
  const int t0 = c * CHUNK;
  if (p < CHUNK) {
    const int t = t0 + p;
    const int l = rev ? (L_N - 1 - t) : t;
    const int row = (b << 13) + l;
    const unsigned short* bp = sp.bc + ((long)d * ROWS + row) * 16;
    uint4 bv = *(const uint4*)bp;
    uint4 cv = *(const uint4*)(bp + 8);
    const unsigned short* bu = (const unsigned short*)&bv;
    const unsigned short* cu = (const unsigned short*)&cv;
    float dtvv = sp.dtv[((long)d * 4 + h) * ROWS + row];
    dAs[p] = sp.dA[((long)d * 4 + h) * ROWS + row];
    #pragma unroll
    for (int n = 0; n < 8; ++n) Bst[p][n] = bf2f(bu[n]) * dtvv;
    #pragma unroll
    for (int n = 0; n < 8; ++n) Cst[p][n] = bf2f(cu[n]);
  }
  __syncthreads();

  float st[8];
  {
    const float* cp = carry + ((((long)d * NCHUNK + c) * 8 + bh) * 64 + p) * 8;
    #pragma unroll
    for (int n = 0; n < 8; ++n) st[n] = cp[n];
  }

  const int l0 = rev ? (L_N - 1 - t0) : t0;
  const long base = (long)(b << 13) + l0;
  const unsigned short* xp = sp.xsil + ((long)d * ROWS + base) * 256 + h * 64 + p;
  const unsigned short* zp = sp.zsil + ((long)d * ROWS + base) * 256 + h * 64 + p;
  unsigned short* yp = ybf + ((long)d * ROWS + base) * 256 + h * 64 + p;
  const long stp = rev ? -256L : 256L;

  // double-buffered 8-step load groups (x and z)
  unsigned short xa[8], xb[8], za[8], zb[8];
  #pragma unroll
  for (int j = 0; j < 8; ++j) { xa[j] = xp[(long)j * stp]; za[j] = zp[(long)j * stp]; }
  #pragma unroll
  for (int g = 0; g < 4; ++g) {
    if (g < 3) {
      #pragma unroll
      for (int j = 0; j < 8; ++j) {
        xb[j] = xp[(long)((g + 1) * 8 + j) * stp];
        zb[j] = zp[(long)((g + 1) * 8 + j) * stp];
      }
    }
    #pragma unroll
    for (int j = 0; j < 8; ++j) {
      int s = g * 8 + j;
      float x = bf2f(xa[j]);
      float zv = bf2f(za[j]);
      float dA = dAs[s];
      f32x4 B0 = *(const f32x4*)&Bst[s][0];
      f32x4 B1 = *(const f32x4*)&Bst[s][4];
      f32x4 C0 = *(const f32x4*)&Cst[s][0];
      f32x4 C1 = *(const f32x4*)&Cst[s][4];
      st[0] = fmaf(dA, st[0], x * B0[0]);
      st[1] = fmaf(dA, st[1], x * B0[1]);
      st[2] = fmaf(dA, st[2], x * B0[2]);
      st[3] = fmaf(dA, st[3], x * B0[3]);
      st[4] = fmaf(dA, st[4], x * B1[0]);
      st[5] = fmaf(dA, st[5], x * B1[1]);
      st[6] = fmaf(dA, st[6], x * B1[2]);
      st[7] = fmaf(dA, st[7], x * B1[3]);
      float y01 = fmaf(st[1], C0[1], st[0] * C0[0]);
      float y23 = fmaf(st[3], C0[3], st[2] * C0[2]);
      float y45 = fmaf(st[5], C1[1], st[4] * C1[0]);
      float y67 = fmaf(st[7], C1[3], st[6] * C1[2]);
      float y = (y01 + y23) + (y45 + y67);
      y = fmaf(Dv, x, y) * zv;
      yp[(long)s * stp] = f2bf(y);
    }
    #pragma unroll
    for (int j = 0; j < 8; ++j) { xa[j] = xb[j]; za[j] = zb[j]; }
  }
}

// ---------------- launch ----------------
extern "C" void kernel_launch(void* const* d_in, const int* in_sizes, int n_in,
                              void* d_out, int out_size, void* d_ws, size_t ws_size,
                              hipStream_t stream) {
  const float* x_H = (const float*)d_in[0];
  const float* x_V = (const float*)d_in[1];
  const float* W_in_H = (const float*)d_in[2];
  const float* W_in_V = (const float*)d_in[3];
  const float* W_out_HF = (const float*)d_in[4];
  const float* W_out_HB = (const float*)d_in[5];
  const float* W_out_VF = (const float*)d_in[6];
  const float* W_out_VB = (const float*)d_in[7];
  const float* W_out = (const float*)d_in[8];
  const float* dt_bias_HF = (const float*)d_in[9];
  const float* A_log_HF = (const float*)d_in[10];
  const float* D_HF = (const float*)d_in[11];
  const float* dt_bias_HB = (const float*)d_in[12];
  const float* A_log_HB = (const float*)d_in[13];
  const float* D_HB = (const float*)d_in[14];
  const float* dt_bias_VF = (const float*)d_in[15];
  const float* A_log_VF = (const float*)d_in[16];
  const float* D_VF = (const float*)d_in[17];
  const float* dt_bias_VB = (const float*)d_in[18];
  const float* A_log_VB = (const float*)d_in[19];
  const float* D_VB = (const float*)d_in[20];
  const int* v2h = (const int*)d_in[21];

  char* ws = (char*)d_ws;
  size_t off = 0;
  auto alloc = [&](size_t bytes) {
    void* pp = ws + off;
    off = (off + bytes + 255) & ~(size_t)255;
    return pp;
  };
  unsigned short* xbf = (unsigned short*)alloc((size_t)2 * ROWS * 256 * 2);      // [2 mats]
  unsigned short* Wt_in = (unsigned short*)alloc((size_t)2 * NPAD * 256 * 2);    // [2 mats]
  unsigned short* Wt_dirs = (unsigned short*)alloc((size_t)4 * 65536 * 2);
  unsigned short* Wt_fin = (unsigned short*)alloc((size_t)256 * 1024 * 2);
  unsigned short* zsil = (unsigned short*)alloc((size_t)4 * ROWS * 256 * 2);
  unsigned short* xsil = (unsigned short*)alloc((size_t)4 * ROWS * 256 * 2);
  unsigned short* bc = (unsigned short*)alloc((size_t)4 * ROWS * 16 * 2);
  float* dtv_arr = (float*)alloc((size_t)16 * ROWS * 4);
  float* dA_arr = (float*)alloc((size_t)16 * ROWS * 4);
  unsigned short* ybf = (unsigned short*)alloc((size_t)4 * ROWS * 256 * 2);
  float* S = (float*)alloc((size_t)4 * NCHUNK * 8 * 512 * 4);
  float* P = (float*)alloc((size_t)4 * NCHUNK * 8 * 4);
  float* carry = (float*)alloc((size_t)4 * NCHUNK * 8 * 512 * 4);
  int* inv = (int*)alloc((size_t)ROWS * 4);
  float* pbuf = (float*)alloc((size_t)2 * ROWS * 256 * 4);

  P4 wdirs;  // cat order: dir0 HF->W_out_HB, dir1 HB->W_out_HF, dir2 VF->W_out_VB, dir3 VB->W_out_VF
  wdirs.p[0] = W_out_HB; wdirs.p[1] = W_out_HF; wdirs.p[2] = W_out_VB; wdirs.p[3] = W_out_VF;
  k_prep_all<<<12608, 256, 0, stream>>>(x_H, x_V, W_in_H, W_in_V, wdirs, W_out, v2h,
                                        xbf, Wt_in, Wt_dirs, Wt_fin, inv);

  ScanConsts sc;
  sc.dt_bias[0] = dt_bias_HF; sc.dt_bias[1] = dt_bias_HB;
  sc.dt_bias[2] = dt_bias_VF; sc.dt_bias[3] = dt_bias_VB;
  sc.A_log[0] = A_log_HF; sc.A_log[1] = A_log_HB;
  sc.A_log[2] = A_log_VF; sc.A_log[3] = A_log_VB;
  sc.D[0] = D_HF; sc.D[1] = D_HB; sc.D[2] = D_VF; sc.D[3] = D_VB;

  EpiIn ep; ep.zsil = zsil; ep.xsil = xsil; ep.bc = bc;

  // input GEMMs (batched over 2 mats), routing epilogue -> zsil/xsil/bc bf16
  k_gemm_in<<<dim3(ROWS / 128, NPAD / 128, 2), 256, 0, stream>>>(xbf, Wt_in, ep);
  // exact fp32 dt -> dtv, dA
  k_dtfix<<<dim3(ROWS / 32, 2), 256, 0, stream>>>(x_H, x_V, W_in_H, W_in_V, sc, dtv_arr, dA_arr);

  ScanP sp;
  sp.xsil = xsil; sp.zsil = zsil; sp.bc = bc; sp.dtv = dtv_arr; sp.dA = dA_arr;
  sp.D[0] = D_HF; sp.D[1] = D_HB; sp.D[2] = D_VF; sp.D[3] = D_VB;

  k_scan1<<<dim3(NCHUNK, 8, 4), 64, 0, stream>>>(sp, S, P);
  k_scan2<<<32, 512, 0, stream>>>(S, P, carry);
  k_scan3<<<dim3(NCHUNK, 8, 4), 64, 0, stream>>>(sp, carry, ybf);

  // fused out-proj + final GEMM, split by dir pair -> fp32 partials
  k_fuse<<<dim3(ROWS / 64, 2), 256, 0, stream>>>(ybf, Wt_dirs, Wt_fin, inv, pbuf);
  // sum partials -> d_out
  k_red<<<ROWS * 256 / 4 / 256, 256, 0, stream>>>(pbuf, (float*)d_out);

  (void)in_sizes; (void)n_in; (void)out_size; (void)ws_size;
}